// Round 6
// baseline (1617.397 us; speedup 1.0000x reference)
//
#include <hip/hip_runtime.h>
#include <hip/hip_bf16.h>

typedef __hip_bfloat16 bf16;
typedef short bf16x8 __attribute__((ext_vector_type(8)));
typedef float f32x4 __attribute__((ext_vector_type(4)));

#define BNS 0.9999950000374997f  /* 1/sqrt(1+1e-5) */

__device__ __forceinline__ float geluf(float x) { return 0.5f * x * (1.0f + erff(x * 0.70710678118654752f)); }
__device__ __forceinline__ float sigmf(float x) { return 1.0f / (1.0f + expf(-x)); }
__device__ __forceinline__ unsigned short f2b(float f) { bf16 h = __float2bfloat16(f); return *(unsigned short*)&h; }

// ============ weight prep #1: bf16 frag-linear packs (PA, LA, fuse1) ========================
// Generic frag layout: idx = ((kc*MT + mb)*64 + lane)*8 + j
//   m = mb*16 + (lane&15), k = kc*32 + (lane>>4)*8 + j
__global__ __launch_bounds__(256) void k_wprep(const float* __restrict__ pa_w1,
    const float* __restrict__ pa_g, const float* __restrict__ pa_w2,
    const float* __restrict__ la_w, const float* __restrict__ la_g,
    const float* __restrict__ f1w,
    unsigned short* __restrict__ W1PA, unsigned short* __restrict__ W2PA,
    unsigned short* __restrict__ WLAP, unsigned short* __restrict__ F1P) {
  int i = blockIdx.x * 256 + threadIdx.x;
  if (i < 16384) {
    int j = i & 7, lane = (i >> 3) & 63, q = i >> 9;
    int mb = q % 16, kc = q / 16;
    int m = mb * 16 + (lane & 15), k = kc * 32 + (lane >> 4) * 8 + j;
    W1PA[i] = f2b(pa_w1[m * 64 + k] * (pa_g[m] * BNS));
  } else if (i < 32768) {
    int ii = i - 16384;
    int j = ii & 7, lane = (ii >> 3) & 63, q = ii >> 9;
    int mb = q % 4, kc = q / 4;
    int m = mb * 16 + (lane & 15), k = kc * 32 + (lane >> 4) * 8 + j;
    W2PA[ii] = f2b(pa_w2[m * 256 + k]);
  } else if (i < 69632) {
    int ii = i - 32768;
    int j = ii & 7, lane = (ii >> 3) & 63, q = ii >> 9;
    int mb = q % 4, gk = q / 4;           // gk = tap*2 + kc2, tap = ky*3+kx
    int tap = gk >> 1, kc2 = gk & 1;
    int co = mb * 16 + (lane & 15), ci = kc2 * 32 + (lane >> 4) * 8 + j;
    WLAP[ii] = f2b(la_w[(co * 64 + ci) * 9 + tap] * (la_g[co] * BNS));
  } else if (i < 77824) {
    int ii = i - 69632;
    int j = ii & 7, lane = (ii >> 3) & 63, q = ii >> 9;
    int mb = q % 4, kc = q / 4;
    int m = mb * 16 + (lane & 15), k = kc * 32 + (lane >> 4) * 8 + j;
    F1P[ii] = f2b(f1w[m * 128 + k]);
  }
}

// ============ weight prep #2: GA-phase packs (after MRA frees R-tail) =======================
__global__ __launch_bounds__(256) void k_wprep2(const float* __restrict__ f2w,
    const float* __restrict__ p1w, const float* __restrict__ c1w,
    const float* __restrict__ c2w, const float* __restrict__ cvw,
    const float* __restrict__ p2w,
    unsigned short* __restrict__ F2P, unsigned short* __restrict__ P1P,
    unsigned short* __restrict__ C1P, unsigned short* __restrict__ C2P,
    unsigned short* __restrict__ CVP, unsigned short* __restrict__ P2P) {
  int i = blockIdx.x * 256 + threadIdx.x;
  if (i < 8192) {               // fuse2: MT=4, K=128
    int j = i & 7, lane = (i >> 3) & 63, q = i >> 9;
    int mb = q % 4, kc = q / 4;
    int m = mb * 16 + (lane & 15), k = kc * 32 + (lane >> 4) * 8 + j;
    F2P[i] = f2b(f2w[m * 128 + k]);
  } else if (i < 12288) {       // p1: MT=4, K=64
    int ii = i - 8192;
    int j = ii & 7, lane = (ii >> 3) & 63, q = ii >> 9;
    int mb = q % 4, kc = q / 4;
    int m = mb * 16 + (lane & 15), k = kc * 32 + (lane >> 4) * 8 + j;
    P1P[ii] = f2b(p1w[m * 64 + k]);
  } else if (i < 14336) {       // c1: MT=2, K=64
    int ii = i - 12288;
    int j = ii & 7, lane = (ii >> 3) & 63, q = ii >> 9;
    int mb = q % 2, kc = q / 2;
    int m = mb * 16 + (lane & 15), k = kc * 32 + (lane >> 4) * 8 + j;
    C1P[ii] = f2b(c1w[m * 64 + k]);
  } else if (i < 16384) {       // c2: MT=2, K=64
    int ii = i - 14336;
    int j = ii & 7, lane = (ii >> 3) & 63, q = ii >> 9;
    int mb = q % 2, kc = q / 2;
    int m = mb * 16 + (lane & 15), k = kc * 32 + (lane >> 4) * 8 + j;
    C2P[ii] = f2b(c2w[m * 64 + k]);
  } else if (i < 18432) {       // cv: MT=4, K=32
    int ii = i - 16384;
    int j = ii & 7, lane = (ii >> 3) & 63, q = ii >> 9;
    int mb = q % 4;             // kc = 0
    int m = mb * 16 + (lane & 15), k = (lane >> 4) * 8 + j;
    CVP[ii] = f2b(cvw[m * 32 + k]);
  } else if (i < 22528) {       // p2: MT=4, K=64
    int ii = i - 18432;
    int j = ii & 7, lane = (ii >> 3) & 63, q = ii >> 9;
    int mb = q % 4, kc = q / 4;
    int m = mb * 16 + (lane & 15), k = kc * 32 + (lane >> 4) * 8 + j;
    P2P[ii] = f2b(p2w[m * 64 + k]);
  }
}

// ============ PA branch v3: chained MFMA GEMMs (64 -> 256 gelu -> 64) =======================
// 1152 blocks x 256 thr. Block = 128 px; wave owns 32 px (2 n-tiles).
__global__ __launch_bounds__(256, 2) void k_pa(const float* __restrict__ x,
    const unsigned short* __restrict__ W1PA, const float* __restrict__ b1,
    const unsigned short* __restrict__ W2PA,
    float* __restrict__ x1pa, bf16* __restrict__ xa) {
  __shared__ unsigned short hs[128][40];
  __shared__ float b1s[256];
  int t = threadIdx.x;
  b1s[t] = b1[t];
  __syncthreads();
  int b = blockIdx.x / 72;
  int hw0 = (blockIdx.x % 72) * 128;
  int lane = t & 63, wave = t >> 6, lm = lane & 15, lk = lane >> 4;
  // GEMM1 B-frags: X1[ch=k][px=n], direct global f32 -> bf16
  bf16x8 Bf[2][2];   // [nt][ks]
  {
    const float* xb = x + (size_t)b * 256 * 9216 + hw0 + wave * 32 + lm;
#pragma unroll
    for (int nt = 0; nt < 2; ++nt)
#pragma unroll
      for (int ks = 0; ks < 2; ++ks)
#pragma unroll
        for (int j = 0; j < 8; ++j)
          Bf[nt][ks][j] = (short)f2b(xb[(size_t)(ks * 32 + lk * 8 + j) * 9216 + nt * 16]);
  }
  f32x4 Y[4][2];
#pragma unroll
  for (int i = 0; i < 4; ++i) { Y[i][0] = (f32x4){0,0,0,0}; Y[i][1] = (f32x4){0,0,0,0}; }

  for (int c = 0; c < 8; ++c) {   // hidden chunks of 32
    f32x4 Hc[2][2];
#pragma unroll
    for (int i = 0; i < 2; ++i) { Hc[i][0] = (f32x4){0,0,0,0}; Hc[i][1] = (f32x4){0,0,0,0}; }
#pragma unroll
    for (int ks = 0; ks < 2; ++ks)
#pragma unroll
      for (int mt = 0; mt < 2; ++mt) {
        bf16x8 a = *(const bf16x8*)(W1PA + ((size_t)((ks * 16 + c * 2 + mt) * 64 + lane) * 8));
        Hc[mt][0] = __builtin_amdgcn_mfma_f32_16x16x32_bf16(a, Bf[0][ks], Hc[mt][0], 0, 0, 0);
        Hc[mt][1] = __builtin_amdgcn_mfma_f32_16x16x32_bf16(a, Bf[1][ks], Hc[mt][1], 0, 0, 0);
      }
    // gelu(+bias) -> hs (wave-private rows)
#pragma unroll
    for (int mt = 0; mt < 2; ++mt)
#pragma unroll
      for (int nt = 0; nt < 2; ++nt)
#pragma unroll
        for (int r = 0; r < 4; r += 2) {
          int h = c * 32 + mt * 16 + lk * 4 + r;
          float v0 = geluf(Hc[mt][nt][r]     + b1s[h]);
          float v1 = geluf(Hc[mt][nt][r + 1] + b1s[h + 1]);
          unsigned u = (unsigned)f2b(v0) | ((unsigned)f2b(v1) << 16);
          *(unsigned*)&hs[wave * 32 + nt * 16 + lm][mt * 16 + lk * 4 + r] = u;
        }
    // GEMM2: accumulate Y over this chunk's K=32
    bf16x8 h0 = *(const bf16x8*)&hs[wave * 32 + lm][lk * 8];
    bf16x8 h1 = *(const bf16x8*)&hs[wave * 32 + 16 + lm][lk * 8];
#pragma unroll
    for (int mb = 0; mb < 4; ++mb) {
      bf16x8 a2 = *(const bf16x8*)(W2PA + ((size_t)((c * 4 + mb) * 64 + lane) * 8));
      Y[mb][0] = __builtin_amdgcn_mfma_f32_16x16x32_bf16(a2, h0, Y[mb][0], 0, 0, 0);
      Y[mb][1] = __builtin_amdgcn_mfma_f32_16x16x32_bf16(a2, h1, Y[mb][1], 0, 0, 0);
    }
  }
  // epilogue: sigmoid gate, write x1pa (f32) + xa ch0..63 (bf16)
#pragma unroll
  for (int mb = 0; mb < 4; ++mb)
#pragma unroll
    for (int nt = 0; nt < 2; ++nt)
#pragma unroll
      for (int r = 0; r < 4; ++r) {
        int co = mb * 16 + lk * 4 + r;
        int px = hw0 + wave * 32 + nt * 16 + lm;
        float x1v = x[((size_t)b * 256 + co) * 9216 + px];
        float pa = x1v * sigmf(Y[mb][nt][r]);
        x1pa[((size_t)b * 64 + co) * 9216 + px] = pa;
        xa[((size_t)b * 256 + co) * 9216 + px] = __float2bfloat16(x1v + pa);
      }
}

// ============ generic 1x1 MFMA conv =========================================================
// MT m-tiles (Cout = MT*16); K = (KCA+KCB)*32. Chunks [0,KCA) from inA (ch-major, CinA=KCA*32),
// chunks [KCA,..) from xsrc (256-ch x tensor) at channel xoff. Block = 128 px, 4 waves.
template<int MT, int KCA, int KCB>
__global__ __launch_bounds__(256, 2) void k_cg(const float* __restrict__ inA,
    const float* __restrict__ xsrc, int xoff,
    const unsigned short* __restrict__ wp, const float* __restrict__ bias, int act,
    float* __restrict__ out, int npix) {
  int t = threadIdx.x, lane = t & 63, wave = t >> 6, lm = lane & 15, lk = lane >> 4;
  int p0 = blockIdx.x * 128;
  int b = p0 / npix, hw0 = p0 % npix;
  f32x4 acc[MT][2];
#pragma unroll
  for (int i = 0; i < MT; ++i) { acc[i][0] = (f32x4){0,0,0,0}; acc[i][1] = (f32x4){0,0,0,0}; }
#pragma unroll
  for (int kc = 0; kc < KCA + KCB; ++kc) {
    bf16x8 bf[2];
#pragma unroll
    for (int nt = 0; nt < 2; ++nt) {
      if (kc < KCA) {
        const float* src = inA + ((size_t)b * (KCA * 32) + kc * 32 + lk * 8) * npix
                         + hw0 + wave * 32 + nt * 16 + lm;
#pragma unroll
        for (int j = 0; j < 8; ++j) bf[nt][j] = (short)f2b(src[(size_t)j * npix]);
      } else {
        const float* src = xsrc + ((size_t)b * 256 + xoff + (kc - KCA) * 32 + lk * 8) * 9216
                         + hw0 + wave * 32 + nt * 16 + lm;
#pragma unroll
        for (int j = 0; j < 8; ++j) bf[nt][j] = (short)f2b(src[(size_t)j * 9216]);
      }
    }
#pragma unroll
    for (int mb = 0; mb < MT; ++mb) {
      bf16x8 a = *(const bf16x8*)(wp + ((size_t)((kc * MT + mb) * 64 + lane) * 8));
      acc[mb][0] = __builtin_amdgcn_mfma_f32_16x16x32_bf16(a, bf[0], acc[mb][0], 0, 0, 0);
      acc[mb][1] = __builtin_amdgcn_mfma_f32_16x16x32_bf16(a, bf[1], acc[mb][1], 0, 0, 0);
    }
  }
#pragma unroll
  for (int mb = 0; mb < MT; ++mb)
#pragma unroll
    for (int nt = 0; nt < 2; ++nt)
#pragma unroll
      for (int r = 0; r < 4; ++r) {
        int c = mb * 16 + lk * 4 + r;
        float v = acc[mb][nt][r] + (bias ? bias[c] : 0.f);
        if (act) v = geluf(v);
        out[((size_t)b * (MT * 16) + c) * npix + hw0 + wave * 32 + nt * 16 + lm] = v;
      }
}

// ============ la v3: implicit-GEMM 3x3 conv 64->64 via 9 shifted 1x1s =======================
// 1536 blocks (b*96+py) x 384 thr (6 waves, wave = 16-px n-tile of the row). BN-g in WLAP.
__global__ __launch_bounds__(384, 2) void k_la(const float* __restrict__ Q,
    const unsigned short* __restrict__ WLAP, const float* __restrict__ bb,
    bf16* __restrict__ xa) {
  int py = blockIdx.x % 96, b = blockIdx.x / 96;
  int t = threadIdx.x, lane = t & 63, w = t >> 6, lm = lane & 15, lk = lane >> 4;
  int px = w * 16 + lm;
  f32x4 acc[4];
#pragma unroll
  for (int i = 0; i < 4; ++i) acc[i] = (f32x4){0,0,0,0};
#pragma unroll
  for (int ky = 0; ky < 3; ++ky) {
    int row = py + ky - 1;
    if ((unsigned)row >= 96u) continue;      // uniform: zero-pad row -> skip
#pragma unroll
    for (int kx = 0; kx < 3; ++kx) {
      int pxe = px + kx - 1;
      bool vld = (unsigned)pxe < 96u;        // per-lane horizontal pad
      int pxc = vld ? pxe : 0;
      const float* qb = Q + ((size_t)b * 64 + lk * 8) * 9216 + row * 96 + pxc;
#pragma unroll
      for (int kc = 0; kc < 2; ++kc) {
        bf16x8 bf;
#pragma unroll
        for (int j = 0; j < 8; ++j) {
          float v = vld ? qb[(size_t)(kc * 32 + j) * 9216] : 0.f;
          bf[j] = (short)f2b(v);
        }
        int gk = (ky * 3 + kx) * 2 + kc;
#pragma unroll
        for (int mb = 0; mb < 4; ++mb) {
          bf16x8 a = *(const bf16x8*)(WLAP + ((size_t)((gk * 4 + mb) * 64 + lane) * 8));
          acc[mb] = __builtin_amdgcn_mfma_f32_16x16x32_bf16(a, bf, acc[mb], 0, 0, 0);
        }
      }
    }
  }
#pragma unroll
  for (int mb = 0; mb < 4; ++mb)
#pragma unroll
    for (int r = 0; r < 4; ++r) {
      int co = mb * 16 + lk * 4 + r;
      float v = geluf(acc[mb][r] + bb[co]);
      xa[((size_t)b * 256 + 64 + co) * 9216 + py * 96 + px] = __float2bfloat16(v);
    }
}

// ---------------- maxpool3 -------------------------------------------------------------------
__global__ __launch_bounds__(256) void k_maxpool3(const float* __restrict__ x, float* __restrict__ out) {
  int idx = blockIdx.x * 256 + threadIdx.x;
  if (idx >= 16 * 64 * 9216) return;
  int wpx = idx % 96; int tmp = idx / 96; int h = tmp % 96; tmp /= 96; int c = tmp % 64; int b = tmp / 64;
  const float* src = x + (b * 256 + 128 + c) * 9216;
  float m = -3.4e38f;
  for (int dy = -1; dy <= 1; ++dy) {
    int y = h + dy; if ((unsigned)y >= 96u) continue;
    for (int dx = -1; dx <= 1; ++dx) {
      int xx = wpx + dx; if ((unsigned)xx >= 96u) continue;
      m = fmaxf(m, src[y * 96 + xx]);
    }
  }
  out[idx] = m;
}

// ---------------- blurpool -------------------------------------------------------------------
__global__ __launch_bounds__(256) void k_blur(const float* __restrict__ in, float* __restrict__ out) {
  int idx = blockIdx.x * 256 + threadIdx.x;
  if (idx >= 16 * 64 * 1024) return;
  int ow = idx % 32; int tmp = idx / 32; int oh = tmp % 32; int bc = tmp / 32;
  const float* src = in + bc * 9216;
  const float a4[4] = {1.f, 3.f, 3.f, 1.f};
  float s = 0.f;
  for (int ky = 0; ky < 4; ++ky) {
    int sy = 3 * oh + ky - 1; if (sy < 0) sy = -sy; if (sy > 95) sy = 190 - sy;
    for (int kx = 0; kx < 4; ++kx) {
      int sx = 3 * ow + kx - 1; if (sx < 0) sx = -sx; if (sx > 95) sx = 190 - sx;
      s += a4[ky] * a4[kx] * src[sy * 96 + sx];
    }
  }
  out[idx] = s * (1.0f / 64.0f);
}

// ---------------- generic depthwise conv ----------------------------------------------------
__global__ __launch_bounds__(256) void k_dw(const float* __restrict__ in, const float* __restrict__ w,
    const float* __restrict__ bias, float* __restrict__ out,
    int H, int W, int KH, int KW, int pH, int pW, int dil, int accf) {
  int idx = blockIdx.x * 256 + threadIdx.x;
  int total = 16 * 64 * H * W; if (idx >= total) return;
  int wpx = idx % W; int tmp = idx / W; int h = tmp % H; tmp /= H; int c = tmp % 64;
  const float* src = in + tmp * H * W;
  const float* wr = w + c * KH * KW;
  float a = bias ? bias[c] : 0.f;
  for (int ky = 0; ky < KH; ++ky) {
    int y = h - pH + ky * dil; if ((unsigned)y >= (unsigned)H) continue;
    for (int kx = 0; kx < KW; ++kx) {
      int xx = wpx - pW + kx * dil; if ((unsigned)xx >= (unsigned)W) continue;
      a += wr[ky * KW + kx] * src[y * W + xx];
    }
  }
  if (accf) out[idx] += a; else out[idx] = a;
}

// ---------------- shear transforms ----------------------------------------------------------
__global__ __launch_bounds__(256) void k_htrans(const float* __restrict__ in, float* __restrict__ out) {
  int idx = blockIdx.x * 256 + threadIdx.x;
  if (idx >= 16 * 64 * 32 * 63) return;
  int j = idx % 63; int tmp = idx / 63; int i = tmp % 32; int bc = tmp / 32;
  int k = j - i;
  out[idx] = (k >= 0 && k < 32) ? in[(bc * 32 + i) * 32 + k] : 0.f;
}
__global__ __launch_bounds__(256) void k_invh_add(const float* __restrict__ F, float* __restrict__ D) {
  int idx = blockIdx.x * 256 + threadIdx.x;
  if (idx >= 16 * 64 * 1024) return;
  int j = idx % 32; int tmp = idx / 32; int i = tmp % 32; int bc = tmp / 32;
  D[idx] += F[(bc * 32 + i) * 63 + i + j];
}
__global__ __launch_bounds__(256) void k_vtrans(const float* __restrict__ in, float* __restrict__ out) {
  int idx = blockIdx.x * 256 + threadIdx.x;
  if (idx >= 16 * 64 * 63 * 32) return;
  int c = idx % 32; int tmp = idx / 32; int r = tmp % 63; int bc = tmp / 63;
  int k = r - c;
  out[idx] = (k >= 0 && k < 32) ? in[(bc * 32 + k) * 32 + c] : 0.f;
}
__global__ __launch_bounds__(256) void k_invv_add(const float* __restrict__ F, float* __restrict__ D) {
  int idx = blockIdx.x * 256 + threadIdx.x;
  if (idx >= 16 * 64 * 1024) return;
  int j = idx % 32; int tmp = idx / 32; int i = tmp % 32; int bc = tmp / 32;
  D[idx] += F[(bc * 63 + (i + j)) * 32 + j];
}

// ---------------- gate ----------------------------------------------------------------------
__global__ __launch_bounds__(256) void k_gate(const float* __restrict__ D, const float* __restrict__ x,
    const float* __restrict__ g, const float* __restrict__ bb,
    float* __restrict__ mra_out, bf16* __restrict__ xa) {
  int idx = blockIdx.x * 256 + threadIdx.x;
  if (idx >= 16 * 64 * 9216) return;
  int wv = idx % 96; int tmp = idx / 96; int h = tmp % 96; tmp /= 96; int c = tmp % 64; int b = tmp / 64;
  float d = D[((b * 64 + c) * 32 + h / 3) * 32 + (wv / 3)];
  float gt = sigmf(d * g[c] * BNS + bb[c]);
  float x3v = x[(b * 256 + 128 + c) * 9216 + h * 96 + wv];
  float mra = x3v * gt;
  mra_out[idx] = mra;
  xa[(b * 256 + 128 + c) * 9216 + h * 96 + wv] = __float2bfloat16(x3v + mra);
}

// ---------------- maxpool2 with argmax ------------------------------------------------------
__global__ __launch_bounds__(256) void k_pool2(const float* __restrict__ in, float* __restrict__ out,
                                               int* __restrict__ idxo) {
  int idx = blockIdx.x * 256 + threadIdx.x;
  if (idx >= 16 * 64 * 2304) return;
  int ow = idx % 48; int tmp = idx / 48; int oh = tmp % 48; int bc = tmp / 48;
  const float* src = in + bc * 9216;
  int y = 2 * oh, xx = 2 * ow;
  float v0 = src[y * 96 + xx], v1 = src[y * 96 + xx + 1];
  float v2 = src[(y + 1) * 96 + xx], v3 = src[(y + 1) * 96 + xx + 1];
  float best = v0; int bi = 0;
  if (v1 > best) { best = v1; bi = 1; }
  if (v2 > best) { best = v2; bi = 2; }
  if (v3 > best) { best = v3; bi = 3; }
  out[idx] = best; idxo[idx] = bi;
}

// ---------------- channel mean/max ----------------------------------------------------------
__global__ __launch_bounds__(256) void k_agg(const float* __restrict__ J, const float* __restrict__ K,
                                             float* __restrict__ AGG) {
  int idx = blockIdx.x * 256 + threadIdx.x;
  if (idx >= 16 * 2304) return;
  int hw = idx % 2304; int b = idx / 2304;
  float sum = 0.f, mx = -3.4e38f;
  for (int j = 0; j < 32; ++j) { float v = J[(b * 32 + j) * 2304 + hw]; sum += v; mx = fmaxf(mx, v); }
  for (int j = 0; j < 32; ++j) { float v = K[(b * 32 + j) * 2304 + hw]; sum += v; mx = fmaxf(mx, v); }
  AGG[(b * 2 + 0) * 2304 + hw] = sum * (1.0f / 64.0f);
  AGG[(b * 2 + 1) * 2304 + hw] = mx;
}

// ---------------- squeeze conv 2->2 7x7 pad3 + sigmoid --------------------------------------
__global__ __launch_bounds__(256) void k_sq(const float* __restrict__ AGG, const float* __restrict__ w,
                                            const float* __restrict__ bias, float* __restrict__ SG) {
  int idx = blockIdx.x * 256 + threadIdx.x;
  if (idx >= 16 * 2 * 2304) return;
  int hw = idx % 2304; int tmp = idx / 2304; int co = tmp % 2; int b = tmp / 2;
  int h = hw / 48, wv = hw % 48;
  float acc = bias[co];
  for (int ci = 0; ci < 2; ++ci) {
    const float* src = AGG + (b * 2 + ci) * 2304;
    for (int ky = 0; ky < 7; ++ky) {
      int y = h - 3 + ky; if ((unsigned)y >= 48u) continue;
      for (int kx = 0; kx < 7; ++kx) {
        int xx = wv - 3 + kx; if ((unsigned)xx >= 48u) continue;
        acc += w[((co * 2 + ci) * 7 + ky) * 7 + kx] * src[y * 48 + xx];
      }
    }
  }
  SG[idx] = sigmf(acc);
}

__global__ __launch_bounds__(256) void k_mix(const float* __restrict__ J, const float* __restrict__ K,
                                             const float* __restrict__ SG, float* __restrict__ L) {
  int idx = blockIdx.x * 256 + threadIdx.x;
  if (idx >= 16 * 32 * 2304) return;
  int hw = idx % 2304; int tmp = idx / 2304; int b = tmp / 32;
  L[idx] = J[idx] * SG[(b * 2) * 2304 + hw] + K[idx] * SG[(b * 2 + 1) * 2304 + hw];
}

__global__ __launch_bounds__(256) void k_mul(const float* __restrict__ A, const float* __restrict__ B,
                                             float* __restrict__ O) {
  int idx = blockIdx.x * 256 + threadIdx.x;
  if (idx >= 16 * 64 * 2304) return;
  O[idx] = A[idx] * B[idx];
}

// ---------------- unpool + bn(n4), xa ch192..255 --------------------------------------------
__global__ __launch_bounds__(256) void k_unpool(const float* __restrict__ N2, const int* __restrict__ IDX,
    const float* __restrict__ x, const float* __restrict__ g, const float* __restrict__ bb,
    bf16* __restrict__ xa) {
  int idx = blockIdx.x * 256 + threadIdx.x;
  if (idx >= 16 * 64 * 9216) return;
  int wv = idx % 96; int tmp = idx / 96; int h = tmp % 96; tmp /= 96; int c = tmp % 64; int b = tmp / 64;
  int oh = h >> 1, ow = wv >> 1;
  int pos = (b * 64 + c) * 2304 + oh * 48 + ow;
  int kk = (h & 1) * 2 + (wv & 1);
  float v = (IDX[pos] == kk) ? N2[pos] : 0.f;
  float x4v = x[(b * 256 + 192 + c) * 9216 + h * 96 + wv];
  xa[(b * 256 + 192 + c) * 9216 + h * 96 + wv] =
      __float2bfloat16((x4v + v) * g[c] * BNS + bb[c]);
}

// ---------------- transpose XA (ch-major bf16) -> XAT (pixel-major bf16) --------------------
__global__ __launch_bounds__(256) void k_tr(const unsigned short* __restrict__ XA,
                                            unsigned short* __restrict__ XAT) {
  __shared__ unsigned s[64][65];
  int t = threadIdx.x;
  int bid = blockIdx.x;
  int ct = bid & 3;
  int pt = (bid >> 2) % 144;
  int b = (bid >> 2) / 144;
  int c0 = ct * 64, p0 = pt * 64;
  for (int i = t; i < 4096; i += 256) {
    int cl = i >> 6, pl = i & 63;
    s[cl][pl] = XA[(size_t)(b * 256 + c0 + cl) * 9216 + p0 + pl];
  }
  __syncthreads();
  for (int i = t; i < 4096; i += 256) {
    int pl = i >> 6, cl = i & 63;
    XAT[((size_t)(b * 9216 + p0 + pl) << 8) + c0 + cl] = (unsigned short)s[cl][pl];
  }
}

// ---------------- prep: MLP weights frag-linear, bf16, BN scales folded ---------------------
__global__ __launch_bounds__(256) void k_prep(const float* __restrict__ w1, const float* __restrict__ g1,
    const float* __restrict__ w2, const float* __restrict__ ng,
    unsigned short* __restrict__ w1p, unsigned short* __restrict__ w2p) {
  int i = blockIdx.x * 256 + threadIdx.x;
  if (i >= 262144) return;
  {
    int j = i & 7, lane = (i >> 3) & 63, ks = (i >> 9) & 7, mb = i >> 12;
    int h = mb * 16 + (lane & 15);
    int k = ks * 32 + (lane >> 4) * 8 + j;
    w1p[i] = f2b(w1[h * 256 + k] * (g1[h] * BNS));
  }
  {
    int j = i & 7, lane = (i >> 3) & 63, mb = (i >> 9) & 15, c = i >> 13;
    int m = mb * 16 + (lane & 15);
    int k = c * 32 + (lane >> 4) * 8 + j;
    w2p[i] = f2b(w2[m * 1024 + k] * (ng[m] * BNS));
  }
}

// ---------------- fused MFMA MLP v3: register-prefetch double-buffered weight staging -------
// Per chunk: issue chunk c+1's global loads at top of compute (latency hides under MFMA+gelu),
// then barrier -> ds_write regs -> barrier. No exposed global latency between barriers.
__global__ __launch_bounds__(256, 2) void k_mlp_mfma(
    const unsigned short* __restrict__ XAT,
    const unsigned short* __restrict__ W1P, const float* __restrict__ b1,
    const unsigned short* __restrict__ W2P, const float* __restrict__ nbv,
    const float* __restrict__ xin, float* __restrict__ out) {
  __shared__ uint4 w1c4[1024];
  __shared__ uint4 w2c4[1024];
  __shared__ unsigned short hs[128][56];
  __shared__ float b1s[1024];
  __shared__ float nbs[256];
  unsigned short* w1c = (unsigned short*)w1c4;
  unsigned short* w2c = (unsigned short*)w2c4;
  int t = threadIdx.x;
  int b = blockIdx.x / 72;
  int hw0 = (blockIdx.x % 72) * 128;
  for (int i = t; i < 1024; i += 256) b1s[i] = b1[i];
  nbs[t] = nbv[t];
  int lane = t & 63, wave = t >> 6;
  int lm = lane & 15, lk = lane >> 4;
  bf16x8 Bf[2][8];
  {
    const unsigned short* base = XAT + ((size_t)(b * 9216 + hw0 + wave * 32 + lm) << 8) + lk * 8;
#pragma unroll
    for (int nt2 = 0; nt2 < 2; ++nt2)
#pragma unroll
      for (int ks = 0; ks < 8; ++ks)
        Bf[nt2][ks] = *(const bf16x8*)(base + nt2 * 16 * 256 + ks * 32);
  }
  f32x4 Y[16][2];
#pragma unroll
  for (int i = 0; i < 16; ++i) { Y[i][0] = (f32x4){0,0,0,0}; Y[i][1] = (f32x4){0,0,0,0}; }

  const uint4* g1p = (const uint4*)W1P;
  const uint4* g2p = (const uint4*)W2P;
  // prologue: stage chunk 0 through regs
  uint4 p1[4], p2[4];
#pragma unroll
  for (int i = 0; i < 4; ++i) { p1[i] = g1p[i * 256 + t]; p2[i] = g2p[i * 256 + t]; }
#pragma unroll
  for (int i = 0; i < 4; ++i) { w1c4[i * 256 + t] = p1[i]; w2c4[i * 256 + t] = p2[i]; }
  __syncthreads();

  for (int c = 0; c < 32; ++c) {
    // prefetch chunk c+1 weights into regs (in flight during this chunk's compute)
    if (c < 31) {
#pragma unroll
      for (int i = 0; i < 4; ++i) {
        p1[i] = g1p[(c + 1) * 1024 + i * 256 + t];
        p2[i] = g2p[(c + 1) * 1024 + i * 256 + t];
      }
    }
    f32x4 Hc[2][2];
#pragma unroll
    for (int i = 0; i < 2; ++i) { Hc[i][0] = (f32x4){0,0,0,0}; Hc[i][1] = (f32x4){0,0,0,0}; }
#pragma unroll
    for (int ks = 0; ks < 8; ++ks) {
      bf16x8 a0 = *(const bf16x8*)&w1c[(ks * 64 + lane) * 8];
      bf16x8 a1 = *(const bf16x8*)&w1c[((8 + ks) * 64 + lane) * 8];
      Hc[0][0] = __builtin_amdgcn_mfma_f32_16x16x32_bf16(a0, Bf[0][ks], Hc[0][0], 0, 0, 0);
      Hc[0][1] = __builtin_amdgcn_mfma_f32_16x16x32_bf16(a0, Bf[1][ks], Hc[0][1], 0, 0, 0);
      Hc[1][0] = __builtin_amdgcn_mfma_f32_16x16x32_bf16(a1, Bf[0][ks], Hc[1][0], 0, 0, 0);
      Hc[1][1] = __builtin_amdgcn_mfma_f32_16x16x32_bf16(a1, Bf[1][ks], Hc[1][1], 0, 0, 0);
    }
#pragma unroll
    for (int mbl = 0; mbl < 2; ++mbl)
#pragma unroll
      for (int nt2 = 0; nt2 < 2; ++nt2)
#pragma unroll
        for (int r = 0; r < 4; r += 2) {
          int h = c * 32 + mbl * 16 + lk * 4 + r;
          float v0 = geluf(Hc[mbl][nt2][r]     + b1s[h]);
          float v1 = geluf(Hc[mbl][nt2][r + 1] + b1s[h + 1]);
          unsigned u = (unsigned)f2b(v0) | ((unsigned)f2b(v1) << 16);
          *(unsigned*)&hs[wave * 32 + nt2 * 16 + lm][mbl * 16 + lk * 4 + r] = u;
        }
    bf16x8 h0 = *(const bf16x8*)&hs[wave * 32 + lm][lk * 8];
    bf16x8 h1 = *(const bf16x8*)&hs[wave * 32 + 16 + lm][lk * 8];
#pragma unroll
    for (int mb = 0; mb < 16; ++mb) {
      bf16x8 a = *(const bf16x8*)&w2c[(mb * 64 + lane) * 8];
      Y[mb][0] = __builtin_amdgcn_mfma_f32_16x16x32_bf16(a, h0, Y[mb][0], 0, 0, 0);
      Y[mb][1] = __builtin_amdgcn_mfma_f32_16x16x32_bf16(a, h1, Y[mb][1], 0, 0, 0);
    }
    // swap in next chunk's weights (regs already loaded; global latency amortized)
    if (c < 31) {
      __syncthreads();   // all waves done reading current LDS weights
#pragma unroll
      for (int i = 0; i < 4; ++i) { w1c4[i * 256 + t] = p1[i]; w2c4[i * 256 + t] = p2[i]; }
      __syncthreads();   // new weights visible
    }
  }
#pragma unroll
  for (int mb = 0; mb < 16; ++mb)
#pragma unroll
    for (int nt2 = 0; nt2 < 2; ++nt2)
#pragma unroll
      for (int r = 0; r < 4; ++r) {
        int m = mb * 16 + lk * 4 + r;
        size_t o = (size_t)(b * 256 + m) * 9216 + hw0 + wave * 32 + nt2 * 16 + lm;
        out[o] = Y[mb][nt2][r] + nbs[m] + xin[o];
      }
}

extern "C" void kernel_launch(void* const* d_in, const int* in_sizes, int n_in,
                              void* d_out, int out_size, void* d_ws, size_t ws_size,
                              hipStream_t stream) {
  const float* x        = (const float*)d_in[0];
  const float* pa_w1    = (const float*)d_in[1];
  const float* pa_bn_g  = (const float*)d_in[2];
  const float* pa_bn_b  = (const float*)d_in[3];
  const float* pa_w2    = (const float*)d_in[4];
  const float* fuse1_w  = (const float*)d_in[5];
  const float* la_w     = (const float*)d_in[6];
  const float* la_bn_g  = (const float*)d_in[7];
  const float* la_bn_b  = (const float*)d_in[8];
  const float* h1_w     = (const float*)d_in[9];
  const float* v1_w     = (const float*)d_in[10];
  const float* h2_w     = (const float*)d_in[11];
  const float* v2_w     = (const float*)d_in[12];
  const float* mra_bn_g = (const float*)d_in[13];
  const float* mra_bn_b = (const float*)d_in[14];
  const float* fuse2_w  = (const float*)d_in[15];
  const float* g_p1_w   = (const float*)d_in[16];
  const float* g_p1_b   = (const float*)d_in[17];
  const float* g_c0_w   = (const float*)d_in[18];
  const float* g_c0_b   = (const float*)d_in[19];
  const float* g_cs_w   = (const float*)d_in[20];
  const float* g_cs_b   = (const float*)d_in[21];
  const float* g_c1_w   = (const float*)d_in[22];
  const float* g_c1_b   = (const float*)d_in[23];
  const float* g_c2_w   = (const float*)d_in[24];
  const float* g_c2_b   = (const float*)d_in[25];
  const float* g_sq_w   = (const float*)d_in[26];
  const float* g_sq_b   = (const float*)d_in[27];
  const float* g_cv_w   = (const float*)d_in[28];
  const float* g_cv_b   = (const float*)d_in[29];
  const float* g_p2_w   = (const float*)d_in[30];
  const float* g_p2_b   = (const float*)d_in[31];
  const float* n4_g     = (const float*)d_in[32];
  const float* n4_b     = (const float*)d_in[33];
  const float* mlp_w1   = (const float*)d_in[34];
  const float* mlp_bn_g = (const float*)d_in[35];
  const float* mlp_bn_b = (const float*)d_in[36];
  const float* mlp_w2   = (const float*)d_in[37];
  const float* n1_g     = (const float*)d_in[38];
  const float* n1_b     = (const float*)d_in[39];

  // ---- aliased workspace: 44,236,800 floats = 176.9 MB ----
  float* ws = (float*)d_ws;
  bf16*  XA = (bf16*)ws;                    // (16,256,96,96) bf16 = 18,874,368 f-slots
  float* P  = ws + 18874368;                // 9,437,184 f
  float* Q  = ws + 28311552;                // 9,437,184 f
  float* R  = ws + 37748736;                // 6,225,920 f
  float* T  = R;
  float* D  = R + 1048576;
  float* E  = R + 2097152;
  float* F  = R + 4161536;
  float* C48 = P;
  int*   IDX = (int*)(P + 2359296);
  float* G   = P + 4718592;
  float* H2  = P + 7077888;
  float* I2  = Q;
  float* M   = Q + 2359296;
  float* XM  = Q + 4718592;
  float* N2  = Q + 7077888;
  float* J   = R;
  float* K2  = R + 1179648;
  float* L   = R + 2359296;
  float* AGG = R + 3538944;
  float* SG  = R + 3612672;
  unsigned short* XAT = (unsigned short*)P;
  unsigned short* W1P = (unsigned short*)(ws + 43974656);
  unsigned short* W2P = (unsigned short*)(ws + 43974656 + 131072);

  // Early bf16 frag packs: live in R head (T slot), dead before k_blur writes T.
  unsigned short* W1PA = (unsigned short*)R;   // 16384 sh
  unsigned short* W2PA = W1PA + 16384;         // 16384 sh
  unsigned short* WLAP = W1PA + 32768;         // 36864 sh
  unsigned short* F1P  = W1PA + 69632;         // 8192 sh (ends 77824 sh = 38912 f < 1048576)
  // GA-phase packs: R tail (after SG end 3686400), written post-MRA, inside E's dead zone.
  unsigned short* GWp = (unsigned short*)(R + 3686400);
  unsigned short* F2P = GWp;                   // 8192
  unsigned short* P1P = GWp + 8192;            // 4096
  unsigned short* C1P = GWp + 12288;           // 2048
  unsigned short* C2P = GWp + 14336;           // 2048
  unsigned short* CVP = GWp + 16384;           // 2048
  unsigned short* P2P = GWp + 18432;           // 4096 (ends 22528 sh = 11264 f)

  // Prep
  k_prep<<<1024, 256, 0, stream>>>(mlp_w1, mlp_bn_g, mlp_w2, n1_g, W1P, W2P);
  k_wprep<<<304, 256, 0, stream>>>(pa_w1, pa_bn_g, pa_w2, la_w, la_bn_g, fuse1_w,
                                   W1PA, W2PA, WLAP, F1P);
  // Branch 1 (PA): MFMA chained GEMMs
  k_pa<<<1152, 256, 0, stream>>>(x, W1PA, pa_bn_b, W2PA, P, XA);
  // Branch 2: fuse1 (MFMA) -> Q; la (MFMA implicit GEMM) -> xa ch 64..127
  k_cg<4, 2, 2><<<1152, 256, 0, stream>>>(P, x, 64, F1P, (const float*)nullptr, 0, Q, 9216);
  k_la<<<1536, 384, 0, stream>>>(Q, WLAP, la_bn_b, XA);
  // Branch 3 (MRA)
  k_maxpool3<<<36864, 256, 0, stream>>>(x, P);
  k_blur<<<4096, 256, 0, stream>>>(P, T);
  k_dw<<<4096, 256, 0, stream>>>(T, h1_w, (const float*)nullptr, D, 32, 32, 7, 3, 3, 1, 1, 0);
  k_dw<<<4096, 256, 0, stream>>>(T, v1_w, (const float*)nullptr, D, 32, 32, 3, 7, 1, 3, 1, 1);
  k_htrans<<<8064, 256, 0, stream>>>(T, E);
  k_dw<<<8064, 256, 0, stream>>>(E, h2_w, (const float*)nullptr, F, 32, 63, 7, 3, 3, 1, 1, 0);
  k_invh_add<<<4096, 256, 0, stream>>>(F, D);
  k_vtrans<<<8064, 256, 0, stream>>>(T, E);
  k_dw<<<8064, 256, 0, stream>>>(E, v2_w, (const float*)nullptr, F, 63, 32, 3, 7, 1, 3, 1, 0);
  k_invv_add<<<4096, 256, 0, stream>>>(F, D);
  k_gate<<<36864, 256, 0, stream>>>(D, x, mra_bn_g, mra_bn_b, P, XA);
  // Branch 4 (GA): all 1x1s via MFMA
  k_wprep2<<<88, 256, 0, stream>>>(fuse2_w, g_p1_w, g_c1_w, g_c2_w, g_cv_w, g_p2_w,
                                   F2P, P1P, C1P, C2P, CVP, P2P);
  k_cg<4, 2, 2><<<1152, 256, 0, stream>>>(P, x, 192, F2P, (const float*)nullptr, 0, Q, 9216);
  k_pool2<<<9216, 256, 0, stream>>>(Q, C48, IDX);
  k_cg<4, 2, 0><<<288, 256, 0, stream>>>(C48, (const float*)nullptr, 0, P1P, g_p1_b, 1, G, 2304);
  k_dw<<<9216, 256, 0, stream>>>(G, g_c0_w, g_c0_b, H2, 48, 48, 5, 5, 2, 2, 1, 0);
  k_dw<<<9216, 256, 0, stream>>>(H2, g_cs_w, g_cs_b, I2, 48, 48, 7, 7, 9, 9, 3, 0);
  k_cg<2, 2, 0><<<288, 256, 0, stream>>>(H2, (const float*)nullptr, 0, C1P, g_c1_b, 0, J, 2304);
  k_cg<2, 2, 0><<<288, 256, 0, stream>>>(I2, (const float*)nullptr, 0, C2P, g_c2_b, 0, K2, 2304);
  k_agg<<<144, 256, 0, stream>>>(J, K2, AGG);
  k_sq<<<288, 256, 0, stream>>>(AGG, g_sq_w, g_sq_b, SG);
  k_mix<<<4608, 256, 0, stream>>>(J, K2, SG, L);
  k_cg<4, 1, 0><<<288, 256, 0, stream>>>(L, (const float*)nullptr, 0, CVP, g_cv_b, 0, M, 2304);
  k_mul<<<9216, 256, 0, stream>>>(G, M, XM);
  k_cg<4, 2, 0><<<288, 256, 0, stream>>>(XM, (const float*)nullptr, 0, P2P, g_p2_b, 0, N2, 2304);
  k_unpool<<<36864, 256, 0, stream>>>(N2, IDX, x, n4_g, n4_b, XA);
  // Transpose xa -> pixel-major
  k_tr<<<9216, 256, 0, stream>>>((const unsigned short*)XA, XAT);
  // MLP + residual
  k_mlp_mfma<<<1152, 256, 0, stream>>>(XAT, W1P, mlp_bn_b, W2P, n1_b, x, (float*)d_out);
}

// Round 8
// 1220.825 us; speedup vs baseline: 1.3248x; 1.3248x over previous
//
#include <hip/hip_runtime.h>
#include <hip/hip_bf16.h>

typedef __hip_bfloat16 bf16;
typedef short bf16x8 __attribute__((ext_vector_type(8)));
typedef float f32x4 __attribute__((ext_vector_type(4)));

#define BNS 0.9999950000374997f  /* 1/sqrt(1+1e-5) */

// Fast erf: Abramowitz-Stegun 7.1.26, |err| <= 1.5e-7 (invisible vs bf16 rounding).
// ~15 VALU ops vs libm erff's ~30-40.
__device__ __forceinline__ float erf_fast(float x) {
  float ax = fabsf(x);
  float t = __builtin_amdgcn_rcpf(1.0f + 0.3275911f * ax);
  float p = t * (0.254829592f + t * (-0.284496736f + t * (1.421413741f
          + t * (-1.453152027f + t * 1.061405429f))));
  float r = 1.0f - p * __expf(-ax * ax);
  return copysignf(r, x);
}
__device__ __forceinline__ float geluf(float x) { return 0.5f * x * (1.0f + erf_fast(x * 0.70710678118654752f)); }
__device__ __forceinline__ float sigmf(float x) { return 1.0f / (1.0f + expf(-x)); }
__device__ __forceinline__ unsigned short f2b(float f) { bf16 h = __float2bfloat16(f); return *(unsigned short*)&h; }

// ============ weight prep #1: bf16 frag-linear packs (PA, LA, fuse1) ========================
// Generic frag layout: idx = ((kc*MT + mb)*64 + lane)*8 + j
//   m = mb*16 + (lane&15), k = kc*32 + (lane>>4)*8 + j
__global__ __launch_bounds__(256) void k_wprep(const float* __restrict__ pa_w1,
    const float* __restrict__ pa_g, const float* __restrict__ pa_w2,
    const float* __restrict__ la_w, const float* __restrict__ la_g,
    const float* __restrict__ f1w,
    unsigned short* __restrict__ W1PA, unsigned short* __restrict__ W2PA,
    unsigned short* __restrict__ WLAP, unsigned short* __restrict__ F1P) {
  int i = blockIdx.x * 256 + threadIdx.x;
  if (i < 16384) {
    int j = i & 7, lane = (i >> 3) & 63, q = i >> 9;
    int mb = q % 16, kc = q / 16;
    int m = mb * 16 + (lane & 15), k = kc * 32 + (lane >> 4) * 8 + j;
    W1PA[i] = f2b(pa_w1[m * 64 + k] * (pa_g[m] * BNS));
  } else if (i < 32768) {
    int ii = i - 16384;
    int j = ii & 7, lane = (ii >> 3) & 63, q = ii >> 9;
    int mb = q % 4, kc = q / 4;
    int m = mb * 16 + (lane & 15), k = kc * 32 + (lane >> 4) * 8 + j;
    W2PA[ii] = f2b(pa_w2[m * 256 + k]);
  } else if (i < 69632) {
    int ii = i - 32768;
    int j = ii & 7, lane = (ii >> 3) & 63, q = ii >> 9;
    int mb = q % 4, gk = q / 4;           // gk = tap*2 + kc2, tap = ky*3+kx
    int tap = gk >> 1, kc2 = gk & 1;
    int co = mb * 16 + (lane & 15), ci = kc2 * 32 + (lane >> 4) * 8 + j;
    WLAP[ii] = f2b(la_w[(co * 64 + ci) * 9 + tap] * (la_g[co] * BNS));
  } else if (i < 77824) {
    int ii = i - 69632;
    int j = ii & 7, lane = (ii >> 3) & 63, q = ii >> 9;
    int mb = q % 4, kc = q / 4;
    int m = mb * 16 + (lane & 15), k = kc * 32 + (lane >> 4) * 8 + j;
    F1P[ii] = f2b(f1w[m * 128 + k]);
  }
}

// ============ weight prep #2: GA-phase packs (after MRA frees R-tail) =======================
__global__ __launch_bounds__(256) void k_wprep2(const float* __restrict__ f2w,
    const float* __restrict__ p1w, const float* __restrict__ c1w,
    const float* __restrict__ c2w, const float* __restrict__ cvw,
    const float* __restrict__ p2w,
    unsigned short* __restrict__ F2P, unsigned short* __restrict__ P1P,
    unsigned short* __restrict__ C1P, unsigned short* __restrict__ C2P,
    unsigned short* __restrict__ CVP, unsigned short* __restrict__ P2P) {
  int i = blockIdx.x * 256 + threadIdx.x;
  if (i < 8192) {               // fuse2: MT=4, K=128
    int j = i & 7, lane = (i >> 3) & 63, q = i >> 9;
    int mb = q % 4, kc = q / 4;
    int m = mb * 16 + (lane & 15), k = kc * 32 + (lane >> 4) * 8 + j;
    F2P[i] = f2b(f2w[m * 128 + k]);
  } else if (i < 12288) {       // p1: MT=4, K=64
    int ii = i - 8192;
    int j = ii & 7, lane = (ii >> 3) & 63, q = ii >> 9;
    int mb = q % 4, kc = q / 4;
    int m = mb * 16 + (lane & 15), k = kc * 32 + (lane >> 4) * 8 + j;
    P1P[ii] = f2b(p1w[m * 64 + k]);
  } else if (i < 14336) {       // c1: MT=2, K=64
    int ii = i - 12288;
    int j = ii & 7, lane = (ii >> 3) & 63, q = ii >> 9;
    int mb = q % 2, kc = q / 2;
    int m = mb * 16 + (lane & 15), k = kc * 32 + (lane >> 4) * 8 + j;
    C1P[ii] = f2b(c1w[m * 64 + k]);
  } else if (i < 16384) {       // c2: MT=2, K=64
    int ii = i - 14336;
    int j = ii & 7, lane = (ii >> 3) & 63, q = ii >> 9;
    int mb = q % 2, kc = q / 2;
    int m = mb * 16 + (lane & 15), k = kc * 32 + (lane >> 4) * 8 + j;
    C2P[ii] = f2b(c2w[m * 64 + k]);
  } else if (i < 18432) {       // cv: MT=4, K=32
    int ii = i - 16384;
    int j = ii & 7, lane = (ii >> 3) & 63, q = ii >> 9;
    int mb = q % 4;             // kc = 0
    int m = mb * 16 + (lane & 15), k = (lane >> 4) * 8 + j;
    CVP[ii] = f2b(cvw[m * 32 + k]);
  } else if (i < 22528) {       // p2: MT=4, K=64
    int ii = i - 18432;
    int j = ii & 7, lane = (ii >> 3) & 63, q = ii >> 9;
    int mb = q % 4, kc = q / 4;
    int m = mb * 16 + (lane & 15), k = kc * 32 + (lane >> 4) * 8 + j;
    P2P[ii] = f2b(p2w[m * 64 + k]);
  }
}

// ============ PA branch v3: chained MFMA GEMMs (64 -> 256 gelu -> 64) =======================
// 1152 blocks x 256 thr. Block = 128 px; wave owns 32 px (2 n-tiles).
__global__ __launch_bounds__(256, 2) void k_pa(const float* __restrict__ x,
    const unsigned short* __restrict__ W1PA, const float* __restrict__ b1,
    const unsigned short* __restrict__ W2PA,
    float* __restrict__ x1pa, bf16* __restrict__ xa) {
  __shared__ unsigned short hs[128][40];
  __shared__ float b1s[256];
  int t = threadIdx.x;
  b1s[t] = b1[t];
  __syncthreads();
  int b = blockIdx.x / 72;
  int hw0 = (blockIdx.x % 72) * 128;
  int lane = t & 63, wave = t >> 6, lm = lane & 15, lk = lane >> 4;
  // GEMM1 B-frags: X1[ch=k][px=n], direct global f32 -> bf16
  bf16x8 Bf[2][2];   // [nt][ks]
  {
    const float* xb = x + (size_t)b * 256 * 9216 + hw0 + wave * 32 + lm;
#pragma unroll
    for (int nt = 0; nt < 2; ++nt)
#pragma unroll
      for (int ks = 0; ks < 2; ++ks)
#pragma unroll
        for (int j = 0; j < 8; ++j)
          Bf[nt][ks][j] = (short)f2b(xb[(size_t)(ks * 32 + lk * 8 + j) * 9216 + nt * 16]);
  }
  f32x4 Y[4][2];
#pragma unroll
  for (int i = 0; i < 4; ++i) { Y[i][0] = (f32x4){0,0,0,0}; Y[i][1] = (f32x4){0,0,0,0}; }

  for (int c = 0; c < 8; ++c) {   // hidden chunks of 32
    f32x4 Hc[2][2];
#pragma unroll
    for (int i = 0; i < 2; ++i) { Hc[i][0] = (f32x4){0,0,0,0}; Hc[i][1] = (f32x4){0,0,0,0}; }
#pragma unroll
    for (int ks = 0; ks < 2; ++ks)
#pragma unroll
      for (int mt = 0; mt < 2; ++mt) {
        bf16x8 a = *(const bf16x8*)(W1PA + ((size_t)((ks * 16 + c * 2 + mt) * 64 + lane) * 8));
        Hc[mt][0] = __builtin_amdgcn_mfma_f32_16x16x32_bf16(a, Bf[0][ks], Hc[mt][0], 0, 0, 0);
        Hc[mt][1] = __builtin_amdgcn_mfma_f32_16x16x32_bf16(a, Bf[1][ks], Hc[mt][1], 0, 0, 0);
      }
    // gelu(+bias) -> hs (wave-private rows)
#pragma unroll
    for (int mt = 0; mt < 2; ++mt)
#pragma unroll
      for (int nt = 0; nt < 2; ++nt)
#pragma unroll
        for (int r = 0; r < 4; r += 2) {
          int h = c * 32 + mt * 16 + lk * 4 + r;
          float v0 = geluf(Hc[mt][nt][r]     + b1s[h]);
          float v1 = geluf(Hc[mt][nt][r + 1] + b1s[h + 1]);
          unsigned u = (unsigned)f2b(v0) | ((unsigned)f2b(v1) << 16);
          *(unsigned*)&hs[wave * 32 + nt * 16 + lm][mt * 16 + lk * 4 + r] = u;
        }
    // GEMM2: accumulate Y over this chunk's K=32
    bf16x8 h0 = *(const bf16x8*)&hs[wave * 32 + lm][lk * 8];
    bf16x8 h1 = *(const bf16x8*)&hs[wave * 32 + 16 + lm][lk * 8];
#pragma unroll
    for (int mb = 0; mb < 4; ++mb) {
      bf16x8 a2 = *(const bf16x8*)(W2PA + ((size_t)((c * 4 + mb) * 64 + lane) * 8));
      Y[mb][0] = __builtin_amdgcn_mfma_f32_16x16x32_bf16(a2, h0, Y[mb][0], 0, 0, 0);
      Y[mb][1] = __builtin_amdgcn_mfma_f32_16x16x32_bf16(a2, h1, Y[mb][1], 0, 0, 0);
    }
  }
  // epilogue: sigmoid gate, write x1pa (f32) + xa ch0..63 (bf16)
#pragma unroll
  for (int mb = 0; mb < 4; ++mb)
#pragma unroll
    for (int nt = 0; nt < 2; ++nt)
#pragma unroll
      for (int r = 0; r < 4; ++r) {
        int co = mb * 16 + lk * 4 + r;
        int px = hw0 + wave * 32 + nt * 16 + lm;
        float x1v = x[((size_t)b * 256 + co) * 9216 + px];
        float pa = x1v * sigmf(Y[mb][nt][r]);
        x1pa[((size_t)b * 64 + co) * 9216 + px] = pa;
        xa[((size_t)b * 256 + co) * 9216 + px] = __float2bfloat16(x1v + pa);
      }
}

// ============ generic 1x1 MFMA conv =========================================================
// MT m-tiles (Cout = MT*16); K = (KCA+KCB)*32. Chunks [0,KCA) from inA (ch-major, CinA=KCA*32),
// chunks [KCA,..) from xsrc (256-ch x tensor) at channel xoff. Block = 128 px, 4 waves.
template<int MT, int KCA, int KCB>
__global__ __launch_bounds__(256, 2) void k_cg(const float* __restrict__ inA,
    const float* __restrict__ xsrc, int xoff,
    const unsigned short* __restrict__ wp, const float* __restrict__ bias, int act,
    float* __restrict__ out, int npix) {
  int t = threadIdx.x, lane = t & 63, wave = t >> 6, lm = lane & 15, lk = lane >> 4;
  int p0 = blockIdx.x * 128;
  int b = p0 / npix, hw0 = p0 % npix;
  f32x4 acc[MT][2];
#pragma unroll
  for (int i = 0; i < MT; ++i) { acc[i][0] = (f32x4){0,0,0,0}; acc[i][1] = (f32x4){0,0,0,0}; }
#pragma unroll
  for (int kc = 0; kc < KCA + KCB; ++kc) {
    bf16x8 bf[2];
#pragma unroll
    for (int nt = 0; nt < 2; ++nt) {
      if (kc < KCA) {
        const float* src = inA + ((size_t)b * (KCA * 32) + kc * 32 + lk * 8) * npix
                         + hw0 + wave * 32 + nt * 16 + lm;
#pragma unroll
        for (int j = 0; j < 8; ++j) bf[nt][j] = (short)f2b(src[(size_t)j * npix]);
      } else {
        const float* src = xsrc + ((size_t)b * 256 + xoff + (kc - KCA) * 32 + lk * 8) * 9216
                         + hw0 + wave * 32 + nt * 16 + lm;
#pragma unroll
        for (int j = 0; j < 8; ++j) bf[nt][j] = (short)f2b(src[(size_t)j * 9216]);
      }
    }
#pragma unroll
    for (int mb = 0; mb < MT; ++mb) {
      bf16x8 a = *(const bf16x8*)(wp + ((size_t)((kc * MT + mb) * 64 + lane) * 8));
      acc[mb][0] = __builtin_amdgcn_mfma_f32_16x16x32_bf16(a, bf[0], acc[mb][0], 0, 0, 0);
      acc[mb][1] = __builtin_amdgcn_mfma_f32_16x16x32_bf16(a, bf[1], acc[mb][1], 0, 0, 0);
    }
  }
#pragma unroll
  for (int mb = 0; mb < MT; ++mb)
#pragma unroll
    for (int nt = 0; nt < 2; ++nt)
#pragma unroll
      for (int r = 0; r < 4; ++r) {
        int c = mb * 16 + lk * 4 + r;
        float v = acc[mb][nt][r] + (bias ? bias[c] : 0.f);
        if (act) v = geluf(v);
        out[((size_t)b * (MT * 16) + c) * npix + hw0 + wave * 32 + nt * 16 + lm] = v;
      }
}

// ============ la v3: implicit-GEMM 3x3 conv 64->64 via 9 shifted 1x1s =======================
// 1536 blocks (b*96+py) x 384 thr (6 waves, wave = 16-px n-tile of the row). BN-g in WLAP.
__global__ __launch_bounds__(384, 2) void k_la(const float* __restrict__ Q,
    const unsigned short* __restrict__ WLAP, const float* __restrict__ bb,
    bf16* __restrict__ xa) {
  int py = blockIdx.x % 96, b = blockIdx.x / 96;
  int t = threadIdx.x, lane = t & 63, w = t >> 6, lm = lane & 15, lk = lane >> 4;
  int px = w * 16 + lm;
  f32x4 acc[4];
#pragma unroll
  for (int i = 0; i < 4; ++i) acc[i] = (f32x4){0,0,0,0};
#pragma unroll
  for (int ky = 0; ky < 3; ++ky) {
    int row = py + ky - 1;
    if ((unsigned)row >= 96u) continue;      // uniform: zero-pad row -> skip
#pragma unroll
    for (int kx = 0; kx < 3; ++kx) {
      int pxe = px + kx - 1;
      bool vld = (unsigned)pxe < 96u;        // per-lane horizontal pad
      int pxc = vld ? pxe : 0;
      const float* qb = Q + ((size_t)b * 64 + lk * 8) * 9216 + row * 96 + pxc;
#pragma unroll
      for (int kc = 0; kc < 2; ++kc) {
        bf16x8 bf;
#pragma unroll
        for (int j = 0; j < 8; ++j) {
          float v = vld ? qb[(size_t)(kc * 32 + j) * 9216] : 0.f;
          bf[j] = (short)f2b(v);
        }
        int gk = (ky * 3 + kx) * 2 + kc;
#pragma unroll
        for (int mb = 0; mb < 4; ++mb) {
          bf16x8 a = *(const bf16x8*)(WLAP + ((size_t)((gk * 4 + mb) * 64 + lane) * 8));
          acc[mb] = __builtin_amdgcn_mfma_f32_16x16x32_bf16(a, bf, acc[mb], 0, 0, 0);
        }
      }
    }
  }
#pragma unroll
  for (int mb = 0; mb < 4; ++mb)
#pragma unroll
    for (int r = 0; r < 4; ++r) {
      int co = mb * 16 + lk * 4 + r;
      float v = geluf(acc[mb][r] + bb[co]);
      xa[((size_t)b * 256 + 64 + co) * 9216 + py * 96 + px] = __float2bfloat16(v);
    }
}

// ---------------- maxpool3 -------------------------------------------------------------------
__global__ __launch_bounds__(256) void k_maxpool3(const float* __restrict__ x, float* __restrict__ out) {
  int idx = blockIdx.x * 256 + threadIdx.x;
  if (idx >= 16 * 64 * 9216) return;
  int wpx = idx % 96; int tmp = idx / 96; int h = tmp % 96; tmp /= 96; int c = tmp % 64; int b = tmp / 64;
  const float* src = x + (b * 256 + 128 + c) * 9216;
  float m = -3.4e38f;
  for (int dy = -1; dy <= 1; ++dy) {
    int y = h + dy; if ((unsigned)y >= 96u) continue;
    for (int dx = -1; dx <= 1; ++dx) {
      int xx = wpx + dx; if ((unsigned)xx >= 96u) continue;
      m = fmaxf(m, src[y * 96 + xx]);
    }
  }
  out[idx] = m;
}

// ---------------- blurpool -------------------------------------------------------------------
__global__ __launch_bounds__(256) void k_blur(const float* __restrict__ in, float* __restrict__ out) {
  int idx = blockIdx.x * 256 + threadIdx.x;
  if (idx >= 16 * 64 * 1024) return;
  int ow = idx % 32; int tmp = idx / 32; int oh = tmp % 32; int bc = tmp / 32;
  const float* src = in + bc * 9216;
  const float a4[4] = {1.f, 3.f, 3.f, 1.f};
  float s = 0.f;
  for (int ky = 0; ky < 4; ++ky) {
    int sy = 3 * oh + ky - 1; if (sy < 0) sy = -sy; if (sy > 95) sy = 190 - sy;
    for (int kx = 0; kx < 4; ++kx) {
      int sx = 3 * ow + kx - 1; if (sx < 0) sx = -sx; if (sx > 95) sx = 190 - sx;
      s += a4[ky] * a4[kx] * src[sy * 96 + sx];
    }
  }
  out[idx] = s * (1.0f / 64.0f);
}

// ---------------- generic depthwise conv ----------------------------------------------------
__global__ __launch_bounds__(256) void k_dw(const float* __restrict__ in, const float* __restrict__ w,
    const float* __restrict__ bias, float* __restrict__ out,
    int H, int W, int KH, int KW, int pH, int pW, int dil, int accf) {
  int idx = blockIdx.x * 256 + threadIdx.x;
  int total = 16 * 64 * H * W; if (idx >= total) return;
  int wpx = idx % W; int tmp = idx / W; int h = tmp % H; tmp /= H; int c = tmp % 64;
  const float* src = in + tmp * H * W;
  const float* wr = w + c * KH * KW;
  float a = bias ? bias[c] : 0.f;
  for (int ky = 0; ky < KH; ++ky) {
    int y = h - pH + ky * dil; if ((unsigned)y >= (unsigned)H) continue;
    for (int kx = 0; kx < KW; ++kx) {
      int xx = wpx - pW + kx * dil; if ((unsigned)xx >= (unsigned)W) continue;
      a += wr[ky * KW + kx] * src[y * W + xx];
    }
  }
  if (accf) out[idx] += a; else out[idx] = a;
}

// ---------------- shear transforms ----------------------------------------------------------
__global__ __launch_bounds__(256) void k_htrans(const float* __restrict__ in, float* __restrict__ out) {
  int idx = blockIdx.x * 256 + threadIdx.x;
  if (idx >= 16 * 64 * 32 * 63) return;
  int j = idx % 63; int tmp = idx / 63; int i = tmp % 32; int bc = tmp / 32;
  int k = j - i;
  out[idx] = (k >= 0 && k < 32) ? in[(bc * 32 + i) * 32 + k] : 0.f;
}
__global__ __launch_bounds__(256) void k_invh_add(const float* __restrict__ F, float* __restrict__ D) {
  int idx = blockIdx.x * 256 + threadIdx.x;
  if (idx >= 16 * 64 * 1024) return;
  int j = idx % 32; int tmp = idx / 32; int i = tmp % 32; int bc = tmp / 32;
  D[idx] += F[(bc * 32 + i) * 63 + i + j];
}
__global__ __launch_bounds__(256) void k_vtrans(const float* __restrict__ in, float* __restrict__ out) {
  int idx = blockIdx.x * 256 + threadIdx.x;
  if (idx >= 16 * 64 * 63 * 32) return;
  int c = idx % 32; int tmp = idx / 32; int r = tmp % 63; int bc = tmp / 63;
  int k = r - c;
  out[idx] = (k >= 0 && k < 32) ? in[(bc * 32 + k) * 32 + c] : 0.f;
}
__global__ __launch_bounds__(256) void k_invv_add(const float* __restrict__ F, float* __restrict__ D) {
  int idx = blockIdx.x * 256 + threadIdx.x;
  if (idx >= 16 * 64 * 1024) return;
  int j = idx % 32; int tmp = idx / 32; int i = tmp % 32; int bc = tmp / 32;
  D[idx] += F[(bc * 63 + (i + j)) * 32 + j];
}

// ---------------- gate ----------------------------------------------------------------------
__global__ __launch_bounds__(256) void k_gate(const float* __restrict__ D, const float* __restrict__ x,
    const float* __restrict__ g, const float* __restrict__ bb,
    float* __restrict__ mra_out, bf16* __restrict__ xa) {
  int idx = blockIdx.x * 256 + threadIdx.x;
  if (idx >= 16 * 64 * 9216) return;
  int wv = idx % 96; int tmp = idx / 96; int h = tmp % 96; tmp /= 96; int c = tmp % 64; int b = tmp / 64;
  float d = D[((b * 64 + c) * 32 + h / 3) * 32 + (wv / 3)];
  float gt = sigmf(d * g[c] * BNS + bb[c]);
  float x3v = x[(b * 256 + 128 + c) * 9216 + h * 96 + wv];
  float mra = x3v * gt;
  mra_out[idx] = mra;
  xa[(b * 256 + 128 + c) * 9216 + h * 96 + wv] = __float2bfloat16(x3v + mra);
}

// ---------------- maxpool2 with argmax ------------------------------------------------------
__global__ __launch_bounds__(256) void k_pool2(const float* __restrict__ in, float* __restrict__ out,
                                               int* __restrict__ idxo) {
  int idx = blockIdx.x * 256 + threadIdx.x;
  if (idx >= 16 * 64 * 2304) return;
  int ow = idx % 48; int tmp = idx / 48; int oh = tmp % 48; int bc = tmp / 48;
  const float* src = in + bc * 9216;
  int y = 2 * oh, xx = 2 * ow;
  float v0 = src[y * 96 + xx], v1 = src[y * 96 + xx + 1];
  float v2 = src[(y + 1) * 96 + xx], v3 = src[(y + 1) * 96 + xx + 1];
  float best = v0; int bi = 0;
  if (v1 > best) { best = v1; bi = 1; }
  if (v2 > best) { best = v2; bi = 2; }
  if (v3 > best) { best = v3; bi = 3; }
  out[idx] = best; idxo[idx] = bi;
}

// ---------------- channel mean/max ----------------------------------------------------------
__global__ __launch_bounds__(256) void k_agg(const float* __restrict__ J, const float* __restrict__ K,
                                             float* __restrict__ AGG) {
  int idx = blockIdx.x * 256 + threadIdx.x;
  if (idx >= 16 * 2304) return;
  int hw = idx % 2304; int b = idx / 2304;
  float sum = 0.f, mx = -3.4e38f;
  for (int j = 0; j < 32; ++j) { float v = J[(b * 32 + j) * 2304 + hw]; sum += v; mx = fmaxf(mx, v); }
  for (int j = 0; j < 32; ++j) { float v = K[(b * 32 + j) * 2304 + hw]; sum += v; mx = fmaxf(mx, v); }
  AGG[(b * 2 + 0) * 2304 + hw] = sum * (1.0f / 64.0f);
  AGG[(b * 2 + 1) * 2304 + hw] = mx;
}

// ---------------- squeeze conv 2->2 7x7 pad3 + sigmoid --------------------------------------
__global__ __launch_bounds__(256) void k_sq(const float* __restrict__ AGG, const float* __restrict__ w,
                                            const float* __restrict__ bias, float* __restrict__ SG) {
  int idx = blockIdx.x * 256 + threadIdx.x;
  if (idx >= 16 * 2 * 2304) return;
  int hw = idx % 2304; int tmp = idx / 2304; int co = tmp % 2; int b = tmp / 2;
  int h = hw / 48, wv = hw % 48;
  float acc = bias[co];
  for (int ci = 0; ci < 2; ++ci) {
    const float* src = AGG + (b * 2 + ci) * 2304;
    for (int ky = 0; ky < 7; ++ky) {
      int y = h - 3 + ky; if ((unsigned)y >= 48u) continue;
      for (int kx = 0; kx < 7; ++kx) {
        int xx = wv - 3 + kx; if ((unsigned)xx >= 48u) continue;
        acc += w[((co * 2 + ci) * 7 + ky) * 7 + kx] * src[y * 48 + xx];
      }
    }
  }
  SG[idx] = sigmf(acc);
}

__global__ __launch_bounds__(256) void k_mix(const float* __restrict__ J, const float* __restrict__ K,
                                             const float* __restrict__ SG, float* __restrict__ L) {
  int idx = blockIdx.x * 256 + threadIdx.x;
  if (idx >= 16 * 32 * 2304) return;
  int hw = idx % 2304; int tmp = idx / 2304; int b = tmp / 32;
  L[idx] = J[idx] * SG[(b * 2) * 2304 + hw] + K[idx] * SG[(b * 2 + 1) * 2304 + hw];
}

__global__ __launch_bounds__(256) void k_mul(const float* __restrict__ A, const float* __restrict__ B,
                                             float* __restrict__ O) {
  int idx = blockIdx.x * 256 + threadIdx.x;
  if (idx >= 16 * 64 * 2304) return;
  O[idx] = A[idx] * B[idx];
}

// ---------------- unpool + bn(n4), xa ch192..255 --------------------------------------------
__global__ __launch_bounds__(256) void k_unpool(const float* __restrict__ N2, const int* __restrict__ IDX,
    const float* __restrict__ x, const float* __restrict__ g, const float* __restrict__ bb,
    bf16* __restrict__ xa) {
  int idx = blockIdx.x * 256 + threadIdx.x;
  if (idx >= 16 * 64 * 9216) return;
  int wv = idx % 96; int tmp = idx / 96; int h = tmp % 96; tmp /= 96; int c = tmp % 64; int b = tmp / 64;
  int oh = h >> 1, ow = wv >> 1;
  int pos = (b * 64 + c) * 2304 + oh * 48 + ow;
  int kk = (h & 1) * 2 + (wv & 1);
  float v = (IDX[pos] == kk) ? N2[pos] : 0.f;
  float x4v = x[(b * 256 + 192 + c) * 9216 + h * 96 + wv];
  xa[(b * 256 + 192 + c) * 9216 + h * 96 + wv] =
      __float2bfloat16((x4v + v) * g[c] * BNS + bb[c]);
}

// ---------------- transpose XA (ch-major bf16) -> XAT (pixel-major bf16) --------------------
__global__ __launch_bounds__(256) void k_tr(const unsigned short* __restrict__ XA,
                                            unsigned short* __restrict__ XAT) {
  __shared__ unsigned s[64][65];
  int t = threadIdx.x;
  int bid = blockIdx.x;
  int ct = bid & 3;
  int pt = (bid >> 2) % 144;
  int b = (bid >> 2) / 144;
  int c0 = ct * 64, p0 = pt * 64;
  for (int i = t; i < 4096; i += 256) {
    int cl = i >> 6, pl = i & 63;
    s[cl][pl] = XA[(size_t)(b * 256 + c0 + cl) * 9216 + p0 + pl];
  }
  __syncthreads();
  for (int i = t; i < 4096; i += 256) {
    int pl = i >> 6, cl = i & 63;
    XAT[((size_t)(b * 9216 + p0 + pl) << 8) + c0 + cl] = (unsigned short)s[cl][pl];
  }
}

// ---------------- prep: MLP weights frag-linear, bf16, BN scales folded ---------------------
__global__ __launch_bounds__(256) void k_prep(const float* __restrict__ w1, const float* __restrict__ g1,
    const float* __restrict__ w2, const float* __restrict__ ng,
    unsigned short* __restrict__ w1p, unsigned short* __restrict__ w2p) {
  int i = blockIdx.x * 256 + threadIdx.x;
  if (i >= 262144) return;
  {
    int j = i & 7, lane = (i >> 3) & 63, ks = (i >> 9) & 7, mb = i >> 12;
    int h = mb * 16 + (lane & 15);
    int k = ks * 32 + (lane >> 4) * 8 + j;
    w1p[i] = f2b(w1[h * 256 + k] * (g1[h] * BNS));
  }
  {
    int j = i & 7, lane = (i >> 3) & 63, mb = (i >> 9) & 15, c = i >> 13;
    int m = mb * 16 + (lane & 15);
    int k = c * 32 + (lane >> 4) * 8 + j;
    w2p[i] = f2b(w2[m * 1024 + k] * (ng[m] * BNS));
  }
}

// ---------------- fused MFMA MLP (round-5 structure, known-good): W staged in LDS -----------
__global__ __launch_bounds__(256, 2) void k_mlp_mfma(
    const unsigned short* __restrict__ XAT,
    const unsigned short* __restrict__ W1P, const float* __restrict__ b1,
    const unsigned short* __restrict__ W2P, const float* __restrict__ nbv,
    const float* __restrict__ xin, float* __restrict__ out) {
  __shared__ uint4 w1c4[1024];
  __shared__ uint4 w2c4[1024];
  __shared__ unsigned short hs[128][56];
  __shared__ float b1s[1024];
  __shared__ float nbs[256];
  unsigned short* w1c = (unsigned short*)w1c4;
  unsigned short* w2c = (unsigned short*)w2c4;
  int t = threadIdx.x;
  int b = blockIdx.x / 72;
  int hw0 = (blockIdx.x % 72) * 128;
  for (int i = t; i < 1024; i += 256) b1s[i] = b1[i];
  nbs[t] = nbv[t];
  int lane = t & 63, wave = t >> 6;
  int lm = lane & 15, lk = lane >> 4;
  bf16x8 Bf[2][8];
  {
    const unsigned short* base = XAT + ((size_t)(b * 9216 + hw0 + wave * 32 + lm) << 8) + lk * 8;
#pragma unroll
    for (int nt2 = 0; nt2 < 2; ++nt2)
#pragma unroll
      for (int ks = 0; ks < 8; ++ks)
        Bf[nt2][ks] = *(const bf16x8*)(base + nt2 * 16 * 256 + ks * 32);
  }
  f32x4 Y[16][2];
#pragma unroll
  for (int i = 0; i < 16; ++i) { Y[i][0] = (f32x4){0,0,0,0}; Y[i][1] = (f32x4){0,0,0,0}; }

  const uint4* g1p = (const uint4*)W1P;
  const uint4* g2p = (const uint4*)W2P;
  for (int c = 0; c < 32; ++c) {
    __syncthreads();
#pragma unroll
    for (int i = 0; i < 4; ++i) {
      int o = i * 256 + t;
      w1c4[o] = g1p[c * 1024 + o];
      w2c4[o] = g2p[c * 1024 + o];
    }
    __syncthreads();
    f32x4 Hc[2][2];
#pragma unroll
    for (int i = 0; i < 2; ++i) { Hc[i][0] = (f32x4){0,0,0,0}; Hc[i][1] = (f32x4){0,0,0,0}; }
#pragma unroll
    for (int ks = 0; ks < 8; ++ks) {
      bf16x8 a0 = *(const bf16x8*)&w1c[(ks * 64 + lane) * 8];
      bf16x8 a1 = *(const bf16x8*)&w1c[((8 + ks) * 64 + lane) * 8];
      Hc[0][0] = __builtin_amdgcn_mfma_f32_16x16x32_bf16(a0, Bf[0][ks], Hc[0][0], 0, 0, 0);
      Hc[0][1] = __builtin_amdgcn_mfma_f32_16x16x32_bf16(a0, Bf[1][ks], Hc[0][1], 0, 0, 0);
      Hc[1][0] = __builtin_amdgcn_mfma_f32_16x16x32_bf16(a1, Bf[0][ks], Hc[1][0], 0, 0, 0);
      Hc[1][1] = __builtin_amdgcn_mfma_f32_16x16x32_bf16(a1, Bf[1][ks], Hc[1][1], 0, 0, 0);
    }
#pragma unroll
    for (int mbl = 0; mbl < 2; ++mbl)
#pragma unroll
      for (int nt2 = 0; nt2 < 2; ++nt2)
#pragma unroll
        for (int r = 0; r < 4; r += 2) {
          int h = c * 32 + mbl * 16 + lk * 4 + r;
          float v0 = geluf(Hc[mbl][nt2][r]     + b1s[h]);
          float v1 = geluf(Hc[mbl][nt2][r + 1] + b1s[h + 1]);
          unsigned u = (unsigned)f2b(v0) | ((unsigned)f2b(v1) << 16);
          *(unsigned*)&hs[wave * 32 + nt2 * 16 + lm][mbl * 16 + lk * 4 + r] = u;
        }
    bf16x8 h0 = *(const bf16x8*)&hs[wave * 32 + lm][lk * 8];
    bf16x8 h1 = *(const bf16x8*)&hs[wave * 32 + 16 + lm][lk * 8];
#pragma unroll
    for (int mb = 0; mb < 16; ++mb) {
      bf16x8 a = *(const bf16x8*)&w2c[(mb * 64 + lane) * 8];
      Y[mb][0] = __builtin_amdgcn_mfma_f32_16x16x32_bf16(a, h0, Y[mb][0], 0, 0, 0);
      Y[mb][1] = __builtin_amdgcn_mfma_f32_16x16x32_bf16(a, h1, Y[mb][1], 0, 0, 0);
    }
  }
#pragma unroll
  for (int mb = 0; mb < 16; ++mb)
#pragma unroll
    for (int nt2 = 0; nt2 < 2; ++nt2)
#pragma unroll
      for (int r = 0; r < 4; ++r) {
        int m = mb * 16 + lk * 4 + r;
        size_t o = (size_t)(b * 256 + m) * 9216 + hw0 + wave * 32 + nt2 * 16 + lm;
        out[o] = Y[mb][nt2][r] + nbs[m] + xin[o];
      }
}

extern "C" void kernel_launch(void* const* d_in, const int* in_sizes, int n_in,
                              void* d_out, int out_size, void* d_ws, size_t ws_size,
                              hipStream_t stream) {
  const float* x        = (const float*)d_in[0];
  const float* pa_w1    = (const float*)d_in[1];
  const float* pa_bn_g  = (const float*)d_in[2];
  const float* pa_bn_b  = (const float*)d_in[3];
  const float* pa_w2    = (const float*)d_in[4];
  const float* fuse1_w  = (const float*)d_in[5];
  const float* la_w     = (const float*)d_in[6];
  const float* la_bn_g  = (const float*)d_in[7];
  const float* la_bn_b  = (const float*)d_in[8];
  const float* h1_w     = (const float*)d_in[9];
  const float* v1_w     = (const float*)d_in[10];
  const float* h2_w     = (const float*)d_in[11];
  const float* v2_w     = (const float*)d_in[12];
  const float* mra_bn_g = (const float*)d_in[13];
  const float* mra_bn_b = (const float*)d_in[14];
  const float* fuse2_w  = (const float*)d_in[15];
  const float* g_p1_w   = (const float*)d_in[16];
  const float* g_p1_b   = (const float*)d_in[17];
  const float* g_c0_w   = (const float*)d_in[18];
  const float* g_c0_b   = (const float*)d_in[19];
  const float* g_cs_w   = (const float*)d_in[20];
  const float* g_cs_b   = (const float*)d_in[21];
  const float* g_c1_w   = (const float*)d_in[22];
  const float* g_c1_b   = (const float*)d_in[23];
  const float* g_c2_w   = (const float*)d_in[24];
  const float* g_c2_b   = (const float*)d_in[25];
  const float* g_sq_w   = (const float*)d_in[26];
  const float* g_sq_b   = (const float*)d_in[27];
  const float* g_cv_w   = (const float*)d_in[28];
  const float* g_cv_b   = (const float*)d_in[29];
  const float* g_p2_w   = (const float*)d_in[30];
  const float* g_p2_b   = (const float*)d_in[31];
  const float* n4_g     = (const float*)d_in[32];
  const float* n4_b     = (const float*)d_in[33];
  const float* mlp_w1   = (const float*)d_in[34];
  const float* mlp_bn_g = (const float*)d_in[35];
  const float* mlp_bn_b = (const float*)d_in[36];
  const float* mlp_w2   = (const float*)d_in[37];
  const float* n1_g     = (const float*)d_in[38];
  const float* n1_b     = (const float*)d_in[39];

  // ---- aliased workspace: 44,236,800 floats = 176.9 MB ----
  float* ws = (float*)d_ws;
  bf16*  XA = (bf16*)ws;                    // (16,256,96,96) bf16 = 18,874,368 f-slots
  float* P  = ws + 18874368;                // 9,437,184 f
  float* Q  = ws + 28311552;                // 9,437,184 f
  float* R  = ws + 37748736;                // 6,225,920 f
  float* T  = R;
  float* D  = R + 1048576;
  float* E  = R + 2097152;
  float* F  = R + 4161536;
  float* C48 = P;
  int*   IDX = (int*)(P + 2359296);
  float* G   = P + 4718592;
  float* H2  = P + 7077888;
  float* I2  = Q;
  float* M   = Q + 2359296;
  float* XM  = Q + 4718592;
  float* N2  = Q + 7077888;
  float* J   = R;
  float* K2  = R + 1179648;
  float* L   = R + 2359296;
  float* AGG = R + 3538944;
  float* SG  = R + 3612672;
  unsigned short* XAT = (unsigned short*)P;
  unsigned short* W1P = (unsigned short*)(ws + 43974656);
  unsigned short* W2P = (unsigned short*)(ws + 43974656 + 131072);

  // Early bf16 frag packs: live in R head (T slot), dead before k_blur writes T.
  unsigned short* W1PA = (unsigned short*)R;   // 16384 sh
  unsigned short* W2PA = W1PA + 16384;         // 16384 sh
  unsigned short* WLAP = W1PA + 32768;         // 36864 sh
  unsigned short* F1P  = W1PA + 69632;         // 8192 sh (ends 77824 sh = 38912 f < 1048576)
  // GA-phase packs: R tail (after SG end 3686400), written post-MRA, inside E's dead zone.
  unsigned short* GWp = (unsigned short*)(R + 3686400);
  unsigned short* F2P = GWp;                   // 8192
  unsigned short* P1P = GWp + 8192;            // 4096
  unsigned short* C1P = GWp + 12288;           // 2048
  unsigned short* C2P = GWp + 14336;           // 2048
  unsigned short* CVP = GWp + 16384;           // 2048
  unsigned short* P2P = GWp + 18432;           // 4096 (ends 22528 sh = 11264 f)

  // Prep
  k_prep<<<1024, 256, 0, stream>>>(mlp_w1, mlp_bn_g, mlp_w2, n1_g, W1P, W2P);
  k_wprep<<<304, 256, 0, stream>>>(pa_w1, pa_bn_g, pa_w2, la_w, la_bn_g, fuse1_w,
                                   W1PA, W2PA, WLAP, F1P);
  // Branch 1 (PA): MFMA chained GEMMs
  k_pa<<<1152, 256, 0, stream>>>(x, W1PA, pa_bn_b, W2PA, P, XA);
  // Branch 2: fuse1 (MFMA) -> Q; la (MFMA implicit GEMM) -> xa ch 64..127
  k_cg<4, 2, 2><<<1152, 256, 0, stream>>>(P, x, 64, F1P, (const float*)nullptr, 0, Q, 9216);
  k_la<<<1536, 384, 0, stream>>>(Q, WLAP, la_bn_b, XA);
  // Branch 3 (MRA)
  k_maxpool3<<<36864, 256, 0, stream>>>(x, P);
  k_blur<<<4096, 256, 0, stream>>>(P, T);
  k_dw<<<4096, 256, 0, stream>>>(T, h1_w, (const float*)nullptr, D, 32, 32, 7, 3, 3, 1, 1, 0);
  k_dw<<<4096, 256, 0, stream>>>(T, v1_w, (const float*)nullptr, D, 32, 32, 3, 7, 1, 3, 1, 1);
  k_htrans<<<8064, 256, 0, stream>>>(T, E);
  k_dw<<<8064, 256, 0, stream>>>(E, h2_w, (const float*)nullptr, F, 32, 63, 7, 3, 3, 1, 1, 0);
  k_invh_add<<<4096, 256, 0, stream>>>(F, D);
  k_vtrans<<<8064, 256, 0, stream>>>(T, E);
  k_dw<<<8064, 256, 0, stream>>>(E, v2_w, (const float*)nullptr, F, 63, 32, 3, 7, 1, 3, 1, 0);
  k_invv_add<<<4096, 256, 0, stream>>>(F, D);
  k_gate<<<36864, 256, 0, stream>>>(D, x, mra_bn_g, mra_bn_b, P, XA);
  // Branch 4 (GA): all 1x1s via MFMA
  k_wprep2<<<88, 256, 0, stream>>>(fuse2_w, g_p1_w, g_c1_w, g_c2_w, g_cv_w, g_p2_w,
                                   F2P, P1P, C1P, C2P, CVP, P2P);
  k_cg<4, 2, 2><<<1152, 256, 0, stream>>>(P, x, 192, F2P, (const float*)nullptr, 0, Q, 9216);
  k_pool2<<<9216, 256, 0, stream>>>(Q, C48, IDX);
  k_cg<4, 2, 0><<<288, 256, 0, stream>>>(C48, (const float*)nullptr, 0, P1P, g_p1_b, 1, G, 2304);
  k_dw<<<9216, 256, 0, stream>>>(G, g_c0_w, g_c0_b, H2, 48, 48, 5, 5, 2, 2, 1, 0);
  k_dw<<<9216, 256, 0, stream>>>(H2, g_cs_w, g_cs_b, I2, 48, 48, 7, 7, 9, 9, 3, 0);
  k_cg<2, 2, 0><<<288, 256, 0, stream>>>(H2, (const float*)nullptr, 0, C1P, g_c1_b, 0, J, 2304);
  k_cg<2, 2, 0><<<288, 256, 0, stream>>>(I2, (const float*)nullptr, 0, C2P, g_c2_b, 0, K2, 2304);
  k_agg<<<144, 256, 0, stream>>>(J, K2, AGG);
  k_sq<<<288, 256, 0, stream>>>(AGG, g_sq_w, g_sq_b, SG);
  k_mix<<<4608, 256, 0, stream>>>(J, K2, SG, L);
  k_cg<4, 1, 0><<<288, 256, 0, stream>>>(L, (const float*)nullptr, 0, CVP, g_cv_b, 0, M, 2304);
  k_mul<<<9216, 256, 0, stream>>>(G, M, XM);
  k_cg<4, 2, 0><<<288, 256, 0, stream>>>(XM, (const float*)nullptr, 0, P2P, g_p2_b, 0, N2, 2304);
  k_unpool<<<36864, 256, 0, stream>>>(N2, IDX, x, n4_g, n4_b, XA);
  // Transpose xa -> pixel-major
  k_tr<<<9216, 256, 0, stream>>>((const unsigned short*)XA, XAT);
  // MLP + residual
  k_mlp_mfma<<<1152, 256, 0, stream>>>(XAT, W1P, mlp_bn_b, W2P, n1_b, x, (float*)d_out);
}

// Round 13
// 1197.987 us; speedup vs baseline: 1.3501x; 1.0191x over previous
//
#include <hip/hip_runtime.h>
#include <hip/hip_bf16.h>

typedef __hip_bfloat16 bf16;
typedef short bf16x8 __attribute__((ext_vector_type(8)));
typedef float f32x4 __attribute__((ext_vector_type(4)));

#define BNS 0.9999950000374997f  /* 1/sqrt(1+1e-5) */

// Fast erf: Abramowitz-Stegun 7.1.26, |err| <= 1.5e-7 (invisible vs bf16 rounding).
__device__ __forceinline__ float erf_fast(float x) {
  float ax = fabsf(x);
  float t = __builtin_amdgcn_rcpf(1.0f + 0.3275911f * ax);
  float p = t * (0.254829592f + t * (-0.284496736f + t * (1.421413741f
          + t * (-1.453152027f + t * 1.061405429f))));
  float r = 1.0f - p * __expf(-ax * ax);
  return copysignf(r, x);
}
__device__ __forceinline__ float geluf(float x) { return 0.5f * x * (1.0f + erf_fast(x * 0.70710678118654752f)); }
__device__ __forceinline__ float sigmf(float x) { return 1.0f / (1.0f + expf(-x)); }
__device__ __forceinline__ unsigned short f2b(float f) { bf16 h = __float2bfloat16(f); return *(unsigned short*)&h; }

// async global->LDS, 16B per lane (linear per-wave mapping required)
__device__ __forceinline__ void gload_lds16(const void* g, void* l) {
  __builtin_amdgcn_global_load_lds(
      (const __attribute__((address_space(1))) void*)g,
      (__attribute__((address_space(3))) void*)l, 16, 0, 0);
}

// ============ weight prep #1: bf16 frag-linear packs (PA, LA, fuse1) ========================
// Generic frag layout: idx = ((kc*MT + mb)*64 + lane)*8 + j
//   m = mb*16 + (lane&15), k = kc*32 + (lane>>4)*8 + j
__global__ __launch_bounds__(256) void k_wprep(const float* __restrict__ pa_w1,
    const float* __restrict__ pa_g, const float* __restrict__ pa_w2,
    const float* __restrict__ la_w, const float* __restrict__ la_g,
    const float* __restrict__ f1w,
    unsigned short* __restrict__ W1PA, unsigned short* __restrict__ W2PA,
    unsigned short* __restrict__ WLAP, unsigned short* __restrict__ F1P) {
  int i = blockIdx.x * 256 + threadIdx.x;
  if (i < 16384) {
    int j = i & 7, lane = (i >> 3) & 63, q = i >> 9;
    int mb = q % 16, kc = q / 16;
    int m = mb * 16 + (lane & 15), k = kc * 32 + (lane >> 4) * 8 + j;
    W1PA[i] = f2b(pa_w1[m * 64 + k] * (pa_g[m] * BNS));
  } else if (i < 32768) {
    int ii = i - 16384;
    int j = ii & 7, lane = (ii >> 3) & 63, q = ii >> 9;
    int mb = q % 4, kc = q / 4;
    int m = mb * 16 + (lane & 15), k = kc * 32 + (lane >> 4) * 8 + j;
    W2PA[ii] = f2b(pa_w2[m * 256 + k]);
  } else if (i < 69632) {
    int ii = i - 32768;
    int j = ii & 7, lane = (ii >> 3) & 63, q = ii >> 9;
    int mb = q % 4, gk = q / 4;           // gk = tap*2 + kc2, tap = ky*3+kx
    int tap = gk >> 1, kc2 = gk & 1;
    int co = mb * 16 + (lane & 15), ci = kc2 * 32 + (lane >> 4) * 8 + j;
    WLAP[ii] = f2b(la_w[(co * 64 + ci) * 9 + tap] * (la_g[co] * BNS));
  } else if (i < 77824) {
    int ii = i - 69632;
    int j = ii & 7, lane = (ii >> 3) & 63, q = ii >> 9;
    int mb = q % 4, kc = q / 4;
    int m = mb * 16 + (lane & 15), k = kc * 32 + (lane >> 4) * 8 + j;
    F1P[ii] = f2b(f1w[m * 128 + k]);
  }
}

// ============ weight prep #2: GA-phase packs (after MRA frees R-tail) =======================
__global__ __launch_bounds__(256) void k_wprep2(const float* __restrict__ f2w,
    const float* __restrict__ p1w, const float* __restrict__ c1w,
    const float* __restrict__ c2w, const float* __restrict__ cvw,
    const float* __restrict__ p2w,
    unsigned short* __restrict__ F2P, unsigned short* __restrict__ P1P,
    unsigned short* __restrict__ C1P, unsigned short* __restrict__ C2P,
    unsigned short* __restrict__ CVP, unsigned short* __restrict__ P2P) {
  int i = blockIdx.x * 256 + threadIdx.x;
  if (i < 8192) {               // fuse2: MT=4, K=128
    int j = i & 7, lane = (i >> 3) & 63, q = i >> 9;
    int mb = q % 4, kc = q / 4;
    int m = mb * 16 + (lane & 15), k = kc * 32 + (lane >> 4) * 8 + j;
    F2P[i] = f2b(f2w[m * 128 + k]);
  } else if (i < 12288) {       // p1: MT=4, K=64
    int ii = i - 8192;
    int j = ii & 7, lane = (ii >> 3) & 63, q = ii >> 9;
    int mb = q % 4, kc = q / 4;
    int m = mb * 16 + (lane & 15), k = kc * 32 + (lane >> 4) * 8 + j;
    P1P[ii] = f2b(p1w[m * 64 + k]);
  } else if (i < 14336) {       // c1: MT=2, K=64
    int ii = i - 12288;
    int j = ii & 7, lane = (ii >> 3) & 63, q = ii >> 9;
    int mb = q % 2, kc = q / 2;
    int m = mb * 16 + (lane & 15), k = kc * 32 + (lane >> 4) * 8 + j;
    C1P[ii] = f2b(c1w[m * 64 + k]);
  } else if (i < 16384) {       // c2: MT=2, K=64
    int ii = i - 14336;
    int j = ii & 7, lane = (ii >> 3) & 63, q = ii >> 9;
    int mb = q % 2, kc = q / 2;
    int m = mb * 16 + (lane & 15), k = kc * 32 + (lane >> 4) * 8 + j;
    C2P[ii] = f2b(c2w[m * 64 + k]);
  } else if (i < 18432) {       // cv: MT=4, K=32
    int ii = i - 16384;
    int j = ii & 7, lane = (ii >> 3) & 63, q = ii >> 9;
    int mb = q % 4;             // kc = 0
    int m = mb * 16 + (lane & 15), k = (lane >> 4) * 8 + j;
    CVP[ii] = f2b(cvw[m * 32 + k]);
  } else if (i < 22528) {       // p2: MT=4, K=64
    int ii = i - 18432;
    int j = ii & 7, lane = (ii >> 3) & 63, q = ii >> 9;
    int mb = q % 4, kc = q / 4;
    int m = mb * 16 + (lane & 15), k = kc * 32 + (lane >> 4) * 8 + j;
    P2P[ii] = f2b(p2w[m * 64 + k]);
  }
}

// ============ PA branch v3: chained MFMA GEMMs (64 -> 256 gelu -> 64) =======================
__global__ __launch_bounds__(256, 2) void k_pa(const float* __restrict__ x,
    const unsigned short* __restrict__ W1PA, const float* __restrict__ b1,
    const unsigned short* __restrict__ W2PA,
    float* __restrict__ x1pa, bf16* __restrict__ xa) {
  __shared__ unsigned short hs[128][40];
  __shared__ float b1s[256];
  int t = threadIdx.x;
  b1s[t] = b1[t];
  __syncthreads();
  int b = blockIdx.x / 72;
  int hw0 = (blockIdx.x % 72) * 128;
  int lane = t & 63, wave = t >> 6, lm = lane & 15, lk = lane >> 4;
  bf16x8 Bf[2][2];   // [nt][ks]
  {
    const float* xb = x + (size_t)b * 256 * 9216 + hw0 + wave * 32 + lm;
#pragma unroll
    for (int nt = 0; nt < 2; ++nt)
#pragma unroll
      for (int ks = 0; ks < 2; ++ks)
#pragma unroll
        for (int j = 0; j < 8; ++j)
          Bf[nt][ks][j] = (short)f2b(xb[(size_t)(ks * 32 + lk * 8 + j) * 9216 + nt * 16]);
  }
  f32x4 Y[4][2];
#pragma unroll
  for (int i = 0; i < 4; ++i) { Y[i][0] = (f32x4){0,0,0,0}; Y[i][1] = (f32x4){0,0,0,0}; }

  for (int c = 0; c < 8; ++c) {   // hidden chunks of 32
    f32x4 Hc[2][2];
#pragma unroll
    for (int i = 0; i < 2; ++i) { Hc[i][0] = (f32x4){0,0,0,0}; Hc[i][1] = (f32x4){0,0,0,0}; }
#pragma unroll
    for (int ks = 0; ks < 2; ++ks)
#pragma unroll
      for (int mt = 0; mt < 2; ++mt) {
        bf16x8 a = *(const bf16x8*)(W1PA + ((size_t)((ks * 16 + c * 2 + mt) * 64 + lane) * 8));
        Hc[mt][0] = __builtin_amdgcn_mfma_f32_16x16x32_bf16(a, Bf[0][ks], Hc[mt][0], 0, 0, 0);
        Hc[mt][1] = __builtin_amdgcn_mfma_f32_16x16x32_bf16(a, Bf[1][ks], Hc[mt][1], 0, 0, 0);
      }
#pragma unroll
    for (int mt = 0; mt < 2; ++mt)
#pragma unroll
      for (int nt = 0; nt < 2; ++nt)
#pragma unroll
        for (int r = 0; r < 4; r += 2) {
          int h = c * 32 + mt * 16 + lk * 4 + r;
          float v0 = geluf(Hc[mt][nt][r]     + b1s[h]);
          float v1 = geluf(Hc[mt][nt][r + 1] + b1s[h + 1]);
          unsigned u = (unsigned)f2b(v0) | ((unsigned)f2b(v1) << 16);
          *(unsigned*)&hs[wave * 32 + nt * 16 + lm][mt * 16 + lk * 4 + r] = u;
        }
    bf16x8 h0 = *(const bf16x8*)&hs[wave * 32 + lm][lk * 8];
    bf16x8 h1 = *(const bf16x8*)&hs[wave * 32 + 16 + lm][lk * 8];
#pragma unroll
    for (int mb = 0; mb < 4; ++mb) {
      bf16x8 a2 = *(const bf16x8*)(W2PA + ((size_t)((c * 4 + mb) * 64 + lane) * 8));
      Y[mb][0] = __builtin_amdgcn_mfma_f32_16x16x32_bf16(a2, h0, Y[mb][0], 0, 0, 0);
      Y[mb][1] = __builtin_amdgcn_mfma_f32_16x16x32_bf16(a2, h1, Y[mb][1], 0, 0, 0);
    }
  }
#pragma unroll
  for (int mb = 0; mb < 4; ++mb)
#pragma unroll
    for (int nt = 0; nt < 2; ++nt)
#pragma unroll
      for (int r = 0; r < 4; ++r) {
        int co = mb * 16 + lk * 4 + r;
        int px = hw0 + wave * 32 + nt * 16 + lm;
        float x1v = x[((size_t)b * 256 + co) * 9216 + px];
        float pa = x1v * sigmf(Y[mb][nt][r]);
        x1pa[((size_t)b * 64 + co) * 9216 + px] = pa;
        xa[((size_t)b * 256 + co) * 9216 + px] = __float2bfloat16(x1v + pa);
      }
}

// ============ generic 1x1 MFMA conv =========================================================
template<int MT, int KCA, int KCB>
__global__ __launch_bounds__(256, 2) void k_cg(const float* __restrict__ inA,
    const float* __restrict__ xsrc, int xoff,
    const unsigned short* __restrict__ wp, const float* __restrict__ bias, int act,
    float* __restrict__ out, int npix) {
  int t = threadIdx.x, lane = t & 63, wave = t >> 6, lm = lane & 15, lk = lane >> 4;
  int p0 = blockIdx.x * 128;
  int b = p0 / npix, hw0 = p0 % npix;
  f32x4 acc[MT][2];
#pragma unroll
  for (int i = 0; i < MT; ++i) { acc[i][0] = (f32x4){0,0,0,0}; acc[i][1] = (f32x4){0,0,0,0}; }
#pragma unroll
  for (int kc = 0; kc < KCA + KCB; ++kc) {
    bf16x8 bf[2];
#pragma unroll
    for (int nt = 0; nt < 2; ++nt) {
      if (kc < KCA) {
        const float* src = inA + ((size_t)b * (KCA * 32) + kc * 32 + lk * 8) * npix
                         + hw0 + wave * 32 + nt * 16 + lm;
#pragma unroll
        for (int j = 0; j < 8; ++j) bf[nt][j] = (short)f2b(src[(size_t)j * npix]);
      } else {
        const float* src = xsrc + ((size_t)b * 256 + xoff + (kc - KCA) * 32 + lk * 8) * 9216
                         + hw0 + wave * 32 + nt * 16 + lm;
#pragma unroll
        for (int j = 0; j < 8; ++j) bf[nt][j] = (short)f2b(src[(size_t)j * 9216]);
      }
    }
#pragma unroll
    for (int mb = 0; mb < MT; ++mb) {
      bf16x8 a = *(const bf16x8*)(wp + ((size_t)((kc * MT + mb) * 64 + lane) * 8));
      acc[mb][0] = __builtin_amdgcn_mfma_f32_16x16x32_bf16(a, bf[0], acc[mb][0], 0, 0, 0);
      acc[mb][1] = __builtin_amdgcn_mfma_f32_16x16x32_bf16(a, bf[1], acc[mb][1], 0, 0, 0);
    }
  }
#pragma unroll
  for (int mb = 0; mb < MT; ++mb)
#pragma unroll
    for (int nt = 0; nt < 2; ++nt)
#pragma unroll
      for (int r = 0; r < 4; ++r) {
        int c = mb * 16 + lk * 4 + r;
        float v = acc[mb][nt][r] + (bias ? bias[c] : 0.f);
        if (act) v = geluf(v);
        out[((size_t)b * (MT * 16) + c) * npix + hw0 + wave * 32 + nt * 16 + lm] = v;
      }
}

// ============ la v3: implicit-GEMM 3x3 conv 64->64 via 9 shifted 1x1s =======================
__global__ __launch_bounds__(384, 2) void k_la(const float* __restrict__ Q,
    const unsigned short* __restrict__ WLAP, const float* __restrict__ bb,
    bf16* __restrict__ xa) {
  int py = blockIdx.x % 96, b = blockIdx.x / 96;
  int t = threadIdx.x, lane = t & 63, w = t >> 6, lm = lane & 15, lk = lane >> 4;
  int px = w * 16 + lm;
  f32x4 acc[4];
#pragma unroll
  for (int i = 0; i < 4; ++i) acc[i] = (f32x4){0,0,0,0};
#pragma unroll
  for (int ky = 0; ky < 3; ++ky) {
    int row = py + ky - 1;
    if ((unsigned)row >= 96u) continue;
#pragma unroll
    for (int kx = 0; kx < 3; ++kx) {
      int pxe = px + kx - 1;
      bool vld = (unsigned)pxe < 96u;
      int pxc = vld ? pxe : 0;
      const float* qb = Q + ((size_t)b * 64 + lk * 8) * 9216 + row * 96 + pxc;
#pragma unroll
      for (int kc = 0; kc < 2; ++kc) {
        bf16x8 bf;
#pragma unroll
        for (int j = 0; j < 8; ++j) {
          float v = vld ? qb[(size_t)(kc * 32 + j) * 9216] : 0.f;
          bf[j] = (short)f2b(v);
        }
        int gk = (ky * 3 + kx) * 2 + kc;
#pragma unroll
        for (int mb = 0; mb < 4; ++mb) {
          bf16x8 a = *(const bf16x8*)(WLAP + ((size_t)((gk * 4 + mb) * 64 + lane) * 8));
          acc[mb] = __builtin_amdgcn_mfma_f32_16x16x32_bf16(a, bf, acc[mb], 0, 0, 0);
        }
      }
    }
  }
#pragma unroll
  for (int mb = 0; mb < 4; ++mb)
#pragma unroll
    for (int r = 0; r < 4; ++r) {
      int co = mb * 16 + lk * 4 + r;
      float v = geluf(acc[mb][r] + bb[co]);
      xa[((size_t)b * 256 + 64 + co) * 9216 + py * 96 + px] = __float2bfloat16(v);
    }
}

// ---------------- maxpool3 -------------------------------------------------------------------
__global__ __launch_bounds__(256) void k_maxpool3(const float* __restrict__ x, float* __restrict__ out) {
  int idx = blockIdx.x * 256 + threadIdx.x;
  if (idx >= 16 * 64 * 9216) return;
  int wpx = idx % 96; int tmp = idx / 96; int h = tmp % 96; tmp /= 96; int c = tmp % 64; int b = tmp / 64;
  const float* src = x + (b * 256 + 128 + c) * 9216;
  float m = -3.4e38f;
  for (int dy = -1; dy <= 1; ++dy) {
    int y = h + dy; if ((unsigned)y >= 96u) continue;
    for (int dx = -1; dx <= 1; ++dx) {
      int xx = wpx + dx; if ((unsigned)xx >= 96u) continue;
      m = fmaxf(m, src[y * 96 + xx]);
    }
  }
  out[idx] = m;
}

// ---------------- blurpool -------------------------------------------------------------------
__global__ __launch_bounds__(256) void k_blur(const float* __restrict__ in, float* __restrict__ out) {
  int idx = blockIdx.x * 256 + threadIdx.x;
  if (idx >= 16 * 64 * 1024) return;
  int ow = idx % 32; int tmp = idx / 32; int oh = tmp % 32; int bc = tmp / 32;
  const float* src = in + bc * 9216;
  const float a4[4] = {1.f, 3.f, 3.f, 1.f};
  float s = 0.f;
  for (int ky = 0; ky < 4; ++ky) {
    int sy = 3 * oh + ky - 1; if (sy < 0) sy = -sy; if (sy > 95) sy = 190 - sy;
    for (int kx = 0; kx < 4; ++kx) {
      int sx = 3 * ow + kx - 1; if (sx < 0) sx = -sx; if (sx > 95) sx = 190 - sx;
      s += a4[ky] * a4[kx] * src[sy * 96 + sx];
    }
  }
  out[idx] = s * (1.0f / 64.0f);
}

// ---------------- generic depthwise conv ----------------------------------------------------
__global__ __launch_bounds__(256) void k_dw(const float* __restrict__ in, const float* __restrict__ w,
    const float* __restrict__ bias, float* __restrict__ out,
    int H, int W, int KH, int KW, int pH, int pW, int dil, int accf) {
  int idx = blockIdx.x * 256 + threadIdx.x;
  int total = 16 * 64 * H * W; if (idx >= total) return;
  int wpx = idx % W; int tmp = idx / W; int h = tmp % H; tmp /= H; int c = tmp % 64;
  const float* src = in + tmp * H * W;
  const float* wr = w + c * KH * KW;
  float a = bias ? bias[c] : 0.f;
  for (int ky = 0; ky < KH; ++ky) {
    int y = h - pH + ky * dil; if ((unsigned)y >= (unsigned)H) continue;
    for (int kx = 0; kx < KW; ++kx) {
      int xx = wpx - pW + kx * dil; if ((unsigned)xx >= (unsigned)W) continue;
      a += wr[ky * KW + kx] * src[y * W + xx];
    }
  }
  if (accf) out[idx] += a; else out[idx] = a;
}

// ---------------- shear transforms ----------------------------------------------------------
__global__ __launch_bounds__(256) void k_htrans(const float* __restrict__ in, float* __restrict__ out) {
  int idx = blockIdx.x * 256 + threadIdx.x;
  if (idx >= 16 * 64 * 32 * 63) return;
  int j = idx % 63; int tmp = idx / 63; int i = tmp % 32; int bc = tmp / 32;
  int k = j - i;
  out[idx] = (k >= 0 && k < 32) ? in[(bc * 32 + i) * 32 + k] : 0.f;
}
__global__ __launch_bounds__(256) void k_invh_add(const float* __restrict__ F, float* __restrict__ D) {
  int idx = blockIdx.x * 256 + threadIdx.x;
  if (idx >= 16 * 64 * 1024) return;
  int j = idx % 32; int tmp = idx / 32; int i = tmp % 32; int bc = tmp / 32;
  D[idx] += F[(bc * 32 + i) * 63 + i + j];
}
__global__ __launch_bounds__(256) void k_vtrans(const float* __restrict__ in, float* __restrict__ out) {
  int idx = blockIdx.x * 256 + threadIdx.x;
  if (idx >= 16 * 64 * 63 * 32) return;
  int c = idx % 32; int tmp = idx / 32; int r = tmp % 63; int bc = tmp / 63;
  int k = r - c;
  out[idx] = (k >= 0 && k < 32) ? in[(bc * 32 + k) * 32 + c] : 0.f;
}
__global__ __launch_bounds__(256) void k_invv_add(const float* __restrict__ F, float* __restrict__ D) {
  int idx = blockIdx.x * 256 + threadIdx.x;
  if (idx >= 16 * 64 * 1024) return;
  int j = idx % 32; int tmp = idx / 32; int i = tmp % 32; int bc = tmp / 32;
  D[idx] += F[(bc * 63 + (i + j)) * 32 + j];
}

// ---------------- gate ----------------------------------------------------------------------
__global__ __launch_bounds__(256) void k_gate(const float* __restrict__ D, const float* __restrict__ x,
    const float* __restrict__ g, const float* __restrict__ bb,
    float* __restrict__ mra_out, bf16* __restrict__ xa) {
  int idx = blockIdx.x * 256 + threadIdx.x;
  if (idx >= 16 * 64 * 9216) return;
  int wv = idx % 96; int tmp = idx / 96; int h = tmp % 96; tmp /= 96; int c = tmp % 64; int b = tmp / 64;
  float d = D[((b * 64 + c) * 32 + h / 3) * 32 + (wv / 3)];
  float gt = sigmf(d * g[c] * BNS + bb[c]);
  float x3v = x[(b * 256 + 128 + c) * 9216 + h * 96 + wv];
  float mra = x3v * gt;
  mra_out[idx] = mra;
  xa[(b * 256 + 128 + c) * 9216 + h * 96 + wv] = __float2bfloat16(x3v + mra);
}

// ---------------- maxpool2 with argmax ------------------------------------------------------
__global__ __launch_bounds__(256) void k_pool2(const float* __restrict__ in, float* __restrict__ out,
                                               int* __restrict__ idxo) {
  int idx = blockIdx.x * 256 + threadIdx.x;
  if (idx >= 16 * 64 * 2304) return;
  int ow = idx % 48; int tmp = idx / 48; int oh = tmp % 48; int bc = tmp / 48;
  const float* src = in + bc * 9216;
  int y = 2 * oh, xx = 2 * ow;
  float v0 = src[y * 96 + xx], v1 = src[y * 96 + xx + 1];
  float v2 = src[(y + 1) * 96 + xx], v3 = src[(y + 1) * 96 + xx + 1];
  float best = v0; int bi = 0;
  if (v1 > best) { best = v1; bi = 1; }
  if (v2 > best) { best = v2; bi = 2; }
  if (v3 > best) { best = v3; bi = 3; }
  out[idx] = best; idxo[idx] = bi;
}

// ---------------- channel mean/max ----------------------------------------------------------
__global__ __launch_bounds__(256) void k_agg(const float* __restrict__ J, const float* __restrict__ K,
                                             float* __restrict__ AGG) {
  int idx = blockIdx.x * 256 + threadIdx.x;
  if (idx >= 16 * 2304) return;
  int hw = idx % 2304; int b = idx / 2304;
  float sum = 0.f, mx = -3.4e38f;
  for (int j = 0; j < 32; ++j) { float v = J[(b * 32 + j) * 2304 + hw]; sum += v; mx = fmaxf(mx, v); }
  for (int j = 0; j < 32; ++j) { float v = K[(b * 32 + j) * 2304 + hw]; sum += v; mx = fmaxf(mx, v); }
  AGG[(b * 2 + 0) * 2304 + hw] = sum * (1.0f / 64.0f);
  AGG[(b * 2 + 1) * 2304 + hw] = mx;
}

// ---------------- squeeze conv 2->2 7x7 pad3 + sigmoid --------------------------------------
__global__ __launch_bounds__(256) void k_sq(const float* __restrict__ AGG, const float* __restrict__ w,
                                            const float* __restrict__ bias, float* __restrict__ SG) {
  int idx = blockIdx.x * 256 + threadIdx.x;
  if (idx >= 16 * 2 * 2304) return;
  int hw = idx % 2304; int tmp = idx / 2304; int co = tmp % 2; int b = tmp / 2;
  int h = hw / 48, wv = hw % 48;
  float acc = bias[co];
  for (int ci = 0; ci < 2; ++ci) {
    const float* src = AGG + (b * 2 + ci) * 2304;
    for (int ky = 0; ky < 7; ++ky) {
      int y = h - 3 + ky; if ((unsigned)y >= 48u) continue;
      for (int kx = 0; kx < 7; ++kx) {
        int xx = wv - 3 + kx; if ((unsigned)xx >= 48u) continue;
        acc += w[((co * 2 + ci) * 7 + ky) * 7 + kx] * src[y * 48 + xx];
      }
    }
  }
  SG[idx] = sigmf(acc);
}

__global__ __launch_bounds__(256) void k_mix(const float* __restrict__ J, const float* __restrict__ K,
                                             const float* __restrict__ SG, float* __restrict__ L) {
  int idx = blockIdx.x * 256 + threadIdx.x;
  if (idx >= 16 * 32 * 2304) return;
  int hw = idx % 2304; int tmp = idx / 2304; int b = tmp / 32;
  L[idx] = J[idx] * SG[(b * 2) * 2304 + hw] + K[idx] * SG[(b * 2 + 1) * 2304 + hw];
}

__global__ __launch_bounds__(256) void k_mul(const float* __restrict__ A, const float* __restrict__ B,
                                             float* __restrict__ O) {
  int idx = blockIdx.x * 256 + threadIdx.x;
  if (idx >= 16 * 64 * 2304) return;
  O[idx] = A[idx] * B[idx];
}

// ---------------- unpool + bn(n4), xa ch192..255 --------------------------------------------
__global__ __launch_bounds__(256) void k_unpool(const float* __restrict__ N2, const int* __restrict__ IDX,
    const float* __restrict__ x, const float* __restrict__ g, const float* __restrict__ bb,
    bf16* __restrict__ xa) {
  int idx = blockIdx.x * 256 + threadIdx.x;
  if (idx >= 16 * 64 * 9216) return;
  int wv = idx % 96; int tmp = idx / 96; int h = tmp % 96; tmp /= 96; int c = tmp % 64; int b = tmp / 64;
  int oh = h >> 1, ow = wv >> 1;
  int pos = (b * 64 + c) * 2304 + oh * 48 + ow;
  int kk = (h & 1) * 2 + (wv & 1);
  float v = (IDX[pos] == kk) ? N2[pos] : 0.f;
  float x4v = x[(b * 256 + 192 + c) * 9216 + h * 96 + wv];
  xa[(b * 256 + 192 + c) * 9216 + h * 96 + wv] =
      __float2bfloat16((x4v + v) * g[c] * BNS + bb[c]);
}

// ---------------- transpose XA (ch-major bf16) -> XAT (pixel-major bf16) --------------------
__global__ __launch_bounds__(256) void k_tr(const unsigned short* __restrict__ XA,
                                            unsigned short* __restrict__ XAT) {
  __shared__ unsigned s[64][65];
  int t = threadIdx.x;
  int bid = blockIdx.x;
  int ct = bid & 3;
  int pt = (bid >> 2) % 144;
  int b = (bid >> 2) / 144;
  int c0 = ct * 64, p0 = pt * 64;
  for (int i = t; i < 4096; i += 256) {
    int cl = i >> 6, pl = i & 63;
    s[cl][pl] = XA[(size_t)(b * 256 + c0 + cl) * 9216 + p0 + pl];
  }
  __syncthreads();
  for (int i = t; i < 4096; i += 256) {
    int pl = i >> 6, cl = i & 63;
    XAT[((size_t)(b * 9216 + p0 + pl) << 8) + c0 + cl] = (unsigned short)s[cl][pl];
  }
}

// ---------------- prep: MLP weights frag-linear, bf16, BN scales folded ---------------------
__global__ __launch_bounds__(256) void k_prep(const float* __restrict__ w1, const float* __restrict__ g1,
    const float* __restrict__ w2, const float* __restrict__ ng,
    unsigned short* __restrict__ w1p, unsigned short* __restrict__ w2p) {
  int i = blockIdx.x * 256 + threadIdx.x;
  if (i >= 262144) return;
  {
    int j = i & 7, lane = (i >> 3) & 63, ks = (i >> 9) & 7, mb = i >> 12;
    int h = mb * 16 + (lane & 15);
    int k = ks * 32 + (lane >> 4) * 8 + j;
    w1p[i] = f2b(w1[h * 256 + k] * (g1[h] * BNS));
  }
  {
    int j = i & 7, lane = (i >> 3) & 63, mb = (i >> 9) & 15, c = i >> 13;
    int m = mb * 16 + (lane & 15);
    int k = c * 32 + (lane >> 4) * 8 + j;
    w2p[i] = f2b(w2[m * 1024 + k] * (ng[m] * BNS));
  }
}

// ---------------- fused MFMA MLP v4: 2-chunk stage per barrier-pair via global_load_lds -----
// 16 barrier-pairs instead of 32; staging has no VGPR roundtrip (async direct-to-LDS).
// LDS: w1c4[2048](32K) + w2c4[2048](32K) + hs[128][40](10.25K) + b1s(4K) + nbs(1K) = 80,896 B
// -> 2 blocks/CU (161,792 <= 163,840).
__global__ __launch_bounds__(256, 2) void k_mlp_mfma(
    const unsigned short* __restrict__ XAT,
    const unsigned short* __restrict__ W1P, const float* __restrict__ b1,
    const unsigned short* __restrict__ W2P, const float* __restrict__ nbv,
    const float* __restrict__ xin, float* __restrict__ out) {
  __shared__ uint4 w1c4[2048];             // 2 chunk-buffers
  __shared__ uint4 w2c4[2048];
  __shared__ unsigned short hs[128][40];   // stride 80B = 5x16B (aligned b128 reads)
  __shared__ float b1s[1024];
  __shared__ float nbs[256];
  unsigned short* w1c = (unsigned short*)w1c4;
  unsigned short* w2c = (unsigned short*)w2c4;
  int t = threadIdx.x;
  int b = blockIdx.x / 72;
  int hw0 = (blockIdx.x % 72) * 128;
  for (int i = t; i < 1024; i += 256) b1s[i] = b1[i];
  nbs[t] = nbv[t];
  int lane = t & 63, wave = t >> 6;
  int lm = lane & 15, lk = lane >> 4;
  bf16x8 Bf[2][8];
  {
    const unsigned short* base = XAT + ((size_t)(b * 9216 + hw0 + wave * 32 + lm) << 8) + lk * 8;
#pragma unroll
    for (int nt2 = 0; nt2 < 2; ++nt2)
#pragma unroll
      for (int ks = 0; ks < 8; ++ks)
        Bf[nt2][ks] = *(const bf16x8*)(base + nt2 * 16 * 256 + ks * 32);
  }
  f32x4 Y[16][2];
#pragma unroll
  for (int i = 0; i < 16; ++i) { Y[i][0] = (f32x4){0,0,0,0}; Y[i][1] = (f32x4){0,0,0,0}; }

  const uint4* g1p = (const uint4*)W1P;
  const uint4* g2p = (const uint4*)W2P;
  for (int p = 0; p < 16; ++p) {
    __syncthreads();  // previous pair's LDS reads complete before overwrite
    // stage chunks 2p (buf0) and 2p+1 (buf1): async global->LDS, linear per-wave mapping
#pragma unroll
    for (int i = 0; i < 4; ++i) {
      int o = i * 256 + t;
      gload_lds16(&g1p[(2 * p) * 1024 + o],     &w1c4[o]);
      gload_lds16(&g1p[(2 * p + 1) * 1024 + o], &w1c4[1024 + o]);
      gload_lds16(&g2p[(2 * p) * 1024 + o],     &w2c4[o]);
      gload_lds16(&g2p[(2 * p + 1) * 1024 + o], &w2c4[1024 + o]);
    }
    __syncthreads();  // vmcnt(0) drain + barrier: both buffers ready
#pragma unroll
    for (int sub = 0; sub < 2; ++sub) {
      int cc = 2 * p + sub;
      int wo = sub * 8192;   // shorts offset of this chunk's buffer
      f32x4 Hc[2][2];
#pragma unroll
      for (int i = 0; i < 2; ++i) { Hc[i][0] = (f32x4){0,0,0,0}; Hc[i][1] = (f32x4){0,0,0,0}; }
#pragma unroll
      for (int ks = 0; ks < 8; ++ks) {
        bf16x8 a0 = *(const bf16x8*)&w1c[wo + (ks * 64 + lane) * 8];
        bf16x8 a1 = *(const bf16x8*)&w1c[wo + ((8 + ks) * 64 + lane) * 8];
        Hc[0][0] = __builtin_amdgcn_mfma_f32_16x16x32_bf16(a0, Bf[0][ks], Hc[0][0], 0, 0, 0);
        Hc[0][1] = __builtin_amdgcn_mfma_f32_16x16x32_bf16(a0, Bf[1][ks], Hc[0][1], 0, 0, 0);
        Hc[1][0] = __builtin_amdgcn_mfma_f32_16x16x32_bf16(a1, Bf[0][ks], Hc[1][0], 0, 0, 0);
        Hc[1][1] = __builtin_amdgcn_mfma_f32_16x16x32_bf16(a1, Bf[1][ks], Hc[1][1], 0, 0, 0);
      }
#pragma unroll
      for (int mbl = 0; mbl < 2; ++mbl)
#pragma unroll
        for (int nt2 = 0; nt2 < 2; ++nt2)
#pragma unroll
          for (int r = 0; r < 4; r += 2) {
            int h = cc * 32 + mbl * 16 + lk * 4 + r;
            float v0 = geluf(Hc[mbl][nt2][r]     + b1s[h]);
            float v1 = geluf(Hc[mbl][nt2][r + 1] + b1s[h + 1]);
            unsigned u = (unsigned)f2b(v0) | ((unsigned)f2b(v1) << 16);
            *(unsigned*)&hs[wave * 32 + nt2 * 16 + lm][mbl * 16 + lk * 4 + r] = u;
          }
      bf16x8 h0 = *(const bf16x8*)&hs[wave * 32 + lm][lk * 8];
      bf16x8 h1 = *(const bf16x8*)&hs[wave * 32 + 16 + lm][lk * 8];
#pragma unroll
      for (int mb = 0; mb < 16; ++mb) {
        bf16x8 a = *(const bf16x8*)&w2c[wo + (mb * 64 + lane) * 8];
        Y[mb][0] = __builtin_amdgcn_mfma_f32_16x16x32_bf16(a, h0, Y[mb][0], 0, 0, 0);
        Y[mb][1] = __builtin_amdgcn_mfma_f32_16x16x32_bf16(a, h1, Y[mb][1], 0, 0, 0);
      }
    }
  }
#pragma unroll
  for (int mb = 0; mb < 16; ++mb)
#pragma unroll
    for (int nt2 = 0; nt2 < 2; ++nt2)
#pragma unroll
      for (int r = 0; r < 4; ++r) {
        int m = mb * 16 + lk * 4 + r;
        size_t o = (size_t)(b * 256 + m) * 9216 + hw0 + wave * 32 + nt2 * 16 + lm;
        out[o] = Y[mb][nt2][r] + nbs[m] + xin[o];
      }
}

extern "C" void kernel_launch(void* const* d_in, const int* in_sizes, int n_in,
                              void* d_out, int out_size, void* d_ws, size_t ws_size,
                              hipStream_t stream) {
  const float* x        = (const float*)d_in[0];
  const float* pa_w1    = (const float*)d_in[1];
  const float* pa_bn_g  = (const float*)d_in[2];
  const float* pa_bn_b  = (const float*)d_in[3];
  const float* pa_w2    = (const float*)d_in[4];
  const float* fuse1_w  = (const float*)d_in[5];
  const float* la_w     = (const float*)d_in[6];
  const float* la_bn_g  = (const float*)d_in[7];
  const float* la_bn_b  = (const float*)d_in[8];
  const float* h1_w     = (const float*)d_in[9];
  const float* v1_w     = (const float*)d_in[10];
  const float* h2_w     = (const float*)d_in[11];
  const float* v2_w     = (const float*)d_in[12];
  const float* mra_bn_g = (const float*)d_in[13];
  const float* mra_bn_b = (const float*)d_in[14];
  const float* fuse2_w  = (const float*)d_in[15];
  const float* g_p1_w   = (const float*)d_in[16];
  const float* g_p1_b   = (const float*)d_in[17];
  const float* g_c0_w   = (const float*)d_in[18];
  const float* g_c0_b   = (const float*)d_in[19];
  const float* g_cs_w   = (const float*)d_in[20];
  const float* g_cs_b   = (const float*)d_in[21];
  const float* g_c1_w   = (const float*)d_in[22];
  const float* g_c1_b   = (const float*)d_in[23];
  const float* g_c2_w   = (const float*)d_in[24];
  const float* g_c2_b   = (const float*)d_in[25];
  const float* g_sq_w   = (const float*)d_in[26];
  const float* g_sq_b   = (const float*)d_in[27];
  const float* g_cv_w   = (const float*)d_in[28];
  const float* g_cv_b   = (const float*)d_in[29];
  const float* g_p2_w   = (const float*)d_in[30];
  const float* g_p2_b   = (const float*)d_in[31];
  const float* n4_g     = (const float*)d_in[32];
  const float* n4_b     = (const float*)d_in[33];
  const float* mlp_w1   = (const float*)d_in[34];
  const float* mlp_bn_g = (const float*)d_in[35];
  const float* mlp_bn_b = (const float*)d_in[36];
  const float* mlp_w2   = (const float*)d_in[37];
  const float* n1_g     = (const float*)d_in[38];
  const float* n1_b     = (const float*)d_in[39];

  // ---- aliased workspace: 44,236,800 floats = 176.9 MB ----
  float* ws = (float*)d_ws;
  bf16*  XA = (bf16*)ws;                    // (16,256,96,96) bf16 = 18,874,368 f-slots
  float* P  = ws + 18874368;                // 9,437,184 f
  float* Q  = ws + 28311552;                // 9,437,184 f
  float* R  = ws + 37748736;                // 6,225,920 f
  float* T  = R;
  float* D  = R + 1048576;
  float* E  = R + 2097152;
  float* F  = R + 4161536;
  float* C48 = P;
  int*   IDX = (int*)(P + 2359296);
  float* G   = P + 4718592;
  float* H2  = P + 7077888;
  float* I2  = Q;
  float* M   = Q + 2359296;
  float* XM  = Q + 4718592;
  float* N2  = Q + 7077888;
  float* J   = R;
  float* K2  = R + 1179648;
  float* L   = R + 2359296;
  float* AGG = R + 3538944;
  float* SG  = R + 3612672;
  unsigned short* XAT = (unsigned short*)P;
  unsigned short* W1P = (unsigned short*)(ws + 43974656);
  unsigned short* W2P = (unsigned short*)(ws + 43974656 + 131072);

  // Early bf16 frag packs: live in R head (T slot), dead before k_blur writes T.
  unsigned short* W1PA = (unsigned short*)R;   // 16384 sh
  unsigned short* W2PA = W1PA + 16384;         // 16384 sh
  unsigned short* WLAP = W1PA + 32768;         // 36864 sh
  unsigned short* F1P  = W1PA + 69632;         // 8192 sh (ends 77824 sh = 38912 f < 1048576)
  // GA-phase packs: R tail (after SG end 3686400), written post-MRA, inside E's dead zone.
  unsigned short* GWp = (unsigned short*)(R + 3686400);
  unsigned short* F2P = GWp;                   // 8192
  unsigned short* P1P = GWp + 8192;            // 4096
  unsigned short* C1P = GWp + 12288;           // 2048
  unsigned short* C2P = GWp + 14336;           // 2048
  unsigned short* CVP = GWp + 16384;           // 2048
  unsigned short* P2P = GWp + 18432;           // 4096 (ends 22528 sh = 11264 f)

  // Prep
  k_prep<<<1024, 256, 0, stream>>>(mlp_w1, mlp_bn_g, mlp_w2, n1_g, W1P, W2P);
  k_wprep<<<304, 256, 0, stream>>>(pa_w1, pa_bn_g, pa_w2, la_w, la_bn_g, fuse1_w,
                                   W1PA, W2PA, WLAP, F1P);
  // Branch 1 (PA): MFMA chained GEMMs
  k_pa<<<1152, 256, 0, stream>>>(x, W1PA, pa_bn_b, W2PA, P, XA);
  // Branch 2: fuse1 (MFMA) -> Q; la (MFMA implicit GEMM) -> xa ch 64..127
  k_cg<4, 2, 2><<<1152, 256, 0, stream>>>(P, x, 64, F1P, (const float*)nullptr, 0, Q, 9216);
  k_la<<<1536, 384, 0, stream>>>(Q, WLAP, la_bn_b, XA);
  // Branch 3 (MRA)
  k_maxpool3<<<36864, 256, 0, stream>>>(x, P);
  k_blur<<<4096, 256, 0, stream>>>(P, T);
  k_dw<<<4096, 256, 0, stream>>>(T, h1_w, (const float*)nullptr, D, 32, 32, 7, 3, 3, 1, 1, 0);
  k_dw<<<4096, 256, 0, stream>>>(T, v1_w, (const float*)nullptr, D, 32, 32, 3, 7, 1, 3, 1, 1);
  k_htrans<<<8064, 256, 0, stream>>>(T, E);
  k_dw<<<8064, 256, 0, stream>>>(E, h2_w, (const float*)nullptr, F, 32, 63, 7, 3, 3, 1, 1, 0);
  k_invh_add<<<4096, 256, 0, stream>>>(F, D);
  k_vtrans<<<8064, 256, 0, stream>>>(T, E);
  k_dw<<<8064, 256, 0, stream>>>(E, v2_w, (const float*)nullptr, F, 63, 32, 3, 7, 1, 3, 1, 0);
  k_invv_add<<<4096, 256, 0, stream>>>(F, D);
  k_gate<<<36864, 256, 0, stream>>>(D, x, mra_bn_g, mra_bn_b, P, XA);
  // Branch 4 (GA): all 1x1s via MFMA
  k_wprep2<<<88, 256, 0, stream>>>(fuse2_w, g_p1_w, g_c1_w, g_c2_w, g_cv_w, g_p2_w,
                                   F2P, P1P, C1P, C2P, CVP, P2P);
  k_cg<4, 2, 2><<<1152, 256, 0, stream>>>(P, x, 192, F2P, (const float*)nullptr, 0, Q, 9216);
  k_pool2<<<9216, 256, 0, stream>>>(Q, C48, IDX);
  k_cg<4, 2, 0><<<288, 256, 0, stream>>>(C48, (const float*)nullptr, 0, P1P, g_p1_b, 1, G, 2304);
  k_dw<<<9216, 256, 0, stream>>>(G, g_c0_w, g_c0_b, H2, 48, 48, 5, 5, 2, 2, 1, 0);
  k_dw<<<9216, 256, 0, stream>>>(H2, g_cs_w, g_cs_b, I2, 48, 48, 7, 7, 9, 9, 3, 0);
  k_cg<2, 2, 0><<<288, 256, 0, stream>>>(H2, (const float*)nullptr, 0, C1P, g_c1_b, 0, J, 2304);
  k_cg<2, 2, 0><<<288, 256, 0, stream>>>(I2, (const float*)nullptr, 0, C2P, g_c2_b, 0, K2, 2304);
  k_agg<<<144, 256, 0, stream>>>(J, K2, AGG);
  k_sq<<<288, 256, 0, stream>>>(AGG, g_sq_w, g_sq_b, SG);
  k_mix<<<4608, 256, 0, stream>>>(J, K2, SG, L);
  k_cg<4, 1, 0><<<288, 256, 0, stream>>>(L, (const float*)nullptr, 0, CVP, g_cv_b, 0, M, 2304);
  k_mul<<<9216, 256, 0, stream>>>(G, M, XM);
  k_cg<4, 2, 0><<<288, 256, 0, stream>>>(XM, (const float*)nullptr, 0, P2P, g_p2_b, 0, N2, 2304);
  k_unpool<<<36864, 256, 0, stream>>>(N2, IDX, x, n4_g, n4_b, XA);
  // Transpose xa -> pixel-major
  k_tr<<<9216, 256, 0, stream>>>((const unsigned short*)XA, XAT);
  // MLP + residual
  k_mlp_mfma<<<1152, 256, 0, stream>>>(XAT, W1P, mlp_bn_b, W2P, n1_b, x, (float*)d_out);
}

// Round 15
// 1196.125 us; speedup vs baseline: 1.3522x; 1.0016x over previous
//
#include <hip/hip_runtime.h>
#include <hip/hip_bf16.h>

typedef __hip_bfloat16 bf16;
typedef short bf16x8 __attribute__((ext_vector_type(8)));
typedef float f32x4 __attribute__((ext_vector_type(4)));

#define BNS 0.9999950000374997f  /* 1/sqrt(1+1e-5) */

// Fast erf: Abramowitz-Stegun 7.1.26, |err| <= 1.5e-7 (invisible vs bf16 rounding).
__device__ __forceinline__ float erf_fast(float x) {
  float ax = fabsf(x);
  float t = __builtin_amdgcn_rcpf(1.0f + 0.3275911f * ax);
  float p = t * (0.254829592f + t * (-0.284496736f + t * (1.421413741f
          + t * (-1.453152027f + t * 1.061405429f))));
  float r = 1.0f - p * __expf(-ax * ax);
  return copysignf(r, x);
}
__device__ __forceinline__ float geluf(float x) { return 0.5f * x * (1.0f + erf_fast(x * 0.70710678118654752f)); }
__device__ __forceinline__ float sigmf(float x) { return 1.0f / (1.0f + expf(-x)); }
__device__ __forceinline__ unsigned short f2b(float f) { bf16 h = __float2bfloat16(f); return *(unsigned short*)&h; }

// async global->LDS, 16B per lane (linear per-wave mapping required)
__device__ __forceinline__ void gload_lds16(const void* g, void* l) {
  __builtin_amdgcn_global_load_lds(
      (const __attribute__((address_space(1))) void*)g,
      (__attribute__((address_space(3))) void*)l, 16, 0, 0);
}

// ============ weight prep #1: bf16 frag-linear packs (PA, LA, fuse1) ========================
__global__ __launch_bounds__(256) void k_wprep(const float* __restrict__ pa_w1,
    const float* __restrict__ pa_g, const float* __restrict__ pa_w2,
    const float* __restrict__ la_w, const float* __restrict__ la_g,
    const float* __restrict__ f1w,
    unsigned short* __restrict__ W1PA, unsigned short* __restrict__ W2PA,
    unsigned short* __restrict__ WLAP, unsigned short* __restrict__ F1P) {
  int i = blockIdx.x * 256 + threadIdx.x;
  if (i < 16384) {
    int j = i & 7, lane = (i >> 3) & 63, q = i >> 9;
    int mb = q % 16, kc = q / 16;
    int m = mb * 16 + (lane & 15), k = kc * 32 + (lane >> 4) * 8 + j;
    W1PA[i] = f2b(pa_w1[m * 64 + k] * (pa_g[m] * BNS));
  } else if (i < 32768) {
    int ii = i - 16384;
    int j = ii & 7, lane = (ii >> 3) & 63, q = ii >> 9;
    int mb = q % 4, kc = q / 4;
    int m = mb * 16 + (lane & 15), k = kc * 32 + (lane >> 4) * 8 + j;
    W2PA[ii] = f2b(pa_w2[m * 256 + k]);
  } else if (i < 69632) {
    int ii = i - 32768;
    int j = ii & 7, lane = (ii >> 3) & 63, q = ii >> 9;
    int mb = q % 4, gk = q / 4;           // gk = tap*2 + kc2, tap = ky*3+kx
    int tap = gk >> 1, kc2 = gk & 1;
    int co = mb * 16 + (lane & 15), ci = kc2 * 32 + (lane >> 4) * 8 + j;
    WLAP[ii] = f2b(la_w[(co * 64 + ci) * 9 + tap] * (la_g[co] * BNS));
  } else if (i < 77824) {
    int ii = i - 69632;
    int j = ii & 7, lane = (ii >> 3) & 63, q = ii >> 9;
    int mb = q % 4, kc = q / 4;
    int m = mb * 16 + (lane & 15), k = kc * 32 + (lane >> 4) * 8 + j;
    F1P[ii] = f2b(f1w[m * 128 + k]);
  }
}

// ============ weight prep #2: GA-phase packs (after MRA frees R-tail) =======================
__global__ __launch_bounds__(256) void k_wprep2(const float* __restrict__ f2w,
    const float* __restrict__ p1w, const float* __restrict__ c1w,
    const float* __restrict__ c2w, const float* __restrict__ cvw,
    const float* __restrict__ p2w,
    unsigned short* __restrict__ F2P, unsigned short* __restrict__ P1P,
    unsigned short* __restrict__ C1P, unsigned short* __restrict__ C2P,
    unsigned short* __restrict__ CVP, unsigned short* __restrict__ P2P) {
  int i = blockIdx.x * 256 + threadIdx.x;
  if (i < 8192) {               // fuse2: MT=4, K=128
    int j = i & 7, lane = (i >> 3) & 63, q = i >> 9;
    int mb = q % 4, kc = q / 4;
    int m = mb * 16 + (lane & 15), k = kc * 32 + (lane >> 4) * 8 + j;
    F2P[i] = f2b(f2w[m * 128 + k]);
  } else if (i < 12288) {       // p1: MT=4, K=64
    int ii = i - 8192;
    int j = ii & 7, lane = (ii >> 3) & 63, q = ii >> 9;
    int mb = q % 4, kc = q / 4;
    int m = mb * 16 + (lane & 15), k = kc * 32 + (lane >> 4) * 8 + j;
    P1P[ii] = f2b(p1w[m * 64 + k]);
  } else if (i < 14336) {       // c1: MT=2, K=64
    int ii = i - 12288;
    int j = ii & 7, lane = (ii >> 3) & 63, q = ii >> 9;
    int mb = q % 2, kc = q / 2;
    int m = mb * 16 + (lane & 15), k = kc * 32 + (lane >> 4) * 8 + j;
    C1P[ii] = f2b(c1w[m * 64 + k]);
  } else if (i < 16384) {       // c2: MT=2, K=64
    int ii = i - 14336;
    int j = ii & 7, lane = (ii >> 3) & 63, q = ii >> 9;
    int mb = q % 2, kc = q / 2;
    int m = mb * 16 + (lane & 15), k = kc * 32 + (lane >> 4) * 8 + j;
    C2P[ii] = f2b(c2w[m * 64 + k]);
  } else if (i < 18432) {       // cv: MT=4, K=32
    int ii = i - 16384;
    int j = ii & 7, lane = (ii >> 3) & 63, q = ii >> 9;
    int mb = q % 4;             // kc = 0
    int m = mb * 16 + (lane & 15), k = (lane >> 4) * 8 + j;
    CVP[ii] = f2b(cvw[m * 32 + k]);
  } else if (i < 22528) {       // p2: MT=4, K=64
    int ii = i - 18432;
    int j = ii & 7, lane = (ii >> 3) & 63, q = ii >> 9;
    int mb = q % 4, kc = q / 4;
    int m = mb * 16 + (lane & 15), k = kc * 32 + (lane >> 4) * 8 + j;
    P2P[ii] = f2b(p2w[m * 64 + k]);
  }
}

// ============ PA branch v3: chained MFMA GEMMs (64 -> 256 gelu -> 64) =======================
__global__ __launch_bounds__(256, 2) void k_pa(const float* __restrict__ x,
    const unsigned short* __restrict__ W1PA, const float* __restrict__ b1,
    const unsigned short* __restrict__ W2PA,
    float* __restrict__ x1pa, bf16* __restrict__ xa) {
  __shared__ unsigned short hs[128][40];
  __shared__ float b1s[256];
  int t = threadIdx.x;
  b1s[t] = b1[t];
  __syncthreads();
  int b = blockIdx.x / 72;
  int hw0 = (blockIdx.x % 72) * 128;
  int lane = t & 63, wave = t >> 6, lm = lane & 15, lk = lane >> 4;
  bf16x8 Bf[2][2];   // [nt][ks]
  {
    const float* xb = x + (size_t)b * 256 * 9216 + hw0 + wave * 32 + lm;
#pragma unroll
    for (int nt = 0; nt < 2; ++nt)
#pragma unroll
      for (int ks = 0; ks < 2; ++ks)
#pragma unroll
        for (int j = 0; j < 8; ++j)
          Bf[nt][ks][j] = (short)f2b(xb[(size_t)(ks * 32 + lk * 8 + j) * 9216 + nt * 16]);
  }
  f32x4 Y[4][2];
#pragma unroll
  for (int i = 0; i < 4; ++i) { Y[i][0] = (f32x4){0,0,0,0}; Y[i][1] = (f32x4){0,0,0,0}; }

  for (int c = 0; c < 8; ++c) {   // hidden chunks of 32
    f32x4 Hc[2][2];
#pragma unroll
    for (int i = 0; i < 2; ++i) { Hc[i][0] = (f32x4){0,0,0,0}; Hc[i][1] = (f32x4){0,0,0,0}; }
#pragma unroll
    for (int ks = 0; ks < 2; ++ks)
#pragma unroll
      for (int mt = 0; mt < 2; ++mt) {
        bf16x8 a = *(const bf16x8*)(W1PA + ((size_t)((ks * 16 + c * 2 + mt) * 64 + lane) * 8));
        Hc[mt][0] = __builtin_amdgcn_mfma_f32_16x16x32_bf16(a, Bf[0][ks], Hc[mt][0], 0, 0, 0);
        Hc[mt][1] = __builtin_amdgcn_mfma_f32_16x16x32_bf16(a, Bf[1][ks], Hc[mt][1], 0, 0, 0);
      }
#pragma unroll
    for (int mt = 0; mt < 2; ++mt)
#pragma unroll
      for (int nt = 0; nt < 2; ++nt)
#pragma unroll
        for (int r = 0; r < 4; r += 2) {
          int h = c * 32 + mt * 16 + lk * 4 + r;
          float v0 = geluf(Hc[mt][nt][r]     + b1s[h]);
          float v1 = geluf(Hc[mt][nt][r + 1] + b1s[h + 1]);
          unsigned u = (unsigned)f2b(v0) | ((unsigned)f2b(v1) << 16);
          *(unsigned*)&hs[wave * 32 + nt * 16 + lm][mt * 16 + lk * 4 + r] = u;
        }
    bf16x8 h0 = *(const bf16x8*)&hs[wave * 32 + lm][lk * 8];
    bf16x8 h1 = *(const bf16x8*)&hs[wave * 32 + 16 + lm][lk * 8];
#pragma unroll
    for (int mb = 0; mb < 4; ++mb) {
      bf16x8 a2 = *(const bf16x8*)(W2PA + ((size_t)((c * 4 + mb) * 64 + lane) * 8));
      Y[mb][0] = __builtin_amdgcn_mfma_f32_16x16x32_bf16(a2, h0, Y[mb][0], 0, 0, 0);
      Y[mb][1] = __builtin_amdgcn_mfma_f32_16x16x32_bf16(a2, h1, Y[mb][1], 0, 0, 0);
    }
  }
#pragma unroll
  for (int mb = 0; mb < 4; ++mb)
#pragma unroll
    for (int nt = 0; nt < 2; ++nt)
#pragma unroll
      for (int r = 0; r < 4; ++r) {
        int co = mb * 16 + lk * 4 + r;
        int px = hw0 + wave * 32 + nt * 16 + lm;
        float x1v = x[((size_t)b * 256 + co) * 9216 + px];
        float pa = x1v * sigmf(Y[mb][nt][r]);
        x1pa[((size_t)b * 64 + co) * 9216 + px] = pa;
        xa[((size_t)b * 256 + co) * 9216 + px] = __float2bfloat16(x1v + pa);
      }
}

// ============ generic 1x1 MFMA conv =========================================================
// Optional mulA: element-wise multiplier for inA (fuses k_mul). Optional mixK: second input
// K2 with per-pixel sigmoid pair SG (fuses k_mix): B = inA*sg0 + mixK*sg1.
template<int MT, int KCA, int KCB>
__global__ __launch_bounds__(256, 2) void k_cg(const float* __restrict__ inA,
    const float* __restrict__ xsrc, int xoff,
    const unsigned short* __restrict__ wp, const float* __restrict__ bias, int act,
    float* __restrict__ out, int npix,
    const float* __restrict__ mulA = nullptr,
    const float* __restrict__ mixK = nullptr, const float* __restrict__ SG = nullptr) {
  int t = threadIdx.x, lane = t & 63, wave = t >> 6, lm = lane & 15, lk = lane >> 4;
  int p0 = blockIdx.x * 128;
  int b = p0 / npix, hw0 = p0 % npix;
  int pxi = hw0 + wave * 32 + lm;   // per-lane pixel (nt adds 16)
  float sg0 = 0.f, sg1 = 0.f, sg0b = 0.f, sg1b = 0.f;
  if (SG) {
    sg0  = SG[(size_t)(b * 2) * npix + pxi];
    sg1  = SG[(size_t)(b * 2 + 1) * npix + pxi];
    sg0b = SG[(size_t)(b * 2) * npix + pxi + 16];
    sg1b = SG[(size_t)(b * 2 + 1) * npix + pxi + 16];
  }
  f32x4 acc[MT][2];
#pragma unroll
  for (int i = 0; i < MT; ++i) { acc[i][0] = (f32x4){0,0,0,0}; acc[i][1] = (f32x4){0,0,0,0}; }
#pragma unroll
  for (int kc = 0; kc < KCA + KCB; ++kc) {
    bf16x8 bf[2];
#pragma unroll
    for (int nt = 0; nt < 2; ++nt) {
      if (kc < KCA) {
        size_t off = ((size_t)b * (KCA * 32) + kc * 32 + lk * 8) * npix
                   + hw0 + wave * 32 + nt * 16 + lm;
        const float* src = inA + off;
        if (SG) {
          const float* srcK = mixK + off;
          float s0 = nt ? sg0b : sg0, s1 = nt ? sg1b : sg1;
#pragma unroll
          for (int j = 0; j < 8; ++j)
            bf[nt][j] = (short)f2b(src[(size_t)j * npix] * s0 + srcK[(size_t)j * npix] * s1);
        } else if (mulA) {
          const float* srcM = mulA + off;
#pragma unroll
          for (int j = 0; j < 8; ++j)
            bf[nt][j] = (short)f2b(src[(size_t)j * npix] * srcM[(size_t)j * npix]);
        } else {
#pragma unroll
          for (int j = 0; j < 8; ++j) bf[nt][j] = (short)f2b(src[(size_t)j * npix]);
        }
      } else {
        const float* src = xsrc + ((size_t)b * 256 + xoff + (kc - KCA) * 32 + lk * 8) * 9216
                         + hw0 + wave * 32 + nt * 16 + lm;
#pragma unroll
        for (int j = 0; j < 8; ++j) bf[nt][j] = (short)f2b(src[(size_t)j * 9216]);
      }
    }
#pragma unroll
    for (int mb = 0; mb < MT; ++mb) {
      bf16x8 a = *(const bf16x8*)(wp + ((size_t)((kc * MT + mb) * 64 + lane) * 8));
      acc[mb][0] = __builtin_amdgcn_mfma_f32_16x16x32_bf16(a, bf[0], acc[mb][0], 0, 0, 0);
      acc[mb][1] = __builtin_amdgcn_mfma_f32_16x16x32_bf16(a, bf[1], acc[mb][1], 0, 0, 0);
    }
  }
#pragma unroll
  for (int mb = 0; mb < MT; ++mb)
#pragma unroll
    for (int nt = 0; nt < 2; ++nt)
#pragma unroll
      for (int r = 0; r < 4; ++r) {
        int c = mb * 16 + lk * 4 + r;
        float v = acc[mb][nt][r] + (bias ? bias[c] : 0.f);
        if (act) v = geluf(v);
        out[((size_t)b * (MT * 16) + c) * npix + hw0 + wave * 32 + nt * 16 + lm] = v;
      }
}

// ============ la v3: implicit-GEMM 3x3 conv 64->64 via 9 shifted 1x1s =======================
__global__ __launch_bounds__(384, 2) void k_la(const float* __restrict__ Q,
    const unsigned short* __restrict__ WLAP, const float* __restrict__ bb,
    bf16* __restrict__ xa) {
  int py = blockIdx.x % 96, b = blockIdx.x / 96;
  int t = threadIdx.x, lane = t & 63, w = t >> 6, lm = lane & 15, lk = lane >> 4;
  int px = w * 16 + lm;
  f32x4 acc[4];
#pragma unroll
  for (int i = 0; i < 4; ++i) acc[i] = (f32x4){0,0,0,0};
#pragma unroll
  for (int ky = 0; ky < 3; ++ky) {
    int row = py + ky - 1;
    if ((unsigned)row >= 96u) continue;
#pragma unroll
    for (int kx = 0; kx < 3; ++kx) {
      int pxe = px + kx - 1;
      bool vld = (unsigned)pxe < 96u;
      int pxc = vld ? pxe : 0;
      const float* qb = Q + ((size_t)b * 64 + lk * 8) * 9216 + row * 96 + pxc;
#pragma unroll
      for (int kc = 0; kc < 2; ++kc) {
        bf16x8 bf;
#pragma unroll
        for (int j = 0; j < 8; ++j) {
          float v = vld ? qb[(size_t)(kc * 32 + j) * 9216] : 0.f;
          bf[j] = (short)f2b(v);
        }
        int gk = (ky * 3 + kx) * 2 + kc;
#pragma unroll
        for (int mb = 0; mb < 4; ++mb) {
          bf16x8 a = *(const bf16x8*)(WLAP + ((size_t)((gk * 4 + mb) * 64 + lane) * 8));
          acc[mb] = __builtin_amdgcn_mfma_f32_16x16x32_bf16(a, bf, acc[mb], 0, 0, 0);
        }
      }
    }
  }
#pragma unroll
  for (int mb = 0; mb < 4; ++mb)
#pragma unroll
    for (int r = 0; r < 4; ++r) {
      int co = mb * 16 + lk * 4 + r;
      float v = geluf(acc[mb][r] + bb[co]);
      xa[((size_t)b * 256 + 64 + co) * 9216 + py * 96 + px] = __float2bfloat16(v);
    }
}

// ---------------- fused maxpool3 + blurpool: x ch128..191 -> T (16,64,32,32) ----------------
__global__ __launch_bounds__(256) void k_mp3blur(const float* __restrict__ x, float* __restrict__ out) {
  int idx = blockIdx.x * 256 + threadIdx.x;
  if (idx >= 16 * 64 * 1024) return;
  int ow = idx % 32; int tmp = idx / 32; int oh = tmp % 32; int bc = tmp / 32;
  int c = bc % 64, b = bc / 64;
  const float* src = x + ((size_t)(b * 256 + 128 + c)) * 9216;
  const float a4[4] = {1.f, 3.f, 3.f, 1.f};
  float s = 0.f;
#pragma unroll
  for (int ky = 0; ky < 4; ++ky) {
    int sy = 3 * oh + ky - 1; if (sy < 0) sy = -sy; if (sy > 95) sy = 190 - sy;
#pragma unroll
    for (int kx = 0; kx < 4; ++kx) {
      int sx = 3 * ow + kx - 1; if (sx < 0) sx = -sx; if (sx > 95) sx = 190 - sx;
      float m = -3.4e38f;
      int y0 = sy > 0 ? sy - 1 : 0, y1 = sy < 95 ? sy + 1 : 95;
      int x0 = sx > 0 ? sx - 1 : 0, x1 = sx < 95 ? sx + 1 : 95;
      for (int y = y0; y <= y1; ++y)
        for (int xx = x0; xx <= x1; ++xx)
          m = fmaxf(m, src[y * 96 + xx]);
      s += a4[ky] * a4[kx] * m;
    }
  }
  out[idx] = s * (1.0f / 64.0f);
}

// ---------------- generic depthwise conv ----------------------------------------------------
__global__ __launch_bounds__(256) void k_dw(const float* __restrict__ in, const float* __restrict__ w,
    const float* __restrict__ bias, float* __restrict__ out,
    int H, int W, int KH, int KW, int pH, int pW, int dil, int accf) {
  int idx = blockIdx.x * 256 + threadIdx.x;
  int total = 16 * 64 * H * W; if (idx >= total) return;
  int wpx = idx % W; int tmp = idx / W; int h = tmp % H; tmp /= H; int c = tmp % 64;
  const float* src = in + tmp * H * W;
  const float* wr = w + c * KH * KW;
  float a = bias ? bias[c] : 0.f;
  for (int ky = 0; ky < KH; ++ky) {
    int y = h - pH + ky * dil; if ((unsigned)y >= (unsigned)H) continue;
    for (int kx = 0; kx < KW; ++kx) {
      int xx = wpx - pW + kx * dil; if ((unsigned)xx >= (unsigned)W) continue;
      a += wr[ky * KW + kx] * src[y * W + xx];
    }
  }
  if (accf) out[idx] += a; else out[idx] = a;
}

// ---------------- shear transforms ----------------------------------------------------------
__global__ __launch_bounds__(256) void k_htrans(const float* __restrict__ in, float* __restrict__ out) {
  int idx = blockIdx.x * 256 + threadIdx.x;
  if (idx >= 16 * 64 * 32 * 63) return;
  int j = idx % 63; int tmp = idx / 63; int i = tmp % 32; int bc = tmp / 32;
  int k = j - i;
  out[idx] = (k >= 0 && k < 32) ? in[(bc * 32 + i) * 32 + k] : 0.f;
}
__global__ __launch_bounds__(256) void k_invh_add(const float* __restrict__ F, float* __restrict__ D) {
  int idx = blockIdx.x * 256 + threadIdx.x;
  if (idx >= 16 * 64 * 1024) return;
  int j = idx % 32; int tmp = idx / 32; int i = tmp % 32; int bc = tmp / 32;
  D[idx] += F[(bc * 32 + i) * 63 + i + j];
}
__global__ __launch_bounds__(256) void k_vtrans(const float* __restrict__ in, float* __restrict__ out) {
  int idx = blockIdx.x * 256 + threadIdx.x;
  if (idx >= 16 * 64 * 63 * 32) return;
  int c = idx % 32; int tmp = idx / 32; int r = tmp % 63; int bc = tmp / 63;
  int k = r - c;
  out[idx] = (k >= 0 && k < 32) ? in[(bc * 32 + k) * 32 + c] : 0.f;
}
__global__ __launch_bounds__(256) void k_invv_add(const float* __restrict__ F, float* __restrict__ D) {
  int idx = blockIdx.x * 256 + threadIdx.x;
  if (idx >= 16 * 64 * 1024) return;
  int j = idx % 32; int tmp = idx / 32; int i = tmp % 32; int bc = tmp / 32;
  D[idx] += F[(bc * 63 + (i + j)) * 32 + j];
}

// ---------------- gate ----------------------------------------------------------------------
__global__ __launch_bounds__(256) void k_gate(const float* __restrict__ D, const float* __restrict__ x,
    const float* __restrict__ g, const float* __restrict__ bb,
    float* __restrict__ mra_out, bf16* __restrict__ xa) {
  int idx = blockIdx.x * 256 + threadIdx.x;
  if (idx >= 16 * 64 * 9216) return;
  int wv = idx % 96; int tmp = idx / 96; int h = tmp % 96; tmp /= 96; int c = tmp % 64; int b = tmp / 64;
  float d = D[((b * 64 + c) * 32 + h / 3) * 32 + (wv / 3)];
  float gt = sigmf(d * g[c] * BNS + bb[c]);
  float x3v = x[(b * 256 + 128 + c) * 9216 + h * 96 + wv];
  float mra = x3v * gt;
  mra_out[idx] = mra;
  xa[(b * 256 + 128 + c) * 9216 + h * 96 + wv] = __float2bfloat16(x3v + mra);
}

// ---------------- maxpool2 with argmax ------------------------------------------------------
__global__ __launch_bounds__(256) void k_pool2(const float* __restrict__ in, float* __restrict__ out,
                                               int* __restrict__ idxo) {
  int idx = blockIdx.x * 256 + threadIdx.x;
  if (idx >= 16 * 64 * 2304) return;
  int ow = idx % 48; int tmp = idx / 48; int oh = tmp % 48; int bc = tmp / 48;
  const float* src = in + bc * 9216;
  int y = 2 * oh, xx = 2 * ow;
  float v0 = src[y * 96 + xx], v1 = src[y * 96 + xx + 1];
  float v2 = src[(y + 1) * 96 + xx], v3 = src[(y + 1) * 96 + xx + 1];
  float best = v0; int bi = 0;
  if (v1 > best) { best = v1; bi = 1; }
  if (v2 > best) { best = v2; bi = 2; }
  if (v3 > best) { best = v3; bi = 3; }
  out[idx] = best; idxo[idx] = bi;
}

// ---------------- channel mean/max ----------------------------------------------------------
__global__ __launch_bounds__(256) void k_agg(const float* __restrict__ J, const float* __restrict__ K,
                                             float* __restrict__ AGG) {
  int idx = blockIdx.x * 256 + threadIdx.x;
  if (idx >= 16 * 2304) return;
  int hw = idx % 2304; int b = idx / 2304;
  float sum = 0.f, mx = -3.4e38f;
  for (int j = 0; j < 32; ++j) { float v = J[(b * 32 + j) * 2304 + hw]; sum += v; mx = fmaxf(mx, v); }
  for (int j = 0; j < 32; ++j) { float v = K[(b * 32 + j) * 2304 + hw]; sum += v; mx = fmaxf(mx, v); }
  AGG[(b * 2 + 0) * 2304 + hw] = sum * (1.0f / 64.0f);
  AGG[(b * 2 + 1) * 2304 + hw] = mx;
}

// ---------------- squeeze conv 2->2 7x7 pad3 + sigmoid --------------------------------------
__global__ __launch_bounds__(256) void k_sq(const float* __restrict__ AGG, const float* __restrict__ w,
                                            const float* __restrict__ bias, float* __restrict__ SG) {
  int idx = blockIdx.x * 256 + threadIdx.x;
  if (idx >= 16 * 2 * 2304) return;
  int hw = idx % 2304; int tmp = idx / 2304; int co = tmp % 2; int b = tmp / 2;
  int h = hw / 48, wv = hw % 48;
  float acc = bias[co];
  for (int ci = 0; ci < 2; ++ci) {
    const float* src = AGG + (b * 2 + ci) * 2304;
    for (int ky = 0; ky < 7; ++ky) {
      int y = h - 3 + ky; if ((unsigned)y >= 48u) continue;
      for (int kx = 0; kx < 7; ++kx) {
        int xx = wv - 3 + kx; if ((unsigned)xx >= 48u) continue;
        acc += w[((co * 2 + ci) * 7 + ky) * 7 + kx] * src[y * 48 + xx];
      }
    }
  }
  SG[idx] = sigmf(acc);
}

// ---------------- unpool + bn(n4), xa ch192..255 --------------------------------------------
__global__ __launch_bounds__(256) void k_unpool(const float* __restrict__ N2, const int* __restrict__ IDX,
    const float* __restrict__ x, const float* __restrict__ g, const float* __restrict__ bb,
    bf16* __restrict__ xa) {
  int idx = blockIdx.x * 256 + threadIdx.x;
  if (idx >= 16 * 64 * 9216) return;
  int wv = idx % 96; int tmp = idx / 96; int h = tmp % 96; tmp /= 96; int c = tmp % 64; int b = tmp / 64;
  int oh = h >> 1, ow = wv >> 1;
  int pos = (b * 64 + c) * 2304 + oh * 48 + ow;
  int kk = (h & 1) * 2 + (wv & 1);
  float v = (IDX[pos] == kk) ? N2[pos] : 0.f;
  float x4v = x[(b * 256 + 192 + c) * 9216 + h * 96 + wv];
  xa[(b * 256 + 192 + c) * 9216 + h * 96 + wv] =
      __float2bfloat16((x4v + v) * g[c] * BNS + bb[c]);
}

// ---------------- transpose XA (ch-major bf16) -> XAT (pixel-major bf16) --------------------
__global__ __launch_bounds__(256) void k_tr(const unsigned short* __restrict__ XA,
                                            unsigned short* __restrict__ XAT) {
  __shared__ unsigned s[64][65];
  int t = threadIdx.x;
  int bid = blockIdx.x;
  int ct = bid & 3;
  int pt = (bid >> 2) % 144;
  int b = (bid >> 2) / 144;
  int c0 = ct * 64, p0 = pt * 64;
  for (int i = t; i < 4096; i += 256) {
    int cl = i >> 6, pl = i & 63;
    s[cl][pl] = XA[(size_t)(b * 256 + c0 + cl) * 9216 + p0 + pl];
  }
  __syncthreads();
  for (int i = t; i < 4096; i += 256) {
    int pl = i >> 6, cl = i & 63;
    XAT[((size_t)(b * 9216 + p0 + pl) << 8) + c0 + cl] = (unsigned short)s[cl][pl];
  }
}

// ---------------- prep: MLP weights frag-linear, bf16, BN scales folded ---------------------
__global__ __launch_bounds__(256) void k_prep(const float* __restrict__ w1, const float* __restrict__ g1,
    const float* __restrict__ w2, const float* __restrict__ ng,
    unsigned short* __restrict__ w1p, unsigned short* __restrict__ w2p) {
  int i = blockIdx.x * 256 + threadIdx.x;
  if (i >= 262144) return;
  {
    int j = i & 7, lane = (i >> 3) & 63, ks = (i >> 9) & 7, mb = i >> 12;
    int h = mb * 16 + (lane & 15);
    int k = ks * 32 + (lane >> 4) * 8 + j;
    w1p[i] = f2b(w1[h * 256 + k] * (g1[h] * BNS));
  }
  {
    int j = i & 7, lane = (i >> 3) & 63, mb = (i >> 9) & 15, c = i >> 13;
    int m = mb * 16 + (lane & 15);
    int k = c * 32 + (lane >> 4) * 8 + j;
    w2p[i] = f2b(w2[m * 1024 + k] * (ng[m] * BNS));
  }
}

// ---------------- fused MFMA MLP v4 (measured 299us; kept) ----------------------------------
__global__ __launch_bounds__(256, 2) void k_mlp_mfma(
    const unsigned short* __restrict__ XAT,
    const unsigned short* __restrict__ W1P, const float* __restrict__ b1,
    const unsigned short* __restrict__ W2P, const float* __restrict__ nbv,
    const float* __restrict__ xin, float* __restrict__ out) {
  __shared__ uint4 w1c4[2048];
  __shared__ uint4 w2c4[2048];
  __shared__ unsigned short hs[128][40];
  __shared__ float b1s[1024];
  __shared__ float nbs[256];
  unsigned short* w1c = (unsigned short*)w1c4;
  unsigned short* w2c = (unsigned short*)w2c4;
  int t = threadIdx.x;
  int b = blockIdx.x / 72;
  int hw0 = (blockIdx.x % 72) * 128;
  for (int i = t; i < 1024; i += 256) b1s[i] = b1[i];
  nbs[t] = nbv[t];
  int lane = t & 63, wave = t >> 6;
  int lm = lane & 15, lk = lane >> 4;
  bf16x8 Bf[2][8];
  {
    const unsigned short* base = XAT + ((size_t)(b * 9216 + hw0 + wave * 32 + lm) << 8) + lk * 8;
#pragma unroll
    for (int nt2 = 0; nt2 < 2; ++nt2)
#pragma unroll
      for (int ks = 0; ks < 8; ++ks)
        Bf[nt2][ks] = *(const bf16x8*)(base + nt2 * 16 * 256 + ks * 32);
  }
  f32x4 Y[16][2];
#pragma unroll
  for (int i = 0; i < 16; ++i) { Y[i][0] = (f32x4){0,0,0,0}; Y[i][1] = (f32x4){0,0,0,0}; }

  const uint4* g1p = (const uint4*)W1P;
  const uint4* g2p = (const uint4*)W2P;
  for (int p = 0; p < 16; ++p) {
    __syncthreads();
#pragma unroll
    for (int i = 0; i < 4; ++i) {
      int o = i * 256 + t;
      gload_lds16(&g1p[(2 * p) * 1024 + o],     &w1c4[o]);
      gload_lds16(&g1p[(2 * p + 1) * 1024 + o], &w1c4[1024 + o]);
      gload_lds16(&g2p[(2 * p) * 1024 + o],     &w2c4[o]);
      gload_lds16(&g2p[(2 * p + 1) * 1024 + o], &w2c4[1024 + o]);
    }
    __syncthreads();
#pragma unroll
    for (int sub = 0; sub < 2; ++sub) {
      int cc = 2 * p + sub;
      int wo = sub * 8192;
      f32x4 Hc[2][2];
#pragma unroll
      for (int i = 0; i < 2; ++i) { Hc[i][0] = (f32x4){0,0,0,0}; Hc[i][1] = (f32x4){0,0,0,0}; }
#pragma unroll
      for (int ks = 0; ks < 8; ++ks) {
        bf16x8 a0 = *(const bf16x8*)&w1c[wo + (ks * 64 + lane) * 8];
        bf16x8 a1 = *(const bf16x8*)&w1c[wo + ((8 + ks) * 64 + lane) * 8];
        Hc[0][0] = __builtin_amdgcn_mfma_f32_16x16x32_bf16(a0, Bf[0][ks], Hc[0][0], 0, 0, 0);
        Hc[0][1] = __builtin_amdgcn_mfma_f32_16x16x32_bf16(a0, Bf[1][ks], Hc[0][1], 0, 0, 0);
        Hc[1][0] = __builtin_amdgcn_mfma_f32_16x16x32_bf16(a1, Bf[0][ks], Hc[1][0], 0, 0, 0);
        Hc[1][1] = __builtin_amdgcn_mfma_f32_16x16x32_bf16(a1, Bf[1][ks], Hc[1][1], 0, 0, 0);
      }
#pragma unroll
      for (int mbl = 0; mbl < 2; ++mbl)
#pragma unroll
        for (int nt2 = 0; nt2 < 2; ++nt2)
#pragma unroll
          for (int r = 0; r < 4; r += 2) {
            int h = cc * 32 + mbl * 16 + lk * 4 + r;
            float v0 = geluf(Hc[mbl][nt2][r]     + b1s[h]);
            float v1 = geluf(Hc[mbl][nt2][r + 1] + b1s[h + 1]);
            unsigned u = (unsigned)f2b(v0) | ((unsigned)f2b(v1) << 16);
            *(unsigned*)&hs[wave * 32 + nt2 * 16 + lm][mbl * 16 + lk * 4 + r] = u;
          }
      bf16x8 h0 = *(const bf16x8*)&hs[wave * 32 + lm][lk * 8];
      bf16x8 h1 = *(const bf16x8*)&hs[wave * 32 + 16 + lm][lk * 8];
#pragma unroll
      for (int mb = 0; mb < 16; ++mb) {
        bf16x8 a = *(const bf16x8*)&w2c[wo + (mb * 64 + lane) * 8];
        Y[mb][0] = __builtin_amdgcn_mfma_f32_16x16x32_bf16(a, h0, Y[mb][0], 0, 0, 0);
        Y[mb][1] = __builtin_amdgcn_mfma_f32_16x16x32_bf16(a, h1, Y[mb][1], 0, 0, 0);
      }
    }
  }
#pragma unroll
  for (int mb = 0; mb < 16; ++mb)
#pragma unroll
    for (int nt2 = 0; nt2 < 2; ++nt2)
#pragma unroll
      for (int r = 0; r < 4; ++r) {
        int m = mb * 16 + lk * 4 + r;
        size_t o = (size_t)(b * 256 + m) * 9216 + hw0 + wave * 32 + nt2 * 16 + lm;
        out[o] = Y[mb][nt2][r] + nbs[m] + xin[o];
      }
}

extern "C" void kernel_launch(void* const* d_in, const int* in_sizes, int n_in,
                              void* d_out, int out_size, void* d_ws, size_t ws_size,
                              hipStream_t stream) {
  const float* x        = (const float*)d_in[0];
  const float* pa_w1    = (const float*)d_in[1];
  const float* pa_bn_g  = (const float*)d_in[2];
  const float* pa_bn_b  = (const float*)d_in[3];
  const float* pa_w2    = (const float*)d_in[4];
  const float* fuse1_w  = (const float*)d_in[5];
  const float* la_w     = (const float*)d_in[6];
  const float* la_bn_g  = (const float*)d_in[7];
  const float* la_bn_b  = (const float*)d_in[8];
  const float* h1_w     = (const float*)d_in[9];
  const float* v1_w     = (const float*)d_in[10];
  const float* h2_w     = (const float*)d_in[11];
  const float* v2_w     = (const float*)d_in[12];
  const float* mra_bn_g = (const float*)d_in[13];
  const float* mra_bn_b = (const float*)d_in[14];
  const float* fuse2_w  = (const float*)d_in[15];
  const float* g_p1_w   = (const float*)d_in[16];
  const float* g_p1_b   = (const float*)d_in[17];
  const float* g_c0_w   = (const float*)d_in[18];
  const float* g_c0_b   = (const float*)d_in[19];
  const float* g_cs_w   = (const float*)d_in[20];
  const float* g_cs_b   = (const float*)d_in[21];
  const float* g_c1_w   = (const float*)d_in[22];
  const float* g_c1_b   = (const float*)d_in[23];
  const float* g_c2_w   = (const float*)d_in[24];
  const float* g_c2_b   = (const float*)d_in[25];
  const float* g_sq_w   = (const float*)d_in[26];
  const float* g_sq_b   = (const float*)d_in[27];
  const float* g_cv_w   = (const float*)d_in[28];
  const float* g_cv_b   = (const float*)d_in[29];
  const float* g_p2_w   = (const float*)d_in[30];
  const float* g_p2_b   = (const float*)d_in[31];
  const float* n4_g     = (const float*)d_in[32];
  const float* n4_b     = (const float*)d_in[33];
  const float* mlp_w1   = (const float*)d_in[34];
  const float* mlp_bn_g = (const float*)d_in[35];
  const float* mlp_bn_b = (const float*)d_in[36];
  const float* mlp_w2   = (const float*)d_in[37];
  const float* n1_g     = (const float*)d_in[38];
  const float* n1_b     = (const float*)d_in[39];

  // ---- aliased workspace: 44,236,800 floats = 176.9 MB ----
  float* ws = (float*)d_ws;
  bf16*  XA = (bf16*)ws;                    // (16,256,96,96) bf16 = 18,874,368 f-slots
  float* P  = ws + 18874368;                // 9,437,184 f
  float* Q  = ws + 28311552;                // 9,437,184 f
  float* R  = ws + 37748736;                // 6,225,920 f
  float* T  = R;
  float* D  = R + 1048576;
  float* E  = R + 2097152;
  float* F  = R + 4161536;
  float* C48 = P;
  int*   IDX = (int*)(P + 2359296);
  float* G   = P + 4718592;
  float* H2  = P + 7077888;
  float* I2  = Q;
  float* M   = Q + 2359296;
  float* N2  = Q + 7077888;
  float* J   = R;
  float* K2  = R + 1179648;
  float* AGG = R + 3538944;
  float* SG  = R + 3612672;
  unsigned short* XAT = (unsigned short*)P;
  unsigned short* W1P = (unsigned short*)(ws + 43974656);
  unsigned short* W2P = (unsigned short*)(ws + 43974656 + 131072);

  // Early bf16 frag packs: live in R head (T slot), dead before k_mp3blur writes T.
  unsigned short* W1PA = (unsigned short*)R;   // 16384 sh
  unsigned short* W2PA = W1PA + 16384;         // 16384 sh
  unsigned short* WLAP = W1PA + 32768;         // 36864 sh
  unsigned short* F1P  = W1PA + 69632;         // 8192 sh (ends 77824 sh = 38912 f < 1048576)
  // GA-phase packs: R tail (after SG end 3686400), written post-MRA.
  unsigned short* GWp = (unsigned short*)(R + 3686400);
  unsigned short* F2P = GWp;                   // 8192
  unsigned short* P1P = GWp + 8192;            // 4096
  unsigned short* C1P = GWp + 12288;           // 2048
  unsigned short* C2P = GWp + 14336;           // 2048
  unsigned short* CVP = GWp + 16384;           // 2048
  unsigned short* P2P = GWp + 18432;           // 4096 (ends 22528 sh = 11264 f)

  // Prep
  k_prep<<<1024, 256, 0, stream>>>(mlp_w1, mlp_bn_g, mlp_w2, n1_g, W1P, W2P);
  k_wprep<<<304, 256, 0, stream>>>(pa_w1, pa_bn_g, pa_w2, la_w, la_bn_g, fuse1_w,
                                   W1PA, W2PA, WLAP, F1P);
  // Branch 1 (PA): MFMA chained GEMMs
  k_pa<<<1152, 256, 0, stream>>>(x, W1PA, pa_bn_b, W2PA, P, XA);
  // Branch 2: fuse1 (MFMA) -> Q; la (MFMA implicit GEMM) -> xa ch 64..127
  k_cg<4, 2, 2><<<1152, 256, 0, stream>>>(P, x, 64, F1P, (const float*)nullptr, 0, Q, 9216);
  k_la<<<1536, 384, 0, stream>>>(Q, WLAP, la_bn_b, XA);
  // Branch 3 (MRA): fused maxpool3+blur (P intermediate eliminated)
  k_mp3blur<<<4096, 256, 0, stream>>>(x, T);
  k_dw<<<4096, 256, 0, stream>>>(T, h1_w, (const float*)nullptr, D, 32, 32, 7, 3, 3, 1, 1, 0);
  k_dw<<<4096, 256, 0, stream>>>(T, v1_w, (const float*)nullptr, D, 32, 32, 3, 7, 1, 3, 1, 1);
  k_htrans<<<8064, 256, 0, stream>>>(T, E);
  k_dw<<<8064, 256, 0, stream>>>(E, h2_w, (const float*)nullptr, F, 32, 63, 7, 3, 3, 1, 1, 0);
  k_invh_add<<<4096, 256, 0, stream>>>(F, D);
  k_vtrans<<<8064, 256, 0, stream>>>(T, E);
  k_dw<<<8064, 256, 0, stream>>>(E, v2_w, (const float*)nullptr, F, 63, 32, 3, 7, 1, 3, 1, 0);
  k_invv_add<<<4096, 256, 0, stream>>>(F, D);
  k_gate<<<36864, 256, 0, stream>>>(D, x, mra_bn_g, mra_bn_b, P, XA);
  // Branch 4 (GA): all 1x1s via MFMA; k_mul and k_mix fused into k_cg
  k_wprep2<<<88, 256, 0, stream>>>(fuse2_w, g_p1_w, g_c1_w, g_c2_w, g_cv_w, g_p2_w,
                                   F2P, P1P, C1P, C2P, CVP, P2P);
  k_cg<4, 2, 2><<<1152, 256, 0, stream>>>(P, x, 192, F2P, (const float*)nullptr, 0, Q, 9216);
  k_pool2<<<9216, 256, 0, stream>>>(Q, C48, IDX);
  k_cg<4, 2, 0><<<288, 256, 0, stream>>>(C48, (const float*)nullptr, 0, P1P, g_p1_b, 1, G, 2304);
  k_dw<<<9216, 256, 0, stream>>>(G, g_c0_w, g_c0_b, H2, 48, 48, 5, 5, 2, 2, 1, 0);
  k_dw<<<9216, 256, 0, stream>>>(H2, g_cs_w, g_cs_b, I2, 48, 48, 7, 7, 9, 9, 3, 0);
  k_cg<2, 2, 0><<<288, 256, 0, stream>>>(H2, (const float*)nullptr, 0, C1P, g_c1_b, 0, J, 2304);
  k_cg<2, 2, 0><<<288, 256, 0, stream>>>(I2, (const float*)nullptr, 0, C2P, g_c2_b, 0, K2, 2304);
  k_agg<<<144, 256, 0, stream>>>(J, K2, AGG);
  k_sq<<<288, 256, 0, stream>>>(AGG, g_sq_w, g_sq_b, SG);
  // cv conv with k_mix fused into B-frag load: B = J*sg0 + K2*sg1
  k_cg<4, 1, 0><<<288, 256, 0, stream>>>(J, (const float*)nullptr, 0, CVP, g_cv_b, 0, M, 2304,
                                         (const float*)nullptr, K2, SG);
  // p2 conv with k_mul fused: B = G * M
  k_cg<4, 2, 0><<<288, 256, 0, stream>>>(G, (const float*)nullptr, 0, P2P, g_p2_b, 0, N2, 2304,
                                         M);
  k_unpool<<<36864, 256, 0, stream>>>(N2, IDX, x, n4_g, n4_b, XA);
  // Transpose xa -> pixel-major
  k_tr<<<9216, 256, 0, stream>>>((const unsigned short*)XA, XAT);
  // MLP + residual
  k_mlp_mfma<<<1152, 256, 0, stream>>>(XAT, W1P, mlp_bn_b, W2P, n1_b, x, (float*)d_out);
}

// Round 16
// 1119.952 us; speedup vs baseline: 1.4442x; 1.0680x over previous
//
#include <hip/hip_runtime.h>
#include <hip/hip_bf16.h>

typedef __hip_bfloat16 bf16;
typedef short bf16x8 __attribute__((ext_vector_type(8)));
typedef float f32x4 __attribute__((ext_vector_type(4)));

#define BNS 0.9999950000374997f  /* 1/sqrt(1+1e-5) */

// Fast erf: Abramowitz-Stegun 7.1.26, |err| <= 1.5e-7 (invisible vs bf16 rounding).
__device__ __forceinline__ float erf_fast(float x) {
  float ax = fabsf(x);
  float t = __builtin_amdgcn_rcpf(1.0f + 0.3275911f * ax);
  float p = t * (0.254829592f + t * (-0.284496736f + t * (1.421413741f
          + t * (-1.453152027f + t * 1.061405429f))));
  float r = 1.0f - p * __expf(-ax * ax);
  return copysignf(r, x);
}
__device__ __forceinline__ float geluf(float x) { return 0.5f * x * (1.0f + erf_fast(x * 0.70710678118654752f)); }
__device__ __forceinline__ float sigmf(float x) { return 1.0f / (1.0f + expf(-x)); }
__device__ __forceinline__ unsigned short f2b(float f) { bf16 h = __float2bfloat16(f); return *(unsigned short*)&h; }

// async global->LDS, 16B per lane (linear per-wave mapping required)
__device__ __forceinline__ void gload_lds16(const void* g, void* l) {
  __builtin_amdgcn_global_load_lds(
      (const __attribute__((address_space(1))) void*)g,
      (__attribute__((address_space(3))) void*)l, 16, 0, 0);
}

// ============ weight prep #1: bf16 frag-linear packs (PA, LA, fuse1) ========================
__global__ __launch_bounds__(256) void k_wprep(const float* __restrict__ pa_w1,
    const float* __restrict__ pa_g, const float* __restrict__ pa_w2,
    const float* __restrict__ la_w, const float* __restrict__ la_g,
    const float* __restrict__ f1w,
    unsigned short* __restrict__ W1PA, unsigned short* __restrict__ W2PA,
    unsigned short* __restrict__ WLAP, unsigned short* __restrict__ F1P) {
  int i = blockIdx.x * 256 + threadIdx.x;
  if (i < 16384) {
    int j = i & 7, lane = (i >> 3) & 63, q = i >> 9;
    int mb = q % 16, kc = q / 16;
    int m = mb * 16 + (lane & 15), k = kc * 32 + (lane >> 4) * 8 + j;
    W1PA[i] = f2b(pa_w1[m * 64 + k] * (pa_g[m] * BNS));
  } else if (i < 32768) {
    int ii = i - 16384;
    int j = ii & 7, lane = (ii >> 3) & 63, q = ii >> 9;
    int mb = q % 4, kc = q / 4;
    int m = mb * 16 + (lane & 15), k = kc * 32 + (lane >> 4) * 8 + j;
    W2PA[ii] = f2b(pa_w2[m * 256 + k]);
  } else if (i < 69632) {
    int ii = i - 32768;
    int j = ii & 7, lane = (ii >> 3) & 63, q = ii >> 9;
    int mb = q % 4, gk = q / 4;           // gk = tap*2 + kc2, tap = ky*3+kx
    int tap = gk >> 1, kc2 = gk & 1;
    int co = mb * 16 + (lane & 15), ci = kc2 * 32 + (lane >> 4) * 8 + j;
    WLAP[ii] = f2b(la_w[(co * 64 + ci) * 9 + tap] * (la_g[co] * BNS));
  } else if (i < 77824) {
    int ii = i - 69632;
    int j = ii & 7, lane = (ii >> 3) & 63, q = ii >> 9;
    int mb = q % 4, kc = q / 4;
    int m = mb * 16 + (lane & 15), k = kc * 32 + (lane >> 4) * 8 + j;
    F1P[ii] = f2b(f1w[m * 128 + k]);
  }
}

// ============ weight prep #2: GA-phase packs (after PA/LA free R-tail usage) ================
__global__ __launch_bounds__(256) void k_wprep2(const float* __restrict__ f2w,
    const float* __restrict__ p1w, const float* __restrict__ c1w,
    const float* __restrict__ c2w, const float* __restrict__ cvw,
    const float* __restrict__ p2w,
    unsigned short* __restrict__ F2P, unsigned short* __restrict__ P1P,
    unsigned short* __restrict__ C1P, unsigned short* __restrict__ C2P,
    unsigned short* __restrict__ CVP, unsigned short* __restrict__ P2P) {
  int i = blockIdx.x * 256 + threadIdx.x;
  if (i < 8192) {               // fuse2: MT=4, K=128
    int j = i & 7, lane = (i >> 3) & 63, q = i >> 9;
    int mb = q % 4, kc = q / 4;
    int m = mb * 16 + (lane & 15), k = kc * 32 + (lane >> 4) * 8 + j;
    F2P[i] = f2b(f2w[m * 128 + k]);
  } else if (i < 12288) {       // p1: MT=4, K=64
    int ii = i - 8192;
    int j = ii & 7, lane = (ii >> 3) & 63, q = ii >> 9;
    int mb = q % 4, kc = q / 4;
    int m = mb * 16 + (lane & 15), k = kc * 32 + (lane >> 4) * 8 + j;
    P1P[ii] = f2b(p1w[m * 64 + k]);
  } else if (i < 14336) {       // c1: MT=2, K=64
    int ii = i - 12288;
    int j = ii & 7, lane = (ii >> 3) & 63, q = ii >> 9;
    int mb = q % 2, kc = q / 2;
    int m = mb * 16 + (lane & 15), k = kc * 32 + (lane >> 4) * 8 + j;
    C1P[ii] = f2b(c1w[m * 64 + k]);
  } else if (i < 16384) {       // c2: MT=2, K=64
    int ii = i - 14336;
    int j = ii & 7, lane = (ii >> 3) & 63, q = ii >> 9;
    int mb = q % 2, kc = q / 2;
    int m = mb * 16 + (lane & 15), k = kc * 32 + (lane >> 4) * 8 + j;
    C2P[ii] = f2b(c2w[m * 64 + k]);
  } else if (i < 18432) {       // cv: MT=4, K=32
    int ii = i - 16384;
    int j = ii & 7, lane = (ii >> 3) & 63, q = ii >> 9;
    int mb = q % 4;             // kc = 0
    int m = mb * 16 + (lane & 15), k = (lane >> 4) * 8 + j;
    CVP[ii] = f2b(cvw[m * 32 + k]);
  } else if (i < 22528) {       // p2: MT=4, K=64
    int ii = i - 18432;
    int j = ii & 7, lane = (ii >> 3) & 63, q = ii >> 9;
    int mb = q % 4, kc = q / 4;
    int m = mb * 16 + (lane & 15), k = kc * 32 + (lane >> 4) * 8 + j;
    P2P[ii] = f2b(p2w[m * 64 + k]);
  }
}

// ============ PA branch v3: chained MFMA GEMMs (64 -> 256 gelu -> 64) =======================
__global__ __launch_bounds__(256, 2) void k_pa(const float* __restrict__ x,
    const unsigned short* __restrict__ W1PA, const float* __restrict__ b1,
    const unsigned short* __restrict__ W2PA,
    float* __restrict__ x1pa, bf16* __restrict__ xa) {
  __shared__ unsigned short hs[128][40];
  __shared__ float b1s[256];
  int t = threadIdx.x;
  b1s[t] = b1[t];
  __syncthreads();
  int b = blockIdx.x / 72;
  int hw0 = (blockIdx.x % 72) * 128;
  int lane = t & 63, wave = t >> 6, lm = lane & 15, lk = lane >> 4;
  bf16x8 Bf[2][2];   // [nt][ks]
  {
    const float* xb = x + (size_t)b * 256 * 9216 + hw0 + wave * 32 + lm;
#pragma unroll
    for (int nt = 0; nt < 2; ++nt)
#pragma unroll
      for (int ks = 0; ks < 2; ++ks)
#pragma unroll
        for (int j = 0; j < 8; ++j)
          Bf[nt][ks][j] = (short)f2b(xb[(size_t)(ks * 32 + lk * 8 + j) * 9216 + nt * 16]);
  }
  f32x4 Y[4][2];
#pragma unroll
  for (int i = 0; i < 4; ++i) { Y[i][0] = (f32x4){0,0,0,0}; Y[i][1] = (f32x4){0,0,0,0}; }

  for (int c = 0; c < 8; ++c) {   // hidden chunks of 32
    f32x4 Hc[2][2];
#pragma unroll
    for (int i = 0; i < 2; ++i) { Hc[i][0] = (f32x4){0,0,0,0}; Hc[i][1] = (f32x4){0,0,0,0}; }
#pragma unroll
    for (int ks = 0; ks < 2; ++ks)
#pragma unroll
      for (int mt = 0; mt < 2; ++mt) {
        bf16x8 a = *(const bf16x8*)(W1PA + ((size_t)((ks * 16 + c * 2 + mt) * 64 + lane) * 8));
        Hc[mt][0] = __builtin_amdgcn_mfma_f32_16x16x32_bf16(a, Bf[0][ks], Hc[mt][0], 0, 0, 0);
        Hc[mt][1] = __builtin_amdgcn_mfma_f32_16x16x32_bf16(a, Bf[1][ks], Hc[mt][1], 0, 0, 0);
      }
#pragma unroll
    for (int mt = 0; mt < 2; ++mt)
#pragma unroll
      for (int nt = 0; nt < 2; ++nt)
#pragma unroll
        for (int r = 0; r < 4; r += 2) {
          int h = c * 32 + mt * 16 + lk * 4 + r;
          float v0 = geluf(Hc[mt][nt][r]     + b1s[h]);
          float v1 = geluf(Hc[mt][nt][r + 1] + b1s[h + 1]);
          unsigned u = (unsigned)f2b(v0) | ((unsigned)f2b(v1) << 16);
          *(unsigned*)&hs[wave * 32 + nt * 16 + lm][mt * 16 + lk * 4 + r] = u;
        }
    bf16x8 h0 = *(const bf16x8*)&hs[wave * 32 + lm][lk * 8];
    bf16x8 h1 = *(const bf16x8*)&hs[wave * 32 + 16 + lm][lk * 8];
#pragma unroll
    for (int mb = 0; mb < 4; ++mb) {
      bf16x8 a2 = *(const bf16x8*)(W2PA + ((size_t)((c * 4 + mb) * 64 + lane) * 8));
      Y[mb][0] = __builtin_amdgcn_mfma_f32_16x16x32_bf16(a2, h0, Y[mb][0], 0, 0, 0);
      Y[mb][1] = __builtin_amdgcn_mfma_f32_16x16x32_bf16(a2, h1, Y[mb][1], 0, 0, 0);
    }
  }
#pragma unroll
  for (int mb = 0; mb < 4; ++mb)
#pragma unroll
    for (int nt = 0; nt < 2; ++nt)
#pragma unroll
      for (int r = 0; r < 4; ++r) {
        int co = mb * 16 + lk * 4 + r;
        int px = hw0 + wave * 32 + nt * 16 + lm;
        float x1v = x[((size_t)b * 256 + co) * 9216 + px];
        float pa = x1v * sigmf(Y[mb][nt][r]);
        x1pa[((size_t)b * 64 + co) * 9216 + px] = pa;
        xa[((size_t)b * 256 + co) * 9216 + px] = __float2bfloat16(x1v + pa);
      }
}

// ============ generic 1x1 MFMA conv =========================================================
// Optional mulA: element-wise multiplier for inA (fuses k_mul). Optional mixK: second input
// K2 with per-pixel sigmoid pair SG (fuses k_mix): B = inA*sg0 + mixK*sg1.
template<int MT, int KCA, int KCB>
__global__ __launch_bounds__(256, 2) void k_cg(const float* __restrict__ inA,
    const float* __restrict__ xsrc, int xoff,
    const unsigned short* __restrict__ wp, const float* __restrict__ bias, int act,
    float* __restrict__ out, int npix,
    const float* __restrict__ mulA = nullptr,
    const float* __restrict__ mixK = nullptr, const float* __restrict__ SG = nullptr) {
  int t = threadIdx.x, lane = t & 63, wave = t >> 6, lm = lane & 15, lk = lane >> 4;
  int p0 = blockIdx.x * 128;
  int b = p0 / npix, hw0 = p0 % npix;
  int pxi = hw0 + wave * 32 + lm;   // per-lane pixel (nt adds 16)
  float sg0 = 0.f, sg1 = 0.f, sg0b = 0.f, sg1b = 0.f;
  if (SG) {
    sg0  = SG[(size_t)(b * 2) * npix + pxi];
    sg1  = SG[(size_t)(b * 2 + 1) * npix + pxi];
    sg0b = SG[(size_t)(b * 2) * npix + pxi + 16];
    sg1b = SG[(size_t)(b * 2 + 1) * npix + pxi + 16];
  }
  f32x4 acc[MT][2];
#pragma unroll
  for (int i = 0; i < MT; ++i) { acc[i][0] = (f32x4){0,0,0,0}; acc[i][1] = (f32x4){0,0,0,0}; }
#pragma unroll
  for (int kc = 0; kc < KCA + KCB; ++kc) {
    bf16x8 bf[2];
#pragma unroll
    for (int nt = 0; nt < 2; ++nt) {
      if (kc < KCA) {
        size_t off = ((size_t)b * (KCA * 32) + kc * 32 + lk * 8) * npix
                   + hw0 + wave * 32 + nt * 16 + lm;
        const float* src = inA + off;
        if (SG) {
          const float* srcK = mixK + off;
          float s0 = nt ? sg0b : sg0, s1 = nt ? sg1b : sg1;
#pragma unroll
          for (int j = 0; j < 8; ++j)
            bf[nt][j] = (short)f2b(src[(size_t)j * npix] * s0 + srcK[(size_t)j * npix] * s1);
        } else if (mulA) {
          const float* srcM = mulA + off;
#pragma unroll
          for (int j = 0; j < 8; ++j)
            bf[nt][j] = (short)f2b(src[(size_t)j * npix] * srcM[(size_t)j * npix]);
        } else {
#pragma unroll
          for (int j = 0; j < 8; ++j) bf[nt][j] = (short)f2b(src[(size_t)j * npix]);
        }
      } else {
        const float* src = xsrc + ((size_t)b * 256 + xoff + (kc - KCA) * 32 + lk * 8) * 9216
                         + hw0 + wave * 32 + nt * 16 + lm;
#pragma unroll
        for (int j = 0; j < 8; ++j) bf[nt][j] = (short)f2b(src[(size_t)j * 9216]);
      }
    }
#pragma unroll
    for (int mb = 0; mb < MT; ++mb) {
      bf16x8 a = *(const bf16x8*)(wp + ((size_t)((kc * MT + mb) * 64 + lane) * 8));
      acc[mb][0] = __builtin_amdgcn_mfma_f32_16x16x32_bf16(a, bf[0], acc[mb][0], 0, 0, 0);
      acc[mb][1] = __builtin_amdgcn_mfma_f32_16x16x32_bf16(a, bf[1], acc[mb][1], 0, 0, 0);
    }
  }
#pragma unroll
  for (int mb = 0; mb < MT; ++mb)
#pragma unroll
    for (int nt = 0; nt < 2; ++nt)
#pragma unroll
      for (int r = 0; r < 4; ++r) {
        int c = mb * 16 + lk * 4 + r;
        float v = acc[mb][nt][r] + (bias ? bias[c] : 0.f);
        if (act) v = geluf(v);
        out[((size_t)b * (MT * 16) + c) * npix + hw0 + wave * 32 + nt * 16 + lm] = v;
      }
}

// ============ la v3: implicit-GEMM 3x3 conv 64->64 via 9 shifted 1x1s =======================
__global__ __launch_bounds__(384, 2) void k_la(const float* __restrict__ Q,
    const unsigned short* __restrict__ WLAP, const float* __restrict__ bb,
    bf16* __restrict__ xa) {
  int py = blockIdx.x % 96, b = blockIdx.x / 96;
  int t = threadIdx.x, lane = t & 63, w = t >> 6, lm = lane & 15, lk = lane >> 4;
  int px = w * 16 + lm;
  f32x4 acc[4];
#pragma unroll
  for (int i = 0; i < 4; ++i) acc[i] = (f32x4){0,0,0,0};
#pragma unroll
  for (int ky = 0; ky < 3; ++ky) {
    int row = py + ky - 1;
    if ((unsigned)row >= 96u) continue;
#pragma unroll
    for (int kx = 0; kx < 3; ++kx) {
      int pxe = px + kx - 1;
      bool vld = (unsigned)pxe < 96u;
      int pxc = vld ? pxe : 0;
      const float* qb = Q + ((size_t)b * 64 + lk * 8) * 9216 + row * 96 + pxc;
#pragma unroll
      for (int kc = 0; kc < 2; ++kc) {
        bf16x8 bf;
#pragma unroll
        for (int j = 0; j < 8; ++j) {
          float v = vld ? qb[(size_t)(kc * 32 + j) * 9216] : 0.f;
          bf[j] = (short)f2b(v);
        }
        int gk = (ky * 3 + kx) * 2 + kc;
#pragma unroll
        for (int mb = 0; mb < 4; ++mb) {
          bf16x8 a = *(const bf16x8*)(WLAP + ((size_t)((gk * 4 + mb) * 64 + lane) * 8));
          acc[mb] = __builtin_amdgcn_mfma_f32_16x16x32_bf16(a, bf, acc[mb], 0, 0, 0);
        }
      }
    }
  }
#pragma unroll
  for (int mb = 0; mb < 4; ++mb)
#pragma unroll
    for (int r = 0; r < 4; ++r) {
      int co = mb * 16 + lk * 4 + r;
      float v = geluf(acc[mb][r] + bb[co]);
      xa[((size_t)b * 256 + 64 + co) * 9216 + py * 96 + px] = __float2bfloat16(v);
    }
}

// ============ fused MRA branch: ONE kernel per (b,c) plane ==================================
// Replaces: mp3blur, dw(h1), dw(v1), htrans, dw(h2), invh_add, vtrans, dw(v2), invv_add, gate.
// Shear algebra: inv_h(conv7x3(h_tr(t)))[i][j] = sum w[ky][kx]*t[i+ky-3][j+kx-ky+2]
//                inv_v(conv3x7(v_tr(t)))[i][j] = sum w[ky][kx]*t[i+ky-kx+2][j+kx-3]
// (E-array row/col bounds auto-satisfied since r'+c' <= 62; only t-bounds remain.)
// fp32 accumulation order matches old chain: ((s1+s2)+s3)+s4, ky-outer kx-inner per conv.
__global__ __launch_bounds__(256) void k_mra(const float* __restrict__ x,
    const float* __restrict__ h1w, const float* __restrict__ v1w,
    const float* __restrict__ h2w, const float* __restrict__ v2w,
    const float* __restrict__ g, const float* __restrict__ bbv,
    float* __restrict__ mra_out, bf16* __restrict__ xa) {
  __shared__ float xs[9216];     // 96x96 x-plane (36 KB)
  __shared__ float ts[32][32];   // blurpool output (4 KB)
  __shared__ float ds[32][32];   // gate pre-activation (4 KB)
  int bc = blockIdx.x;           // = b*64 + c
  int c = bc & 63, b = bc >> 6;
  int t = threadIdx.x;
  const float* src = x + ((size_t)(b * 256 + 128 + c)) * 9216;
  for (int i = t; i < 9216; i += 256) xs[i] = src[i];
  __syncthreads();
  // stage 1: fused maxpool3 + blurpool -> ts
  const float a4[4] = {1.f, 3.f, 3.f, 1.f};
  for (int q = t; q < 1024; q += 256) {
    int oh = q >> 5, ow = q & 31;
    float s = 0.f;
#pragma unroll
    for (int ky = 0; ky < 4; ++ky) {
      int sy = 3 * oh + ky - 1; if (sy < 0) sy = -sy; if (sy > 95) sy = 190 - sy;
#pragma unroll
      for (int kx = 0; kx < 4; ++kx) {
        int sx = 3 * ow + kx - 1; if (sx < 0) sx = -sx; if (sx > 95) sx = 190 - sx;
        float m = -3.4e38f;
        int y0 = sy > 0 ? sy - 1 : 0, y1 = sy < 95 ? sy + 1 : 95;
        int x0 = sx > 0 ? sx - 1 : 0, x1 = sx < 95 ? sx + 1 : 95;
        for (int y = y0; y <= y1; ++y)
          for (int xx = x0; xx <= x1; ++xx)
            m = fmaxf(m, xs[y * 96 + xx]);
        s += a4[ky] * a4[kx] * m;
      }
    }
    ts[oh][ow] = s * (1.0f / 64.0f);
  }
  __syncthreads();
  // stage 2: 4 depthwise convs (2 axis-aligned + 2 skewed) -> ds
  const float* w1  = h1w + c * 21;   // 7x3
  const float* wv1 = v1w + c * 21;   // 3x7
  const float* w2  = h2w + c * 21;   // 7x3 (skewed)
  const float* wv2 = v2w + c * 21;   // 3x7 (skewed)
  for (int q = t; q < 1024; q += 256) {
    int i = q >> 5, j = q & 31;
    float s1 = 0.f, s2 = 0.f, s3 = 0.f, s4 = 0.f;
#pragma unroll
    for (int ky = 0; ky < 7; ++ky) {
      int r = i + ky - 3; if ((unsigned)r >= 32u) continue;
#pragma unroll
      for (int kx = 0; kx < 3; ++kx) {
        int cc = j + kx - 1; if ((unsigned)cc >= 32u) continue;
        s1 += w1[ky * 3 + kx] * ts[r][cc];
      }
    }
#pragma unroll
    for (int ky = 0; ky < 3; ++ky) {
      int r = i + ky - 1; if ((unsigned)r >= 32u) continue;
#pragma unroll
      for (int kx = 0; kx < 7; ++kx) {
        int cc = j + kx - 3; if ((unsigned)cc >= 32u) continue;
        s2 += wv1[ky * 7 + kx] * ts[r][cc];
      }
    }
#pragma unroll
    for (int ky = 0; ky < 7; ++ky) {
      int r = i + ky - 3; if ((unsigned)r >= 32u) continue;
#pragma unroll
      for (int kx = 0; kx < 3; ++kx) {
        int cc = j + kx - ky + 2; if ((unsigned)cc >= 32u) continue;
        s3 += w2[ky * 3 + kx] * ts[r][cc];
      }
    }
#pragma unroll
    for (int ky = 0; ky < 3; ++ky)
#pragma unroll
      for (int kx = 0; kx < 7; ++kx) {
        int r = i + ky - kx + 2, cc = j + kx - 3;
        if ((unsigned)r < 32u && (unsigned)cc < 32u) s4 += wv2[ky * 7 + kx] * ts[r][cc];
      }
    ds[i][j] = ((s1 + s2) + s3) + s4;
  }
  __syncthreads();
  // stage 3: gate (x-plane still in LDS)
  float gg = g[c] * BNS, bb = bbv[c];
  size_t obase = ((size_t)(b * 256 + 128 + c)) * 9216;
  for (int q = t; q < 9216; q += 256) {
    int h = q / 96, wv = q % 96;
    float d = ds[h / 3][wv / 3];
    float gt = sigmf(d * gg + bb);
    float x3v = xs[q];
    float mra = x3v * gt;
    mra_out[(size_t)bc * 9216 + q] = mra;
    xa[obase + q] = __float2bfloat16(x3v + mra);
  }
}

// ---------------- generic depthwise conv (GA branch only) -----------------------------------
__global__ __launch_bounds__(256) void k_dw(const float* __restrict__ in, const float* __restrict__ w,
    const float* __restrict__ bias, float* __restrict__ out,
    int H, int W, int KH, int KW, int pH, int pW, int dil, int accf) {
  int idx = blockIdx.x * 256 + threadIdx.x;
  int total = 16 * 64 * H * W; if (idx >= total) return;
  int wpx = idx % W; int tmp = idx / W; int h = tmp % H; tmp /= H; int c = tmp % 64;
  const float* src = in + tmp * H * W;
  const float* wr = w + c * KH * KW;
  float a = bias ? bias[c] : 0.f;
  for (int ky = 0; ky < KH; ++ky) {
    int y = h - pH + ky * dil; if ((unsigned)y >= (unsigned)H) continue;
    for (int kx = 0; kx < KW; ++kx) {
      int xx = wpx - pW + kx * dil; if ((unsigned)xx >= (unsigned)W) continue;
      a += wr[ky * KW + kx] * src[y * W + xx];
    }
  }
  if (accf) out[idx] += a; else out[idx] = a;
}

// ---------------- maxpool2 with argmax ------------------------------------------------------
__global__ __launch_bounds__(256) void k_pool2(const float* __restrict__ in, float* __restrict__ out,
                                               int* __restrict__ idxo) {
  int idx = blockIdx.x * 256 + threadIdx.x;
  if (idx >= 16 * 64 * 2304) return;
  int ow = idx % 48; int tmp = idx / 48; int oh = tmp % 48; int bc = tmp / 48;
  const float* src = in + bc * 9216;
  int y = 2 * oh, xx = 2 * ow;
  float v0 = src[y * 96 + xx], v1 = src[y * 96 + xx + 1];
  float v2 = src[(y + 1) * 96 + xx], v3 = src[(y + 1) * 96 + xx + 1];
  float best = v0; int bi = 0;
  if (v1 > best) { best = v1; bi = 1; }
  if (v2 > best) { best = v2; bi = 2; }
  if (v3 > best) { best = v3; bi = 3; }
  out[idx] = best; idxo[idx] = bi;
}

// ---------------- channel mean/max ----------------------------------------------------------
__global__ __launch_bounds__(256) void k_agg(const float* __restrict__ J, const float* __restrict__ K,
                                             float* __restrict__ AGG) {
  int idx = blockIdx.x * 256 + threadIdx.x;
  if (idx >= 16 * 2304) return;
  int hw = idx % 2304; int b = idx / 2304;
  float sum = 0.f, mx = -3.4e38f;
  for (int j = 0; j < 32; ++j) { float v = J[(b * 32 + j) * 2304 + hw]; sum += v; mx = fmaxf(mx, v); }
  for (int j = 0; j < 32; ++j) { float v = K[(b * 32 + j) * 2304 + hw]; sum += v; mx = fmaxf(mx, v); }
  AGG[(b * 2 + 0) * 2304 + hw] = sum * (1.0f / 64.0f);
  AGG[(b * 2 + 1) * 2304 + hw] = mx;
}

// ---------------- squeeze conv 2->2 7x7 pad3 + sigmoid --------------------------------------
__global__ __launch_bounds__(256) void k_sq(const float* __restrict__ AGG, const float* __restrict__ w,
                                            const float* __restrict__ bias, float* __restrict__ SG) {
  int idx = blockIdx.x * 256 + threadIdx.x;
  if (idx >= 16 * 2 * 2304) return;
  int hw = idx % 2304; int tmp = idx / 2304; int co = tmp % 2; int b = tmp / 2;
  int h = hw / 48, wv = hw % 48;
  float acc = bias[co];
  for (int ci = 0; ci < 2; ++ci) {
    const float* src = AGG + (b * 2 + ci) * 2304;
    for (int ky = 0; ky < 7; ++ky) {
      int y = h - 3 + ky; if ((unsigned)y >= 48u) continue;
      for (int kx = 0; kx < 7; ++kx) {
        int xx = wv - 3 + kx; if ((unsigned)xx >= 48u) continue;
        acc += w[((co * 2 + ci) * 7 + ky) * 7 + kx] * src[y * 48 + xx];
      }
    }
  }
  SG[idx] = sigmf(acc);
}

// ---------------- unpool + bn(n4), xa ch192..255 --------------------------------------------
__global__ __launch_bounds__(256) void k_unpool(const float* __restrict__ N2, const int* __restrict__ IDX,
    const float* __restrict__ x, const float* __restrict__ g, const float* __restrict__ bb,
    bf16* __restrict__ xa) {
  int idx = blockIdx.x * 256 + threadIdx.x;
  if (idx >= 16 * 64 * 9216) return;
  int wv = idx % 96; int tmp = idx / 96; int h = tmp % 96; tmp /= 96; int c = tmp % 64; int b = tmp / 64;
  int oh = h >> 1, ow = wv >> 1;
  int pos = (b * 64 + c) * 2304 + oh * 48 + ow;
  int kk = (h & 1) * 2 + (wv & 1);
  float v = (IDX[pos] == kk) ? N2[pos] : 0.f;
  float x4v = x[(b * 256 + 192 + c) * 9216 + h * 96 + wv];
  xa[(b * 256 + 192 + c) * 9216 + h * 96 + wv] =
      __float2bfloat16((x4v + v) * g[c] * BNS + bb[c]);
}

// ---------------- transpose XA (ch-major bf16) -> XAT (pixel-major bf16) --------------------
__global__ __launch_bounds__(256) void k_tr(const unsigned short* __restrict__ XA,
                                            unsigned short* __restrict__ XAT) {
  __shared__ unsigned s[64][65];
  int t = threadIdx.x;
  int bid = blockIdx.x;
  int ct = bid & 3;
  int pt = (bid >> 2) % 144;
  int b = (bid >> 2) / 144;
  int c0 = ct * 64, p0 = pt * 64;
  for (int i = t; i < 4096; i += 256) {
    int cl = i >> 6, pl = i & 63;
    s[cl][pl] = XA[(size_t)(b * 256 + c0 + cl) * 9216 + p0 + pl];
  }
  __syncthreads();
  for (int i = t; i < 4096; i += 256) {
    int pl = i >> 6, cl = i & 63;
    XAT[((size_t)(b * 9216 + p0 + pl) << 8) + c0 + cl] = (unsigned short)s[cl][pl];
  }
}

// ---------------- prep: MLP weights frag-linear, bf16, BN scales folded ---------------------
__global__ __launch_bounds__(256) void k_prep(const float* __restrict__ w1, const float* __restrict__ g1,
    const float* __restrict__ w2, const float* __restrict__ ng,
    unsigned short* __restrict__ w1p, unsigned short* __restrict__ w2p) {
  int i = blockIdx.x * 256 + threadIdx.x;
  if (i >= 262144) return;
  {
    int j = i & 7, lane = (i >> 3) & 63, ks = (i >> 9) & 7, mb = i >> 12;
    int h = mb * 16 + (lane & 15);
    int k = ks * 32 + (lane >> 4) * 8 + j;
    w1p[i] = f2b(w1[h * 256 + k] * (g1[h] * BNS));
  }
  {
    int j = i & 7, lane = (i >> 3) & 63, mb = (i >> 9) & 15, c = i >> 13;
    int m = mb * 16 + (lane & 15);
    int k = c * 32 + (lane >> 4) * 8 + j;
    w2p[i] = f2b(w2[m * 1024 + k] * (ng[m] * BNS));
  }
}

// ---------------- fused MFMA MLP v4 (measured 299us; kept) ----------------------------------
__global__ __launch_bounds__(256, 2) void k_mlp_mfma(
    const unsigned short* __restrict__ XAT,
    const unsigned short* __restrict__ W1P, const float* __restrict__ b1,
    const unsigned short* __restrict__ W2P, const float* __restrict__ nbv,
    const float* __restrict__ xin, float* __restrict__ out) {
  __shared__ uint4 w1c4[2048];
  __shared__ uint4 w2c4[2048];
  __shared__ unsigned short hs[128][40];
  __shared__ float b1s[1024];
  __shared__ float nbs[256];
  unsigned short* w1c = (unsigned short*)w1c4;
  unsigned short* w2c = (unsigned short*)w2c4;
  int t = threadIdx.x;
  int b = blockIdx.x / 72;
  int hw0 = (blockIdx.x % 72) * 128;
  for (int i = t; i < 1024; i += 256) b1s[i] = b1[i];
  nbs[t] = nbv[t];
  int lane = t & 63, wave = t >> 6;
  int lm = lane & 15, lk = lane >> 4;
  bf16x8 Bf[2][8];
  {
    const unsigned short* base = XAT + ((size_t)(b * 9216 + hw0 + wave * 32 + lm) << 8) + lk * 8;
#pragma unroll
    for (int nt2 = 0; nt2 < 2; ++nt2)
#pragma unroll
      for (int ks = 0; ks < 8; ++ks)
        Bf[nt2][ks] = *(const bf16x8*)(base + nt2 * 16 * 256 + ks * 32);
  }
  f32x4 Y[16][2];
#pragma unroll
  for (int i = 0; i < 16; ++i) { Y[i][0] = (f32x4){0,0,0,0}; Y[i][1] = (f32x4){0,0,0,0}; }

  const uint4* g1p = (const uint4*)W1P;
  const uint4* g2p = (const uint4*)W2P;
  for (int p = 0; p < 16; ++p) {
    __syncthreads();
#pragma unroll
    for (int i = 0; i < 4; ++i) {
      int o = i * 256 + t;
      gload_lds16(&g1p[(2 * p) * 1024 + o],     &w1c4[o]);
      gload_lds16(&g1p[(2 * p + 1) * 1024 + o], &w1c4[1024 + o]);
      gload_lds16(&g2p[(2 * p) * 1024 + o],     &w2c4[o]);
      gload_lds16(&g2p[(2 * p + 1) * 1024 + o], &w2c4[1024 + o]);
    }
    __syncthreads();
#pragma unroll
    for (int sub = 0; sub < 2; ++sub) {
      int cc = 2 * p + sub;
      int wo = sub * 8192;
      f32x4 Hc[2][2];
#pragma unroll
      for (int i = 0; i < 2; ++i) { Hc[i][0] = (f32x4){0,0,0,0}; Hc[i][1] = (f32x4){0,0,0,0}; }
#pragma unroll
      for (int ks = 0; ks < 8; ++ks) {
        bf16x8 a0 = *(const bf16x8*)&w1c[wo + (ks * 64 + lane) * 8];
        bf16x8 a1 = *(const bf16x8*)&w1c[wo + ((8 + ks) * 64 + lane) * 8];
        Hc[0][0] = __builtin_amdgcn_mfma_f32_16x16x32_bf16(a0, Bf[0][ks], Hc[0][0], 0, 0, 0);
        Hc[0][1] = __builtin_amdgcn_mfma_f32_16x16x32_bf16(a0, Bf[1][ks], Hc[0][1], 0, 0, 0);
        Hc[1][0] = __builtin_amdgcn_mfma_f32_16x16x32_bf16(a1, Bf[0][ks], Hc[1][0], 0, 0, 0);
        Hc[1][1] = __builtin_amdgcn_mfma_f32_16x16x32_bf16(a1, Bf[1][ks], Hc[1][1], 0, 0, 0);
      }
#pragma unroll
      for (int mbl = 0; mbl < 2; ++mbl)
#pragma unroll
        for (int nt2 = 0; nt2 < 2; ++nt2)
#pragma unroll
          for (int r = 0; r < 4; r += 2) {
            int h = cc * 32 + mbl * 16 + lk * 4 + r;
            float v0 = geluf(Hc[mbl][nt2][r]     + b1s[h]);
            float v1 = geluf(Hc[mbl][nt2][r + 1] + b1s[h + 1]);
            unsigned u = (unsigned)f2b(v0) | ((unsigned)f2b(v1) << 16);
            *(unsigned*)&hs[wave * 32 + nt2 * 16 + lm][mbl * 16 + lk * 4 + r] = u;
          }
      bf16x8 h0 = *(const bf16x8*)&hs[wave * 32 + lm][lk * 8];
      bf16x8 h1 = *(const bf16x8*)&hs[wave * 32 + 16 + lm][lk * 8];
#pragma unroll
      for (int mb = 0; mb < 16; ++mb) {
        bf16x8 a = *(const bf16x8*)&w2c[wo + (mb * 64 + lane) * 8];
        Y[mb][0] = __builtin_amdgcn_mfma_f32_16x16x32_bf16(a, h0, Y[mb][0], 0, 0, 0);
        Y[mb][1] = __builtin_amdgcn_mfma_f32_16x16x32_bf16(a, h1, Y[mb][1], 0, 0, 0);
      }
    }
  }
#pragma unroll
  for (int mb = 0; mb < 16; ++mb)
#pragma unroll
    for (int nt2 = 0; nt2 < 2; ++nt2)
#pragma unroll
      for (int r = 0; r < 4; ++r) {
        int m = mb * 16 + lk * 4 + r;
        size_t o = (size_t)(b * 256 + m) * 9216 + hw0 + wave * 32 + nt2 * 16 + lm;
        out[o] = Y[mb][nt2][r] + nbs[m] + xin[o];
      }
}

extern "C" void kernel_launch(void* const* d_in, const int* in_sizes, int n_in,
                              void* d_out, int out_size, void* d_ws, size_t ws_size,
                              hipStream_t stream) {
  const float* x        = (const float*)d_in[0];
  const float* pa_w1    = (const float*)d_in[1];
  const float* pa_bn_g  = (const float*)d_in[2];
  const float* pa_bn_b  = (const float*)d_in[3];
  const float* pa_w2    = (const float*)d_in[4];
  const float* fuse1_w  = (const float*)d_in[5];
  const float* la_w     = (const float*)d_in[6];
  const float* la_bn_g  = (const float*)d_in[7];
  const float* la_bn_b  = (const float*)d_in[8];
  const float* h1_w     = (const float*)d_in[9];
  const float* v1_w     = (const float*)d_in[10];
  const float* h2_w     = (const float*)d_in[11];
  const float* v2_w     = (const float*)d_in[12];
  const float* mra_bn_g = (const float*)d_in[13];
  const float* mra_bn_b = (const float*)d_in[14];
  const float* fuse2_w  = (const float*)d_in[15];
  const float* g_p1_w   = (const float*)d_in[16];
  const float* g_p1_b   = (const float*)d_in[17];
  const float* g_c0_w   = (const float*)d_in[18];
  const float* g_c0_b   = (const float*)d_in[19];
  const float* g_cs_w   = (const float*)d_in[20];
  const float* g_cs_b   = (const float*)d_in[21];
  const float* g_c1_w   = (const float*)d_in[22];
  const float* g_c1_b   = (const float*)d_in[23];
  const float* g_c2_w   = (const float*)d_in[24];
  const float* g_c2_b   = (const float*)d_in[25];
  const float* g_sq_w   = (const float*)d_in[26];
  const float* g_sq_b   = (const float*)d_in[27];
  const float* g_cv_w   = (const float*)d_in[28];
  const float* g_cv_b   = (const float*)d_in[29];
  const float* g_p2_w   = (const float*)d_in[30];
  const float* g_p2_b   = (const float*)d_in[31];
  const float* n4_g     = (const float*)d_in[32];
  const float* n4_b     = (const float*)d_in[33];
  const float* mlp_w1   = (const float*)d_in[34];
  const float* mlp_bn_g = (const float*)d_in[35];
  const float* mlp_bn_b = (const float*)d_in[36];
  const float* mlp_w2   = (const float*)d_in[37];
  const float* n1_g     = (const float*)d_in[38];
  const float* n1_b     = (const float*)d_in[39];

  // ---- aliased workspace: 44,236,800 floats = 176.9 MB ----
  float* ws = (float*)d_ws;
  bf16*  XA = (bf16*)ws;                    // (16,256,96,96) bf16 = 18,874,368 f-slots
  float* P  = ws + 18874368;                // 9,437,184 f
  float* Q  = ws + 28311552;                // 9,437,184 f
  float* R  = ws + 37748736;                // 6,225,920 f
  float* C48 = P;
  int*   IDX = (int*)(P + 2359296);
  float* G   = P + 4718592;
  float* H2  = P + 7077888;
  float* I2  = Q;
  float* M   = Q + 2359296;
  float* N2  = Q + 7077888;
  float* J   = R;
  float* K2  = R + 1179648;
  float* AGG = R + 3538944;
  float* SG  = R + 3612672;
  unsigned short* XAT = (unsigned short*)P;
  unsigned short* W1P = (unsigned short*)(ws + 43974656);
  unsigned short* W2P = (unsigned short*)(ws + 43974656 + 131072);

  // Early bf16 frag packs: live in R head, dead before GA phase writes J to R.
  unsigned short* W1PA = (unsigned short*)(R + 2097152);  // 16384 sh (R mid, clear of J/K2)
  unsigned short* W2PA = W1PA + 16384;         // 16384 sh
  unsigned short* WLAP = W1PA + 32768;         // 36864 sh
  unsigned short* F1P  = W1PA + 69632;         // 8192 sh (ends 77824 sh < 1048576 f span)
  // GA-phase packs: R tail (after SG end 3686400).
  unsigned short* GWp = (unsigned short*)(R + 3686400);
  unsigned short* F2P = GWp;                   // 8192
  unsigned short* P1P = GWp + 8192;            // 4096
  unsigned short* C1P = GWp + 12288;           // 2048
  unsigned short* C2P = GWp + 14336;           // 2048
  unsigned short* CVP = GWp + 16384;           // 2048
  unsigned short* P2P = GWp + 18432;           // 4096 (ends 22528 sh = 11264 f)

  // Prep
  k_prep<<<1024, 256, 0, stream>>>(mlp_w1, mlp_bn_g, mlp_w2, n1_g, W1P, W2P);
  k_wprep<<<304, 256, 0, stream>>>(pa_w1, pa_bn_g, pa_w2, la_w, la_bn_g, fuse1_w,
                                   W1PA, W2PA, WLAP, F1P);
  // Branch 1 (PA): MFMA chained GEMMs
  k_pa<<<1152, 256, 0, stream>>>(x, W1PA, pa_bn_b, W2PA, P, XA);
  // Branch 2: fuse1 (MFMA) -> Q; la (MFMA implicit GEMM) -> xa ch 64..127
  k_cg<4, 2, 2><<<1152, 256, 0, stream>>>(P, x, 64, F1P, (const float*)nullptr, 0, Q, 9216);
  k_la<<<1536, 384, 0, stream>>>(Q, WLAP, la_bn_b, XA);
  // Branch 3 (MRA): entire branch fused into ONE kernel
  k_mra<<<1024, 256, 0, stream>>>(x, h1_w, v1_w, h2_w, v2_w, mra_bn_g, mra_bn_b, P, XA);
  // Branch 4 (GA): all 1x1s via MFMA; k_mul and k_mix fused into k_cg
  k_wprep2<<<88, 256, 0, stream>>>(fuse2_w, g_p1_w, g_c1_w, g_c2_w, g_cv_w, g_p2_w,
                                   F2P, P1P, C1P, C2P, CVP, P2P);
  k_cg<4, 2, 2><<<1152, 256, 0, stream>>>(P, x, 192, F2P, (const float*)nullptr, 0, Q, 9216);
  k_pool2<<<9216, 256, 0, stream>>>(Q, C48, IDX);
  k_cg<4, 2, 0><<<288, 256, 0, stream>>>(C48, (const float*)nullptr, 0, P1P, g_p1_b, 1, G, 2304);
  k_dw<<<9216, 256, 0, stream>>>(G, g_c0_w, g_c0_b, H2, 48, 48, 5, 5, 2, 2, 1, 0);
  k_dw<<<9216, 256, 0, stream>>>(H2, g_cs_w, g_cs_b, I2, 48, 48, 7, 7, 9, 9, 3, 0);
  k_cg<2, 2, 0><<<288, 256, 0, stream>>>(H2, (const float*)nullptr, 0, C1P, g_c1_b, 0, J, 2304);
  k_cg<2, 2, 0><<<288, 256, 0, stream>>>(I2, (const float*)nullptr, 0, C2P, g_c2_b, 0, K2, 2304);
  k_agg<<<144, 256, 0, stream>>>(J, K2, AGG);
  k_sq<<<288, 256, 0, stream>>>(AGG, g_sq_w, g_sq_b, SG);
  // cv conv with k_mix fused into B-frag load: B = J*sg0 + K2*sg1
  k_cg<4, 1, 0><<<288, 256, 0, stream>>>(J, (const float*)nullptr, 0, CVP, g_cv_b, 0, M, 2304,
                                         (const float*)nullptr, K2, SG);
  // p2 conv with k_mul fused: B = G * M
  k_cg<4, 2, 0><<<288, 256, 0, stream>>>(G, (const float*)nullptr, 0, P2P, g_p2_b, 0, N2, 2304,
                                         M);
  k_unpool<<<36864, 256, 0, stream>>>(N2, IDX, x, n4_g, n4_b, XA);
  // Transpose xa -> pixel-major
  k_tr<<<9216, 256, 0, stream>>>((const unsigned short*)XA, XAT);
  // MLP + residual
  k_mlp_mfma<<<1152, 256, 0, stream>>>(XAT, W1P, mlp_bn_b, W2P, n1_b, x, (float*)d_out);
}